// Round 1
// baseline (2301.944 us; speedup 1.0000x reference)
//
#include <hip/hip_runtime.h>
#include <math.h>

#define SMOOTH 1e-4f
#define BN_EPS 1e-5f

constexpr int Bn = 8;
constexpr int Cc = 256;
constexpr int Nn = 1024;   // H*W
constexpr int G = 8;       // heads
constexpr int Dd = 64;     // head dim
constexpr int INNER = 512;
constexpr int OC = 1536;   // 3*INNER

__device__ __forceinline__ float waveSum(float v) {
#pragma unroll
  for (int off = 32; off > 0; off >>= 1) v += __shfl_xor(v, off, 64);
  return v;
}

// ---------------------------------------------------------------------------
// 3x3 conv, SAME pad, no bias. block = 256 thr, covers (b, 8 oc, 32x32 img).
// grid = Bn * (OC/8) = 1536
// ---------------------------------------------------------------------------
__global__ __launch_bounds__(256) void conv3x3_kernel(
    const float* __restrict__ x, const float* __restrict__ wq,
    float* __restrict__ qkv) {
  const int tid = threadIdx.x;
  const int ocg = blockIdx.x % (OC / 8);
  const int b   = blockIdx.x / (OC / 8);
  const int oc0 = ocg * 8;

  __shared__ __align__(16) float ws[64 * 9 * 8];  // [ic_chunk][tap][j] 18KB
  __shared__ __align__(16) float xs[32 * 33];     // +1 padded rows

  const int hh = tid >> 3;        // row 0..31
  const int w0 = (tid & 7) << 2;  // col 0,4,...,28

  float acc[8][4];
#pragma unroll
  for (int j = 0; j < 8; ++j)
#pragma unroll
    for (int p = 0; p < 4; ++p) acc[j][p] = 0.f;

  const float* xb = x + (size_t)b * Cc * Nn;

  for (int icc = 0; icc < Cc; icc += 64) {
    __syncthreads();  // protect ws (and xs) from prior reads
    // stage 64 input-channels' weights, packed [ic2][tap][j]
    for (int i = tid; i < 64 * 72; i += 256) {
      int ic2 = i / 72;
      int rem = i % 72;
      int tap = rem >> 3;
      int j = rem & 7;
      ws[i] = wq[(size_t)(oc0 + j) * (Cc * 9) + (icc + ic2) * 9 + tap];
    }
    for (int ic2 = 0; ic2 < 64; ++ic2) {
      const int ic = icc + ic2;
      __syncthreads();
      {  // stage x channel (padded rows)
        float4 t = reinterpret_cast<const float4*>(xb + (size_t)ic * Nn)[tid];
        float* dst = xs + hh * 33 + w0;
        dst[0] = t.x; dst[1] = t.y; dst[2] = t.z; dst[3] = t.w;
      }
      __syncthreads();

      // neighborhood: rows hh-1..hh+1, cols w0-1..w0+4 (zero outside)
      float xr[3][6];
#pragma unroll
      for (int r = 0; r < 3; ++r) {
        int row = hh - 1 + r;
        bool rv = (row >= 0) && (row < 32);
        int rowc = rv ? row : 0;
#pragma unroll
        for (int c = 0; c < 6; ++c) {
          int col = w0 - 1 + c;
          bool cv = (col >= 0) && (col < 32);
          int colc = cv ? col : 0;
          float v = xs[rowc * 33 + colc];
          xr[r][c] = (rv && cv) ? v : 0.f;
        }
      }

      const float* wrow = ws + ic2 * 72;
#pragma unroll
      for (int kh = 0; kh < 3; ++kh) {
#pragma unroll
        for (int kw = 0; kw < 3; ++kw) {
          const int tap = kh * 3 + kw;
          float4 wa = *reinterpret_cast<const float4*>(wrow + tap * 8);
          float4 wb = *reinterpret_cast<const float4*>(wrow + tap * 8 + 4);
#pragma unroll
          for (int p = 0; p < 4; ++p) {
            float xv = xr[kh][kw + p];
            acc[0][p] += wa.x * xv;
            acc[1][p] += wa.y * xv;
            acc[2][p] += wa.z * xv;
            acc[3][p] += wa.w * xv;
            acc[4][p] += wb.x * xv;
            acc[5][p] += wb.y * xv;
            acc[6][p] += wb.z * xv;
            acc[7][p] += wb.w * xv;
          }
        }
      }
    }
  }

#pragma unroll
  for (int j = 0; j < 8; ++j) {
    float4 t = make_float4(acc[j][0], acc[j][1], acc[j][2], acc[j][3]);
    *reinterpret_cast<float4*>(qkv + ((size_t)b * OC + oc0 + j) * Nn + hh * 32 + w0) = t;
  }
}

// ---------------------------------------------------------------------------
// positional-bias row sums: denom[g][n] = sum_m exp(-sf_g * dis(n,m))
// grid = G*Nn = 8192 blocks of 256
// ---------------------------------------------------------------------------
__global__ __launch_bounds__(256) void pbdenom_kernel(
    const float* __restrict__ head_scale, float* __restrict__ denom) {
  const int tid = threadIdx.x;
  const int g = blockIdx.x >> 10;
  const int n = blockIdx.x & 1023;
  const float hs = head_scale[g];
  const float sg = 1.f / (1.f + __expf(-hs));
  const float s = sg * (0.4f - 0.003f) + 0.003f;
  const float sf = 1.f / (2.f * s * s);
  const float yn = (float)(n >> 5), xn = (float)(n & 31);
  float sum = 0.f;
#pragma unroll
  for (int j = 0; j < 4; ++j) {
    int m = tid + (j << 8);
    float dy = (yn - (float)(m >> 5)) * (1.f / 32.f);
    float dx = (xn - (float)(m & 31)) * (1.f / 32.f);
    sum += __expf(-sf * (dy * dy + dx * dx));
  }
  float tot = waveSum(sum);
  __shared__ float red[4];
  if ((tid & 63) == 0) red[tid >> 6] = tot;
  __syncthreads();
  if (tid == 0) denom[blockIdx.x] = red[0] + red[1] + red[2] + red[3];
}

// ---------------------------------------------------------------------------
// attention: block = 512 thr (8 waves); each wave owns one query row n.
// K,V tiles (64 m x 64 d) staged in LDS as [d4][m] float4 (conflict-free).
// grid = Bn*G*Nn/8 = 8192
// ---------------------------------------------------------------------------
__global__ __launch_bounds__(512, 1) void attn_kernel(
    const float* __restrict__ qkv, const float* __restrict__ head_scale,
    const float* __restrict__ denom, float* __restrict__ aout) {
  const int tid = threadIdx.x;
  const int lane = tid & 63;
  const int wv = tid >> 6;
  const int blk = blockIdx.x;
  const int nb = blk & 127;
  const int g = (blk >> 7) & 7;
  const int b = blk >> 10;
  const int n = nb * 8 + wv;

  __shared__ __align__(16) float kT[16 * 64 * 4];  // 16KB
  __shared__ __align__(16) float vT[16 * 64 * 4];  // 16KB

  const float* qbase = qkv + ((size_t)b * OC + g * Dd) * Nn;
  const float* kbase = qkv + ((size_t)b * OC + INNER + g * Dd) * Nn;
  const float* vbase = qkv + ((size_t)b * OC + 2 * INNER + g * Dd) * Nn;

  // q row in registers (replicated across lanes)
  float q[64];
#pragma unroll
  for (int d = 0; d < 64; ++d) q[d] = qbase[(size_t)d * Nn + n];
  float qq = 0.f;
#pragma unroll
  for (int d = 0; d < 64; ++d) qq += q[d] * q[d];
  const float qn = sqrtf(qq + SMOOTH);

  const float hs = head_scale[g];
  const float sg = 1.f / (1.f + __expf(-hs));
  const float s = sg * (0.4f - 0.003f) + 0.003f;
  const float sf = 1.f / (2.f * s * s);
  const float invden = 1.f / denom[(g << 10) + n];
  const float yn = (float)(n >> 5), xn = (float)(n & 31);

  float acc[64];
#pragma unroll
  for (int d = 0; d < 64; ++d) acc[d] = 0.f;

  for (int mt = 0; mt < 16; ++mt) {
    __syncthreads();
#pragma unroll
    for (int jj = 0; jj < 2; ++jj) {  // stage K,V tile
      int idx = (jj << 9) + tid;      // 0..1023 : d4 = idx>>6, m = idx&63
      int d4 = idx >> 6;
      int m = idx & 63;
      int col = (mt << 6) + m;
      const float* kp = kbase + (size_t)(d4 << 2) * Nn + col;
      float4 t;
      t.x = kp[0]; t.y = kp[Nn]; t.z = kp[2 * Nn]; t.w = kp[3 * Nn];
      reinterpret_cast<float4*>(kT)[idx] = t;
      const float* vp = vbase + (size_t)(d4 << 2) * Nn + col;
      float4 u;
      u.x = vp[0]; u.y = vp[Nn]; u.z = vp[2 * Nn]; u.w = vp[3 * Nn];
      reinterpret_cast<float4*>(vT)[idx] = u;
    }
    __syncthreads();

    const int m = (mt << 6) + lane;
    float dot = 0.f, kk = 0.f;
#pragma unroll
    for (int d4 = 0; d4 < 16; ++d4) {
      float4 k4 = reinterpret_cast<const float4*>(kT)[(d4 << 6) + lane];
      dot += q[4 * d4 + 0] * k4.x + q[4 * d4 + 1] * k4.y +
             q[4 * d4 + 2] * k4.z + q[4 * d4 + 3] * k4.w;
      kk += k4.x * k4.x + k4.y * k4.y + k4.z * k4.z + k4.w * k4.w;
    }
    const float kn = sqrtf(kk + SMOOTH);
    const float dy = (yn - (float)(m >> 5)) * (1.f / 32.f);
    const float dx = (xn - (float)(m & 31)) * (1.f / 32.f);
    const float wgt = __fdividef(dot, qn * kn + SMOOTH) *
                      __expf(-sf * (dy * dy + dx * dx)) * invden;
#pragma unroll
    for (int d4 = 0; d4 < 16; ++d4) {
      float4 v4 = reinterpret_cast<const float4*>(vT)[(d4 << 6) + lane];
      acc[4 * d4 + 0] += wgt * v4.x;
      acc[4 * d4 + 1] += wgt * v4.y;
      acc[4 * d4 + 2] += wgt * v4.z;
      acc[4 * d4 + 3] += wgt * v4.w;
    }
  }

  // distributed log-time cross-lane reduction: lane l ends with sum for d=l
#pragma unroll
  for (int o = 32; o >= 1; o >>= 1) {
    const bool up = (lane & o) != 0;
#pragma unroll
    for (int i = 0; i < o; ++i) {
      float keep = up ? acc[i + o] : acc[i];
      float other = up ? acc[i] : acc[i + o];
      acc[i] = keep + __shfl_xor(other, o, 64);
    }
  }
  // aout layout: [b][i = g*64+d][n]
  aout[((size_t)(b * G + g) * Dd + lane) * Nn + n] = acc[0];
}

// ---------------------------------------------------------------------------
// 1x1 conv: proj[b][c][n] = sum_i wout[c][i] * aout[b][i][n]
// block = 256 thr handles (b, 4 channels), float4 over n. grid = Bn*Cc/4 = 512
// ---------------------------------------------------------------------------
__global__ __launch_bounds__(256) void conv1x1_kernel(
    const float* __restrict__ aout, const float* __restrict__ wout,
    float* __restrict__ proj) {
  const int tid = threadIdx.x;
  const int cg = blockIdx.x % (Cc / 4);
  const int b = blockIdx.x / (Cc / 4);
  const int c0 = cg * 4;
  __shared__ __align__(16) float ws[4][INNER];
  for (int i = tid; i < 4 * INNER; i += 256)
    ws[i >> 9][i & 511] = wout[(size_t)(c0 + (i >> 9)) * INNER + (i & 511)];
  __syncthreads();
  const float* ab = aout + (size_t)b * INNER * Nn;
  float4 a0 = {0, 0, 0, 0}, a1 = {0, 0, 0, 0}, a2 = {0, 0, 0, 0}, a3 = {0, 0, 0, 0};
#pragma unroll 4
  for (int i = 0; i < INNER; ++i) {
    float4 a4 = reinterpret_cast<const float4*>(ab + (size_t)i * Nn)[tid];
    float w0 = ws[0][i], w1 = ws[1][i], w2 = ws[2][i], w3 = ws[3][i];
    a0.x += w0 * a4.x; a0.y += w0 * a4.y; a0.z += w0 * a4.z; a0.w += w0 * a4.w;
    a1.x += w1 * a4.x; a1.y += w1 * a4.y; a1.z += w1 * a4.z; a1.w += w1 * a4.w;
    a2.x += w2 * a4.x; a2.y += w2 * a4.y; a2.z += w2 * a4.z; a2.w += w2 * a4.w;
    a3.x += w3 * a4.x; a3.y += w3 * a4.y; a3.z += w3 * a4.z; a3.w += w3 * a4.w;
  }
  reinterpret_cast<float4*>(proj + ((size_t)b * Cc + c0 + 0) * Nn)[tid] = a0;
  reinterpret_cast<float4*>(proj + ((size_t)b * Cc + c0 + 1) * Nn)[tid] = a1;
  reinterpret_cast<float4*>(proj + ((size_t)b * Cc + c0 + 2) * Nn)[tid] = a2;
  reinterpret_cast<float4*>(proj + ((size_t)b * Cc + c0 + 3) * Nn)[tid] = a3;
}

// ---------------------------------------------------------------------------
// BN train-mode stats per channel. grid = Cc blocks of 256.
// ---------------------------------------------------------------------------
__global__ __launch_bounds__(256) void bn_stats_kernel(
    const float* __restrict__ proj, float* __restrict__ stats) {
  const int c = blockIdx.x;
  const int tid = threadIdx.x;
  float s = 0.f, s2 = 0.f;
  for (int b = 0; b < Bn; ++b) {
    float4 v = reinterpret_cast<const float4*>(proj + ((size_t)b * Cc + c) * Nn)[tid];
    s += v.x + v.y + v.z + v.w;
    s2 += v.x * v.x + v.y * v.y + v.z * v.z + v.w * v.w;
  }
  s = waveSum(s);
  s2 = waveSum(s2);
  __shared__ float r1[4], r2[4];
  if ((tid & 63) == 0) { r1[tid >> 6] = s; r2[tid >> 6] = s2; }
  __syncthreads();
  if (tid == 0) {
    float S = r1[0] + r1[1] + r1[2] + r1[3];
    float S2 = r2[0] + r2[1] + r2[2] + r2[3];
    const float invM = 1.f / (float)(Bn * Nn);
    float mean = S * invM;
    float var = S2 * invM - mean * mean;
    stats[c] = mean;
    stats[Cc + c] = rsqrtf(var + BN_EPS);
  }
}

__global__ __launch_bounds__(256) void bn_apply_kernel(
    const float* __restrict__ proj, const float* __restrict__ stats,
    const float* __restrict__ gamma, const float* __restrict__ beta,
    float* __restrict__ out) {
  const int idx = blockIdx.x * 256 + threadIdx.x;  // float4 index
  const int flat = idx << 2;
  const int c = (flat >> 10) & (Cc - 1);
  float4 v = reinterpret_cast<const float4*>(proj)[idx];
  const float mean = stats[c];
  const float sc = stats[Cc + c] * gamma[c];
  const float sh = beta[c];
  float4 o;
  o.x = fmaxf((v.x - mean) * sc + sh, 0.f);
  o.y = fmaxf((v.y - mean) * sc + sh, 0.f);
  o.z = fmaxf((v.z - mean) * sc + sh, 0.f);
  o.w = fmaxf((v.w - mean) * sc + sh, 0.f);
  reinterpret_cast<float4*>(out)[idx] = o;
}

// ---------------------------------------------------------------------------
extern "C" void kernel_launch(void* const* d_in, const int* in_sizes, int n_in,
                              void* d_out, int out_size, void* d_ws, size_t ws_size,
                              hipStream_t stream) {
  const float* x = (const float*)d_in[0];
  const float* w_qkv = (const float*)d_in[1];
  const float* head_scale = (const float*)d_in[2];
  const float* w_out = (const float*)d_in[3];
  const float* gamma = (const float*)d_in[4];
  const float* beta = (const float*)d_in[5];
  float* out = (float*)d_out;

  float* qkv = (float*)d_ws;                      // 12,582,912 f
  float* aout = qkv + (size_t)Bn * OC * Nn;       // 4,194,304 f
  float* denom = aout + (size_t)Bn * INNER * Nn;  // 8,192 f
  float* stats = denom + (size_t)G * Nn;          // 512 f
  float* proj = qkv;                              // reuse: qkv dead after attn

  conv3x3_kernel<<<dim3(Bn * (OC / 8)), dim3(256), 0, stream>>>(x, w_qkv, qkv);
  pbdenom_kernel<<<dim3(G * Nn), dim3(256), 0, stream>>>(head_scale, denom);
  attn_kernel<<<dim3(Bn * G * Nn / 8), dim3(512), 0, stream>>>(qkv, head_scale, denom, aout);
  conv1x1_kernel<<<dim3(Bn * (Cc / 4)), dim3(256), 0, stream>>>(aout, w_out, proj);
  bn_stats_kernel<<<dim3(Cc), dim3(256), 0, stream>>>(proj, stats);
  bn_apply_kernel<<<dim3((Bn * Cc * Nn / 4) / 256), dim3(256), 0, stream>>>(proj, stats, gamma, beta, out);
}

// Round 2
// 923.650 us; speedup vs baseline: 2.4922x; 2.4922x over previous
//
#include <hip/hip_runtime.h>
#include <math.h>

#define SMOOTH 1e-4f
#define BN_EPS 1e-5f

constexpr int Bn = 8;
constexpr int Cc = 256;
constexpr int Nn = 1024;   // H*W
constexpr int G = 8;       // heads
constexpr int INNER = 512;
constexpr int OC = 1536;   // 3*INNER

typedef unsigned short u16;
typedef __bf16 bf16x8 __attribute__((ext_vector_type(8)));
typedef float f32x4 __attribute__((ext_vector_type(4)));
typedef unsigned short us8 __attribute__((ext_vector_type(8)));
typedef unsigned short us4 __attribute__((ext_vector_type(4)));

__device__ __forceinline__ u16 f2bf(float f) {
  unsigned int u = __float_as_uint(f);
  unsigned int r = (u + 0x7fffu + ((u >> 16) & 1u)) >> 16;
  return (u16)r;
}
__device__ __forceinline__ float bf2f(u16 u) {
  return __uint_as_float(((unsigned int)u) << 16);
}

__device__ __forceinline__ float waveSum(float v) {
#pragma unroll
  for (int off = 32; off > 0; off >>= 1) v += __shfl_xor(v, off, 64);
  return v;
}

// swizzled LDS fragment read: tile rows of 64 u16 (128B), XOR byte-swizzle
// idx(u16) = (row*64+col) ^ ((row&7)<<3)  <=>  byte ^ ((row&7)<<4)
__device__ __forceinline__ bf16x8 ldfrag(const u16* base, int row, int col) {
  int idx = (row * 64 + col) ^ ((row & 7) << 3);
  return __builtin_bit_cast(bf16x8, *reinterpret_cast<const us8*>(base + idx));
}

// ---------------------------------------------------------------------------
// 3x3 conv, SAME pad. block = 256 thr, covers (b, 8 oc, 32x32 img).
// Writes bf16: q,k -> [b][g][n][d]  (n-major);  v -> [b][g][d][n].
// grid = Bn * (OC/8) = 1536
// ---------------------------------------------------------------------------
__global__ __launch_bounds__(256) void conv3x3_kernel(
    const float* __restrict__ x, const float* __restrict__ wq,
    u16* __restrict__ qt, u16* __restrict__ kt, u16* __restrict__ vt) {
  const int tid = threadIdx.x;
  const int ocg = blockIdx.x % (OC / 8);
  const int b   = blockIdx.x / (OC / 8);
  const int oc0 = ocg * 8;

  __shared__ __align__(16) float ws[64 * 9 * 8];  // [ic_chunk][tap][j] 18KB
  __shared__ __align__(16) float xs[32 * 33];     // +1 padded rows

  const int hh = tid >> 3;        // row 0..31
  const int w0 = (tid & 7) << 2;  // col 0,4,...,28

  float acc[8][4];
#pragma unroll
  for (int j = 0; j < 8; ++j)
#pragma unroll
    for (int p = 0; p < 4; ++p) acc[j][p] = 0.f;

  const float* xb = x + (size_t)b * Cc * Nn;

  for (int icc = 0; icc < Cc; icc += 64) {
    __syncthreads();
    for (int i = tid; i < 64 * 72; i += 256) {
      int ic2 = i / 72;
      int rem = i % 72;
      int tap = rem >> 3;
      int j = rem & 7;
      ws[i] = wq[(size_t)(oc0 + j) * (Cc * 9) + (icc + ic2) * 9 + tap];
    }
    for (int ic2 = 0; ic2 < 64; ++ic2) {
      const int ic = icc + ic2;
      __syncthreads();
      {
        float4 t = reinterpret_cast<const float4*>(xb + (size_t)ic * Nn)[tid];
        float* dst = xs + hh * 33 + w0;
        dst[0] = t.x; dst[1] = t.y; dst[2] = t.z; dst[3] = t.w;
      }
      __syncthreads();

      float xr[3][6];
#pragma unroll
      for (int r = 0; r < 3; ++r) {
        int row = hh - 1 + r;
        bool rv = (row >= 0) && (row < 32);
        int rowc = rv ? row : 0;
#pragma unroll
        for (int c = 0; c < 6; ++c) {
          int col = w0 - 1 + c;
          bool cv = (col >= 0) && (col < 32);
          int colc = cv ? col : 0;
          float v = xs[rowc * 33 + colc];
          xr[r][c] = (rv && cv) ? v : 0.f;
        }
      }

      const float* wrow = ws + ic2 * 72;
#pragma unroll
      for (int kh = 0; kh < 3; ++kh) {
#pragma unroll
        for (int kw = 0; kw < 3; ++kw) {
          const int tap = kh * 3 + kw;
          float4 wa = *reinterpret_cast<const float4*>(wrow + tap * 8);
          float4 wb = *reinterpret_cast<const float4*>(wrow + tap * 8 + 4);
#pragma unroll
          for (int p = 0; p < 4; ++p) {
            float xv = xr[kh][kw + p];
            acc[0][p] += wa.x * xv;
            acc[1][p] += wa.y * xv;
            acc[2][p] += wa.z * xv;
            acc[3][p] += wa.w * xv;
            acc[4][p] += wb.x * xv;
            acc[5][p] += wb.y * xv;
            acc[6][p] += wb.z * xv;
            acc[7][p] += wb.w * xv;
          }
        }
      }
    }
  }

  const int sec = oc0 >> 9;  // 0=q 1=k 2=v
  const int io = oc0 & 511;
  const int gq = io >> 6;
  const int d0 = io & 63;
  const size_t bgi = (size_t)b * G + gq;
  const int n0 = hh * 32 + w0;
  if (sec < 2) {
    u16* dst = (sec ? kt : qt) + (bgi * 1024 + n0) * 64 + d0;
#pragma unroll
    for (int p = 0; p < 4; ++p) {
      us8 v;
#pragma unroll
      for (int j = 0; j < 8; ++j) v[j] = f2bf(acc[j][p]);
      *reinterpret_cast<us8*>(dst + (size_t)p * 64) = v;
    }
  } else {
    u16* dst = vt + (bgi * 64 + d0) * 1024 + n0;
#pragma unroll
    for (int j = 0; j < 8; ++j) {
      us4 v;
      v[0] = f2bf(acc[j][0]); v[1] = f2bf(acc[j][1]);
      v[2] = f2bf(acc[j][2]); v[3] = f2bf(acc[j][3]);
      *reinterpret_cast<us4*>(dst + (size_t)j * 1024) = v;
    }
  }
}

// ---------------------------------------------------------------------------
// positional-bias row sums: denom[g][n] = sum_m exp(-sf_g * dis(n,m))
// ---------------------------------------------------------------------------
__global__ __launch_bounds__(256) void pbdenom_kernel(
    const float* __restrict__ head_scale, float* __restrict__ denom) {
  const int tid = threadIdx.x;
  const int g = blockIdx.x >> 10;
  const int n = blockIdx.x & 1023;
  const float hs = head_scale[g];
  const float sg = 1.f / (1.f + __expf(-hs));
  const float s = sg * (0.4f - 0.003f) + 0.003f;
  const float sf = 1.f / (2.f * s * s);
  const float yn = (float)(n >> 5), xn = (float)(n & 31);
  float sum = 0.f;
#pragma unroll
  for (int j = 0; j < 4; ++j) {
    int m = tid + (j << 8);
    float dy = (yn - (float)(m >> 5)) * (1.f / 32.f);
    float dx = (xn - (float)(m & 31)) * (1.f / 32.f);
    sum += __expf(-sf * (dy * dy + dx * dx));
  }
  float tot = waveSum(sum);
  __shared__ float red[4];
  if ((tid & 63) == 0) red[tid >> 6] = tot;
  __syncthreads();
  if (tid == 0) denom[blockIdx.x] = red[0] + red[1] + red[2] + red[3];
}

// ---------------------------------------------------------------------------
// q/k row norms from the bf16-rounded tensors (consistent with MFMA inputs).
// 4 lanes per row; grid = 2*65536/64 = 2048 blocks of 256.
// ---------------------------------------------------------------------------
__global__ __launch_bounds__(256) void norms_kernel(
    const u16* __restrict__ qt, const u16* __restrict__ kt,
    float* __restrict__ qn, float* __restrict__ kn) {
  const int idx = blockIdx.x * 64 + (threadIdx.x >> 2);
  const int sub = threadIdx.x & 3;
  const int sel = idx >> 16;
  const int row = idx & 65535;
  const u16* src = (sel ? kt : qt) + (size_t)row * 64 + sub * 16;
  float s = 0.f;
#pragma unroll
  for (int k = 0; k < 2; ++k) {
    us8 v = reinterpret_cast<const us8*>(src)[k];
#pragma unroll
    for (int j = 0; j < 8; ++j) {
      float f = bf2f(v[j]);
      s += f * f;
    }
  }
  s += __shfl_xor(s, 1, 64);
  s += __shfl_xor(s, 2, 64);
  if (sub == 0) (sel ? kn : qn)[row] = sqrtf(s + SMOOTH);
}

// ---------------------------------------------------------------------------
// MFMA attention. block = 256 thr (4 waves), handles (b, g, 128 q-rows).
// grid = 8b * 8g * 8chunks = 512.
// S = Q·K^T via mfma_f32_16x16x32_bf16 (A rows=n, k=d; B cols=m, k=d),
// elementwise cosine+positional weighting in f32, P->bf16 via per-wave LDS
// transpose, then O += P·V (A rows=n, k=m; B cols=d, k=m).
// Fragment layouts (gfx950, verified m89/m91):
//   A: lane l elem j -> A[l&15][8*(l>>4)+j]
//   B: lane l elem j -> B[8*(l>>4)+j][l&15]
//   D: lane l reg  r -> D[4*(l>>4)+r][l&15]
// ---------------------------------------------------------------------------
__global__ __launch_bounds__(256, 2) void attn_mfma_kernel(
    const u16* __restrict__ qt, const u16* __restrict__ kt,
    const u16* __restrict__ vt, const float* __restrict__ qn_arr,
    const float* __restrict__ kn_arr, const float* __restrict__ denom,
    const float* __restrict__ head_scale, u16* __restrict__ aout) {
  const int tid = threadIdx.x;
  const int lane = tid & 63;
  const int wv = tid >> 6;
  const int h = lane >> 4;
  const int l15 = lane & 15;
  const int nb = blockIdx.x & 7;
  const int g = (blockIdx.x >> 3) & 7;
  const int b = blockIdx.x >> 6;

  __shared__ __align__(16) u16 smem[24576];  // 48KB
  u16* sQ = smem;                            // 128x64
  u16* sK = smem + 8192;                     // 64x64
  u16* sV = smem + 12288;                    // 64x64
  u16* sP = smem + 16384 + wv * 2048;        // per-wave 32x64

  const size_t bg = (size_t)b * G + g;
  const u16* qg = qt + bg * 65536;
  const u16* kg = kt + bg * 65536;
  const u16* vg = vt + bg * 65536;  // [64][1024]

  // stage Q tile (rows nb*128..+127), swizzled
  {
    const int row = tid >> 1, c = (tid & 1) * 4;
    const us8* src = reinterpret_cast<const us8*>(qg + (size_t)(nb * 128 + row) * 64);
#pragma unroll
    for (int k = 0; k < 4; ++k) {
      int idx = (row * 64 + (c + k) * 8) ^ ((row & 7) << 3);
      *reinterpret_cast<us8*>(sQ + idx) = src[c + k];
    }
  }

  const float hs = head_scale[g];
  const float sg = 1.f / (1.f + __expf(-hs));
  const float sv = sg * (0.4f - 0.003f) + 0.003f;
  const float sf = 1.f / (2.f * sv * sv);

  float qnv[2][4], qiv[2][4], nyf[2][4], nxf[2][4];
#pragma unroll
  for (int ti = 0; ti < 2; ++ti)
#pragma unroll
    for (int r = 0; r < 4; ++r) {
      int n = nb * 128 + wv * 32 + ti * 16 + 4 * h + r;
      qnv[ti][r] = qn_arr[bg * 1024 + n];
      qiv[ti][r] = 1.f / denom[g * 1024 + n];
      nyf[ti][r] = (float)(n >> 5);
      nxf[ti][r] = (float)(n & 31);
    }

  f32x4 oacc[2][4];
#pragma unroll
  for (int ti = 0; ti < 2; ++ti)
#pragma unroll
    for (int dj = 0; dj < 4; ++dj) oacc[ti][dj] = (f32x4){0.f, 0.f, 0.f, 0.f};

  const int col8 = h * 8;

  for (int mt = 0; mt < 16; ++mt) {
    __syncthreads();
    {  // stage K (rows m, [m][d]) and V ([d][m]) tiles, swizzled
      const int row = tid >> 2, cc = (tid & 3) * 2;
      const us8* ksrc = reinterpret_cast<const us8*>(kg + (size_t)(mt * 64 + row) * 64);
      const us8* vsrc = reinterpret_cast<const us8*>(vg + (size_t)row * 1024 + mt * 64);
#pragma unroll
      for (int k = 0; k < 2; ++k) {
        int idx = (row * 64 + (cc + k) * 8) ^ ((row & 7) << 3);
        *reinterpret_cast<us8*>(sK + idx) = ksrc[cc + k];
        *reinterpret_cast<us8*>(sV + idx) = vsrc[cc + k];
      }
    }
    __syncthreads();

    // S = Q·K^T  (per wave: 32n x 64m)
    f32x4 sacc[2][4];
#pragma unroll
    for (int ti = 0; ti < 2; ++ti)
#pragma unroll
      for (int tj = 0; tj < 4; ++tj) sacc[ti][tj] = (f32x4){0.f, 0.f, 0.f, 0.f};
#pragma unroll
    for (int kk = 0; kk < 2; ++kk) {
      bf16x8 aq0 = ldfrag(sQ, wv * 32 + l15, kk * 32 + col8);
      bf16x8 aq1 = ldfrag(sQ, wv * 32 + 16 + l15, kk * 32 + col8);
#pragma unroll
      for (int tj = 0; tj < 4; ++tj) {
        bf16x8 bk = ldfrag(sK, tj * 16 + l15, kk * 32 + col8);
        sacc[0][tj] = __builtin_amdgcn_mfma_f32_16x16x32_bf16(aq0, bk, sacc[0][tj], 0, 0, 0);
        sacc[1][tj] = __builtin_amdgcn_mfma_f32_16x16x32_bf16(aq1, bk, sacc[1][tj], 0, 0, 0);
      }
    }

    // weight + write P (bf16) to per-wave LDS
#pragma unroll
    for (int tj = 0; tj < 4; ++tj) {
      const int m = mt * 64 + tj * 16 + l15;
      const float knv = kn_arr[bg * 1024 + m];
      const float my = (float)(m >> 5), mx = (float)(m & 31);
#pragma unroll
      for (int ti = 0; ti < 2; ++ti) {
#pragma unroll
        for (int r = 0; r < 4; ++r) {
          float dy = (nyf[ti][r] - my) * (1.f / 32.f);
          float dx = (nxf[ti][r] - mx) * (1.f / 32.f);
          float pb = __expf(-sf * (dy * dy + dx * dx));
          float wgt = __fdividef(sacc[ti][tj][r], qnv[ti][r] * knv + SMOOTH) * pb * qiv[ti][r];
          int nl = ti * 16 + 4 * h + r;
          int pidx = (nl * 64 + tj * 16 + l15) ^ ((nl & 7) << 3);
          sP[pidx] = f2bf(wgt);
        }
      }
    }
    // (same-wave LDS RAW: compiler inserts lgkmcnt)

    // O += P·V
#pragma unroll
    for (int km = 0; km < 2; ++km) {
      bf16x8 ap0 = ldfrag(sP, l15, km * 32 + col8);
      bf16x8 ap1 = ldfrag(sP, 16 + l15, km * 32 + col8);
#pragma unroll
      for (int dj = 0; dj < 4; ++dj) {
        bf16x8 bv = ldfrag(sV, dj * 16 + l15, km * 32 + col8);
        oacc[0][dj] = __builtin_amdgcn_mfma_f32_16x16x32_bf16(ap0, bv, oacc[0][dj], 0, 0, 0);
        oacc[1][dj] = __builtin_amdgcn_mfma_f32_16x16x32_bf16(ap1, bv, oacc[1][dj], 0, 0, 0);
      }
    }
  }

  __syncthreads();  // all waves done reading sK/sV
  u16* sO = sK;     // 128x64 spans sK+sV
#pragma unroll
  for (int ti = 0; ti < 2; ++ti)
#pragma unroll
    for (int dj = 0; dj < 4; ++dj)
#pragma unroll
      for (int r = 0; r < 4; ++r) {
        int nl = wv * 32 + ti * 16 + 4 * h + r;
        int idx = (nl * 64 + dj * 16 + l15) ^ ((nl & 7) << 3);
        sO[idx] = f2bf(oacc[ti][dj][r]);
      }
  __syncthreads();
  {
    const int row = tid >> 1, c = (tid & 1) * 4;
    us8* dst = reinterpret_cast<us8*>(aout + (bg * 1024 + (size_t)nb * 128 + row) * 64);
#pragma unroll
    for (int k = 0; k < 4; ++k) {
      int idx = (row * 64 + (c + k) * 8) ^ ((row & 7) << 3);
      dst[c + k] = *reinterpret_cast<const us8*>(sO + idx);
    }
  }
}

// ---------------------------------------------------------------------------
// 1x1 conv from aout [b][g][n][d] bf16: proj[b][c][n] fp32.
// block (b, 4 c), thread owns 4 n. grid = Bn*64 = 512.
// ---------------------------------------------------------------------------
__global__ __launch_bounds__(256) void conv1x1_kernel(
    const u16* __restrict__ aout, const float* __restrict__ wout,
    float* __restrict__ proj) {
  const int tid = threadIdx.x;
  const int cg = blockIdx.x & 63;
  const int b = blockIdx.x >> 6;
  const int c0 = cg * 4;
  __shared__ float ws[4 * INNER];
  for (int i = tid; i < 4 * INNER; i += 256)
    ws[i] = wout[(size_t)(c0 + (i >> 9)) * INNER + (i & 511)];
  __syncthreads();
  const int n0 = tid * 4;
  float acc[4][4] = {};
  for (int g8 = 0; g8 < 8; ++g8) {
    const u16* ag = aout + ((size_t)(b * G + g8) * 1024 + n0) * 64;
    const float* wsg0 = ws + 0 * INNER + g8 * 64;
    const float* wsg1 = ws + 1 * INNER + g8 * 64;
    const float* wsg2 = ws + 2 * INNER + g8 * 64;
    const float* wsg3 = ws + 3 * INNER + g8 * 64;
#pragma unroll
    for (int p = 0; p < 4; ++p) {
      const us8* arow = reinterpret_cast<const us8*>(ag + (size_t)p * 64);
#pragma unroll
      for (int d8 = 0; d8 < 8; ++d8) {
        us8 v = arow[d8];
#pragma unroll
        for (int j = 0; j < 8; ++j) {
          float a = bf2f(v[j]);
          int i = d8 * 8 + j;
          acc[0][p] += wsg0[i] * a;
          acc[1][p] += wsg1[i] * a;
          acc[2][p] += wsg2[i] * a;
          acc[3][p] += wsg3[i] * a;
        }
      }
    }
  }
#pragma unroll
  for (int c = 0; c < 4; ++c) {
    float4 t = make_float4(acc[c][0], acc[c][1], acc[c][2], acc[c][3]);
    *reinterpret_cast<float4*>(proj + ((size_t)b * Cc + c0 + c) * Nn + n0) = t;
  }
}

// ---------------------------------------------------------------------------
__global__ __launch_bounds__(256) void bn_stats_kernel(
    const float* __restrict__ proj, float* __restrict__ stats) {
  const int c = blockIdx.x;
  const int tid = threadIdx.x;
  float s = 0.f, s2 = 0.f;
  for (int b = 0; b < Bn; ++b) {
    float4 v = reinterpret_cast<const float4*>(proj + ((size_t)b * Cc + c) * Nn)[tid];
    s += v.x + v.y + v.z + v.w;
    s2 += v.x * v.x + v.y * v.y + v.z * v.z + v.w * v.w;
  }
  s = waveSum(s);
  s2 = waveSum(s2);
  __shared__ float r1[4], r2[4];
  if ((tid & 63) == 0) { r1[tid >> 6] = s; r2[tid >> 6] = s2; }
  __syncthreads();
  if (tid == 0) {
    float S = r1[0] + r1[1] + r1[2] + r1[3];
    float S2 = r2[0] + r2[1] + r2[2] + r2[3];
    const float invM = 1.f / (float)(Bn * Nn);
    float mean = S * invM;
    float var = S2 * invM - mean * mean;
    stats[c] = mean;
    stats[Cc + c] = rsqrtf(var + BN_EPS);
  }
}

__global__ __launch_bounds__(256) void bn_apply_kernel(
    const float* __restrict__ proj, const float* __restrict__ stats,
    const float* __restrict__ gamma, const float* __restrict__ beta,
    float* __restrict__ out) {
  const int idx = blockIdx.x * 256 + threadIdx.x;
  const int flat = idx << 2;
  const int c = (flat >> 10) & (Cc - 1);
  float4 v = reinterpret_cast<const float4*>(proj)[idx];
  const float mean = stats[c];
  const float sc = stats[Cc + c] * gamma[c];
  const float sh = beta[c];
  float4 o;
  o.x = fmaxf((v.x - mean) * sc + sh, 0.f);
  o.y = fmaxf((v.y - mean) * sc + sh, 0.f);
  o.z = fmaxf((v.z - mean) * sc + sh, 0.f);
  o.w = fmaxf((v.w - mean) * sc + sh, 0.f);
  reinterpret_cast<float4*>(out)[idx] = o;
}

// ---------------------------------------------------------------------------
extern "C" void kernel_launch(void* const* d_in, const int* in_sizes, int n_in,
                              void* d_out, int out_size, void* d_ws, size_t ws_size,
                              hipStream_t stream) {
  const float* x = (const float*)d_in[0];
  const float* w_qkv = (const float*)d_in[1];
  const float* head_scale = (const float*)d_in[2];
  const float* w_out = (const float*)d_in[3];
  const float* gamma = (const float*)d_in[4];
  const float* beta = (const float*)d_in[5];
  float* out = (float*)d_out;

  char* w = (char*)d_ws;
  u16* qt = (u16*)w; w += 8388608;
  u16* kt = (u16*)w; w += 8388608;
  u16* vt = (u16*)w; w += 8388608;
  u16* aout = (u16*)w; w += 8388608;
  float* qn = (float*)w; w += 262144;
  float* kn = (float*)w; w += 262144;
  float* denom = (float*)w; w += 32768;
  float* stats = (float*)w; w += 2048;
  float* proj = (float*)w; w += 8388608;

  conv3x3_kernel<<<dim3(Bn * (OC / 8)), dim3(256), 0, stream>>>(x, w_qkv, qt, kt, vt);
  pbdenom_kernel<<<dim3(G * Nn), dim3(256), 0, stream>>>(head_scale, denom);
  norms_kernel<<<dim3(2048), dim3(256), 0, stream>>>(qt, kt, qn, kn);
  attn_mfma_kernel<<<dim3(512), dim3(256), 0, stream>>>(qt, kt, vt, qn, kn, denom, head_scale, aout);
  conv1x1_kernel<<<dim3(512), dim3(256), 0, stream>>>(aout, w_out, proj);
  bn_stats_kernel<<<dim3(Cc), dim3(256), 0, stream>>>(proj, stats);
  bn_apply_kernel<<<dim3((Bn * Cc * Nn / 4) / 256), dim3(256), 0, stream>>>(proj, stats, gamma, beta, out);
}

// Round 3
// 368.217 us; speedup vs baseline: 6.2516x; 2.5084x over previous
//
#include <hip/hip_runtime.h>
#include <math.h>

#define SMOOTH 1e-4f
#define BN_EPS 1e-5f

constexpr int Bn = 8;
constexpr int Cc = 256;
constexpr int Nn = 1024;   // H*W
constexpr int G = 8;       // heads
constexpr int INNER = 512;
constexpr int OC = 1536;   // 3*INNER
constexpr int KK = 2304;   // 9*256 im2col K

typedef unsigned short u16;
typedef __bf16 bf16x8 __attribute__((ext_vector_type(8)));
typedef float f32x4 __attribute__((ext_vector_type(4)));
typedef unsigned short us8 __attribute__((ext_vector_type(8)));
typedef unsigned short us4 __attribute__((ext_vector_type(4)));

__device__ __forceinline__ u16 f2bf(float f) {
  unsigned int u = __float_as_uint(f);
  unsigned int r = (u + 0x7fffu + ((u >> 16) & 1u)) >> 16;
  return (u16)r;
}
__device__ __forceinline__ float bf2f(u16 u) {
  return __uint_as_float(((unsigned int)u) << 16);
}

__device__ __forceinline__ float waveSum(float v) {
#pragma unroll
  for (int off = 32; off > 0; off >>= 1) v += __shfl_xor(v, off, 64);
  return v;
}

__device__ __forceinline__ void gl16(const u16* g, u16* l) {
  __builtin_amdgcn_global_load_lds(
      (const __attribute__((address_space(1))) unsigned int*)g,
      (__attribute__((address_space(3))) unsigned int*)l, 16, 0, 0);
}

// swizzled LDS fragment read (attn): rows of 64 u16, byte ^ ((row&7)<<4)
__device__ __forceinline__ bf16x8 ldfrag(const u16* base, int row, int col) {
  int idx = (row * 64 + col) ^ ((row & 7) << 3);
  return __builtin_bit_cast(bf16x8, *reinterpret_cast<const us8*>(base + idx));
}

// ---------------------------------------------------------------------------
// weight repack: wA[oc][tap*256+ic] = bf16(w_qkv[oc][ic*9+tap]). grid = 1536.
// ---------------------------------------------------------------------------
__global__ __launch_bounds__(256) void wconv_kernel(
    const float* __restrict__ wq, u16* __restrict__ wA) {
  const int oc = blockIdx.x;
  const int tid = threadIdx.x;
  __shared__ float sw[KK];
  for (int i = tid; i < KK; i += 256) sw[i] = wq[(size_t)oc * KK + i];
  __syncthreads();
#pragma unroll
  for (int j = 0; j < 2; ++j) {
    int c8 = tid + j * 256;
    if (c8 < KK / 8) {
      us8 v;
#pragma unroll
      for (int e = 0; e < 8; ++e) {
        int k = c8 * 8 + e;
        int tap = k >> 8, ic = k & 255;
        v[e] = f2bf(sw[ic * 9 + tap]);
      }
      *reinterpret_cast<us8*>(wA + (size_t)oc * KK + c8 * 8) = v;
    }
  }
}

// ---------------------------------------------------------------------------
// fused transpose + im2col: B2[pix][tap*256+ic] = bf16 x[b][ic][shift(pix,tap)]
// block = (b, 2 image rows). LDS: 4 src rows x 32 px transposed to [pos][ic].
// grid = 8*16 = 128.
// ---------------------------------------------------------------------------
__global__ __launch_bounds__(256) void im2col_kernel(
    const float* __restrict__ x, u16* __restrict__ B2) {
  const int tid = threadIdx.x;
  const int b = blockIdx.x >> 4;
  const int y0 = (blockIdx.x & 15) * 2;

  __shared__ u16 sxt[128 * 258];  // [pos 0..127][ic 0..255], stride 258 (odd banks)

  {  // stage: pos = row-major 4 rows (y0-1..y0+2) x 32 cols
    const int pos = tid & 127;
    const int ichalf = tid >> 7;
    const int gidx = (y0 - 1) * 32 + pos;
    const bool valid = (gidx >= 0) && (gidx < 1024);
    const float* xb = x + (size_t)b * Cc * Nn;
    for (int ic2 = 0; ic2 < 128; ++ic2) {
      int ic = ichalf * 128 + ic2;
      float v = valid ? xb[(size_t)ic * Nn + gidx] : 0.f;
      sxt[pos * 258 + ic] = f2bf(v);
    }
  }
  __syncthreads();

  const int c16 = tid & 31;  // 16B chunk within 512B row
  const int pl0 = tid >> 5;  // 0..7
  const us8 zero = {0, 0, 0, 0, 0, 0, 0, 0};
#pragma unroll
  for (int tap = 0; tap < 9; ++tap) {
    const int dy = tap / 3 - 1, dx = tap % 3 - 1;
#pragma unroll
    for (int it = 0; it < 8; ++it) {
      int pixloc = pl0 + it * 8;        // 0..63
      int yl = pixloc >> 5, xx = pixloc & 31;
      int sxx = xx + dx;
      int gy = y0 + yl + dy;
      bool v = (sxx >= 0) && (sxx < 32) && (gy >= 0) && (gy < 32);
      int spos = (yl + dy + 1) * 32 + sxx;
      us8 val = v ? *reinterpret_cast<const us8*>(sxt + spos * 258 + c16 * 8) : zero;
      size_t pix = (size_t)b * 1024 + (y0 + yl) * 32 + xx;
      *reinterpret_cast<us8*>(B2 + pix * KK + tap * 256 + c16 * 8) = val;
    }
  }
}

// ---------------------------------------------------------------------------
// qkv implicit GEMM: C[oc][pix] = sum_k wA[oc][k]*B2[pix][k].
// 128x128 tile, BK=64, 4 waves (2x2), global_load_lds staging, m97 structure.
// Epilogue scatters into qt/kt [b,g,n,d] and vt [b,g,d,n] (bf16).
// grid = 12 * 64 = 768.
// ---------------------------------------------------------------------------
__global__ __launch_bounds__(256, 2) void qkv_gemm_kernel(
    const u16* __restrict__ wA, const u16* __restrict__ B2,
    u16* __restrict__ qt, u16* __restrict__ kt, u16* __restrict__ vt) {
  const int tid = threadIdx.x;
  const int lane = tid & 63;
  const int wv = tid >> 6;
  const int wr = wv >> 1, wc = wv & 1;
  const int h = lane >> 4, l15 = lane & 15;
  const int bm = blockIdx.x % 12;
  const int bn = blockIdx.x / 12;
  const int m0 = bm * 128;
  const int n0 = bn * 128;

  __shared__ __align__(16) u16 sA[128 * 64];  // 16 KB
  __shared__ __align__(16) u16 sB[128 * 64];  // 16 KB

  f32x4 acc[4][4];
#pragma unroll
  for (int i = 0; i < 4; ++i)
#pragma unroll
    for (int j = 0; j < 4; ++j) acc[i][j] = (f32x4){0.f, 0.f, 0.f, 0.f};

  const int srow = (wv << 3) + (lane >> 3);  // 0..31
  const int scol = (lane & 7) << 3;          // u16 units
  const u16* gA = wA + (size_t)(m0 + srow) * KK + scol;
  const u16* gB = B2 + (size_t)(n0 + srow) * KK + scol;
  u16* lA = sA + wv * 512;  // wave-uniform LDS base (1KB per wave)
  u16* lB = sB + wv * 512;

  for (int ks = 0; ks < KK / 64; ++ks) {
    __syncthreads();
#pragma unroll
    for (int it = 0; it < 4; ++it) {
      gl16(gA + (size_t)it * 32 * KK, lA + it * 2048);
      gl16(gB + (size_t)it * 32 * KK, lB + it * 2048);
    }
    gA += 64;
    gB += 64;
    __syncthreads();
#pragma unroll
    for (int kk = 0; kk < 2; ++kk) {
      bf16x8 af[4], bv[4];
#pragma unroll
      for (int mt = 0; mt < 4; ++mt)
        af[mt] = __builtin_bit_cast(bf16x8, *reinterpret_cast<const us8*>(
            sA + (wr * 64 + mt * 16 + l15) * 64 + kk * 32 + h * 8));
#pragma unroll
      for (int nt = 0; nt < 4; ++nt)
        bv[nt] = __builtin_bit_cast(bf16x8, *reinterpret_cast<const us8*>(
            sB + (wc * 64 + nt * 16 + l15) * 64 + kk * 32 + h * 8));
#pragma unroll
      for (int mt = 0; mt < 4; ++mt)
#pragma unroll
        for (int nt = 0; nt < 4; ++nt)
          acc[mt][nt] = __builtin_amdgcn_mfma_f32_16x16x32_bf16(af[mt], bv[nt], acc[mt][nt], 0, 0, 0);
    }
  }

  // epilogue: sec 0=q 1=k 2=v; g and b are block-uniform
  const int sec = bm >> 2;
  const int g = (bm & 3) * 2 + wr;
  const int b = bn >> 3;
  const size_t bg = (size_t)b * G + g;
  if (sec < 2) {
    u16* base = (sec ? kt : qt) + bg * 65536;
#pragma unroll
    for (int nt = 0; nt < 4; ++nt) {
      const int n = (bn & 7) * 128 + wc * 64 + nt * 16 + l15;
#pragma unroll
      for (int mt = 0; mt < 4; ++mt) {
        us4 v;
        v[0] = f2bf(acc[mt][nt][0]); v[1] = f2bf(acc[mt][nt][1]);
        v[2] = f2bf(acc[mt][nt][2]); v[3] = f2bf(acc[mt][nt][3]);
        *reinterpret_cast<us4*>(base + (size_t)n * 64 + mt * 16 + 4 * h) = v;
      }
    }
  } else {
    u16* base = vt + bg * 65536;
#pragma unroll
    for (int nt = 0; nt < 4; ++nt) {
      const int n = (bn & 7) * 128 + wc * 64 + nt * 16 + l15;
#pragma unroll
      for (int mt = 0; mt < 4; ++mt)
#pragma unroll
        for (int r = 0; r < 4; ++r)
          base[(size_t)(mt * 16 + 4 * h + r) * 1024 + n] = f2bf(acc[mt][nt][r]);
    }
  }
}

// ---------------------------------------------------------------------------
// positional-bias row sums: denom[g][n] = sum_m exp(-sf_g * dis(n,m))
// ---------------------------------------------------------------------------
__global__ __launch_bounds__(256) void pbdenom_kernel(
    const float* __restrict__ head_scale, float* __restrict__ denom) {
  const int tid = threadIdx.x;
  const int g = blockIdx.x >> 10;
  const int n = blockIdx.x & 1023;
  const float hs = head_scale[g];
  const float sg = 1.f / (1.f + __expf(-hs));
  const float s = sg * (0.4f - 0.003f) + 0.003f;
  const float sf = 1.f / (2.f * s * s);
  const float yn = (float)(n >> 5), xn = (float)(n & 31);
  float sum = 0.f;
#pragma unroll
  for (int j = 0; j < 4; ++j) {
    int m = tid + (j << 8);
    float dy = (yn - (float)(m >> 5)) * (1.f / 32.f);
    float dx = (xn - (float)(m & 31)) * (1.f / 32.f);
    sum += __expf(-sf * (dy * dy + dx * dx));
  }
  float tot = waveSum(sum);
  __shared__ float red[4];
  if ((tid & 63) == 0) red[tid >> 6] = tot;
  __syncthreads();
  if (tid == 0) denom[blockIdx.x] = red[0] + red[1] + red[2] + red[3];
}

// ---------------------------------------------------------------------------
// q/k row norms from bf16 tensors. grid = 2048 blocks of 256.
// ---------------------------------------------------------------------------
__global__ __launch_bounds__(256) void norms_kernel(
    const u16* __restrict__ qt, const u16* __restrict__ kt,
    float* __restrict__ qn, float* __restrict__ kn) {
  const int idx = blockIdx.x * 64 + (threadIdx.x >> 2);
  const int sub = threadIdx.x & 3;
  const int sel = idx >> 16;
  const int row = idx & 65535;
  const u16* src = (sel ? kt : qt) + (size_t)row * 64 + sub * 16;
  float s = 0.f;
#pragma unroll
  for (int k = 0; k < 2; ++k) {
    us8 v = reinterpret_cast<const us8*>(src)[k];
#pragma unroll
    for (int j = 0; j < 8; ++j) {
      float f = bf2f(v[j]);
      s += f * f;
    }
  }
  s += __shfl_xor(s, 1, 64);
  s += __shfl_xor(s, 2, 64);
  if (sub == 0) (sel ? kn : qn)[row] = sqrtf(s + SMOOTH);
}

// ---------------------------------------------------------------------------
// MFMA attention. block = 256 thr (4 waves), (b, g, 128 q-rows). grid = 512.
// ---------------------------------------------------------------------------
__global__ __launch_bounds__(256, 2) void attn_mfma_kernel(
    const u16* __restrict__ qt, const u16* __restrict__ kt,
    const u16* __restrict__ vt, const float* __restrict__ qn_arr,
    const float* __restrict__ kn_arr, const float* __restrict__ denom,
    const float* __restrict__ head_scale, u16* __restrict__ aout) {
  const int tid = threadIdx.x;
  const int lane = tid & 63;
  const int wv = tid >> 6;
  const int h = lane >> 4;
  const int l15 = lane & 15;
  const int nb = blockIdx.x & 7;
  const int g = (blockIdx.x >> 3) & 7;
  const int b = blockIdx.x >> 6;

  __shared__ __align__(16) u16 smem[24576];  // 48KB
  u16* sQ = smem;                            // 128x64
  u16* sK = smem + 8192;                     // 64x64
  u16* sV = smem + 12288;                    // 64x64
  u16* sP = smem + 16384 + wv * 2048;        // per-wave 32x64

  const size_t bg = (size_t)b * G + g;
  const u16* qg = qt + bg * 65536;
  const u16* kg = kt + bg * 65536;
  const u16* vg = vt + bg * 65536;  // [64][1024]

  {
    const int row = tid >> 1, c = (tid & 1) * 4;
    const us8* src = reinterpret_cast<const us8*>(qg + (size_t)(nb * 128 + row) * 64);
#pragma unroll
    for (int k = 0; k < 4; ++k) {
      int idx = (row * 64 + (c + k) * 8) ^ ((row & 7) << 3);
      *reinterpret_cast<us8*>(sQ + idx) = src[c + k];
    }
  }

  const float hs = head_scale[g];
  const float sg = 1.f / (1.f + __expf(-hs));
  const float sv = sg * (0.4f - 0.003f) + 0.003f;
  const float sf = 1.f / (2.f * sv * sv);

  float qnv[2][4], qiv[2][4], nyf[2][4], nxf[2][4];
#pragma unroll
  for (int ti = 0; ti < 2; ++ti)
#pragma unroll
    for (int r = 0; r < 4; ++r) {
      int n = nb * 128 + wv * 32 + ti * 16 + 4 * h + r;
      qnv[ti][r] = qn_arr[bg * 1024 + n];
      qiv[ti][r] = 1.f / denom[g * 1024 + n];
      nyf[ti][r] = (float)(n >> 5);
      nxf[ti][r] = (float)(n & 31);
    }

  f32x4 oacc[2][4];
#pragma unroll
  for (int ti = 0; ti < 2; ++ti)
#pragma unroll
    for (int dj = 0; dj < 4; ++dj) oacc[ti][dj] = (f32x4){0.f, 0.f, 0.f, 0.f};

  const int col8 = h * 8;

  for (int mt = 0; mt < 16; ++mt) {
    __syncthreads();
    {
      const int row = tid >> 2, cc = (tid & 3) * 2;
      const us8* ksrc = reinterpret_cast<const us8*>(kg + (size_t)(mt * 64 + row) * 64);
      const us8* vsrc = reinterpret_cast<const us8*>(vg + (size_t)row * 1024 + mt * 64);
#pragma unroll
      for (int k = 0; k < 2; ++k) {
        int idx = (row * 64 + (cc + k) * 8) ^ ((row & 7) << 3);
        *reinterpret_cast<us8*>(sK + idx) = ksrc[cc + k];
        *reinterpret_cast<us8*>(sV + idx) = vsrc[cc + k];
      }
    }
    __syncthreads();

    f32x4 sacc[2][4];
#pragma unroll
    for (int ti = 0; ti < 2; ++ti)
#pragma unroll
      for (int tj = 0; tj < 4; ++tj) sacc[ti][tj] = (f32x4){0.f, 0.f, 0.f, 0.f};
#pragma unroll
    for (int kk = 0; kk < 2; ++kk) {
      bf16x8 aq0 = ldfrag(sQ, wv * 32 + l15, kk * 32 + col8);
      bf16x8 aq1 = ldfrag(sQ, wv * 32 + 16 + l15, kk * 32 + col8);
#pragma unroll
      for (int tj = 0; tj < 4; ++tj) {
        bf16x8 bk = ldfrag(sK, tj * 16 + l15, kk * 32 + col8);
        sacc[0][tj] = __builtin_amdgcn_mfma_f32_16x16x32_bf16(aq0, bk, sacc[0][tj], 0, 0, 0);
        sacc[1][tj] = __builtin_amdgcn_mfma_f32_16x16x32_bf16(aq1, bk, sacc[1][tj], 0, 0, 0);
      }
    }

#pragma unroll
    for (int tj = 0; tj < 4; ++tj) {
      const int m = mt * 64 + tj * 16 + l15;
      const float knv = kn_arr[bg * 1024 + m];
      const float my = (float)(m >> 5), mx = (float)(m & 31);
#pragma unroll
      for (int ti = 0; ti < 2; ++ti) {
#pragma unroll
        for (int r = 0; r < 4; ++r) {
          float dy = (nyf[ti][r] - my) * (1.f / 32.f);
          float dx = (nxf[ti][r] - mx) * (1.f / 32.f);
          float pb = __expf(-sf * (dy * dy + dx * dx));
          float wgt = __fdividef(sacc[ti][tj][r], qnv[ti][r] * knv + SMOOTH) * pb * qiv[ti][r];
          int nl = ti * 16 + 4 * h + r;
          int pidx = (nl * 64 + tj * 16 + l15) ^ ((nl & 7) << 3);
          sP[pidx] = f2bf(wgt);
        }
      }
    }

#pragma unroll
    for (int km = 0; km < 2; ++km) {
      bf16x8 ap0 = ldfrag(sP, l15, km * 32 + col8);
      bf16x8 ap1 = ldfrag(sP, 16 + l15, km * 32 + col8);
#pragma unroll
      for (int dj = 0; dj < 4; ++dj) {
        bf16x8 bvv = ldfrag(sV, dj * 16 + l15, km * 32 + col8);
        oacc[0][dj] = __builtin_amdgcn_mfma_f32_16x16x32_bf16(ap0, bvv, oacc[0][dj], 0, 0, 0);
        oacc[1][dj] = __builtin_amdgcn_mfma_f32_16x16x32_bf16(ap1, bvv, oacc[1][dj], 0, 0, 0);
      }
    }
  }

  __syncthreads();
  u16* sO = sK;
#pragma unroll
  for (int ti = 0; ti < 2; ++ti)
#pragma unroll
    for (int dj = 0; dj < 4; ++dj)
#pragma unroll
      for (int r = 0; r < 4; ++r) {
        int nl = wv * 32 + ti * 16 + 4 * h + r;
        int idx = (nl * 64 + dj * 16 + l15) ^ ((nl & 7) << 3);
        sO[idx] = f2bf(oacc[ti][dj][r]);
      }
  __syncthreads();
  {
    const int row = tid >> 1, c = (tid & 1) * 4;
    us8* dst = reinterpret_cast<us8*>(aout + (bg * 1024 + (size_t)nb * 128 + row) * 64);
#pragma unroll
    for (int k = 0; k < 4; ++k) {
      int idx = (row * 64 + (c + k) * 8) ^ ((row & 7) << 3);
      dst[c + k] = *reinterpret_cast<const us8*>(sO + idx);
    }
  }
}

// ---------------------------------------------------------------------------
// 1x1 conv from aout [b][g][n][d] bf16: proj[b][c][n] fp32. grid = 512.
// ---------------------------------------------------------------------------
__global__ __launch_bounds__(256) void conv1x1_kernel(
    const u16* __restrict__ aout, const float* __restrict__ wout,
    float* __restrict__ proj) {
  const int tid = threadIdx.x;
  const int cg = blockIdx.x & 63;
  const int b = blockIdx.x >> 6;
  const int c0 = cg * 4;
  __shared__ float ws[4 * INNER];
  for (int i = tid; i < 4 * INNER; i += 256)
    ws[i] = wout[(size_t)(c0 + (i >> 9)) * INNER + (i & 511)];
  __syncthreads();
  const int n0 = tid * 4;
  float acc[4][4] = {};
  for (int g8 = 0; g8 < 8; ++g8) {
    const u16* ag = aout + ((size_t)(b * G + g8) * 1024 + n0) * 64;
    const float* wsg0 = ws + 0 * INNER + g8 * 64;
    const float* wsg1 = ws + 1 * INNER + g8 * 64;
    const float* wsg2 = ws + 2 * INNER + g8 * 64;
    const float* wsg3 = ws + 3 * INNER + g8 * 64;
#pragma unroll
    for (int p = 0; p < 4; ++p) {
      const us8* arow = reinterpret_cast<const us8*>(ag + (size_t)p * 64);
#pragma unroll
      for (int d8 = 0; d8 < 8; ++d8) {
        us8 v = arow[d8];
#pragma unroll
        for (int j = 0; j < 8; ++j) {
          float a = bf2f(v[j]);
          int i = d8 * 8 + j;
          acc[0][p] += wsg0[i] * a;
          acc[1][p] += wsg1[i] * a;
          acc[2][p] += wsg2[i] * a;
          acc[3][p] += wsg3[i] * a;
        }
      }
    }
  }
#pragma unroll
  for (int c = 0; c < 4; ++c) {
    float4 t = make_float4(acc[c][0], acc[c][1], acc[c][2], acc[c][3]);
    *reinterpret_cast<float4*>(proj + ((size_t)b * Cc + c0 + c) * Nn + n0) = t;
  }
}

// ---------------------------------------------------------------------------
__global__ __launch_bounds__(256) void bn_stats_kernel(
    const float* __restrict__ proj, float* __restrict__ stats) {
  const int c = blockIdx.x;
  const int tid = threadIdx.x;
  float s = 0.f, s2 = 0.f;
  for (int b = 0; b < Bn; ++b) {
    float4 v = reinterpret_cast<const float4*>(proj + ((size_t)b * Cc + c) * Nn)[tid];
    s += v.x + v.y + v.z + v.w;
    s2 += v.x * v.x + v.y * v.y + v.z * v.z + v.w * v.w;
  }
  s = waveSum(s);
  s2 = waveSum(s2);
  __shared__ float r1[4], r2[4];
  if ((tid & 63) == 0) { r1[tid >> 6] = s; r2[tid >> 6] = s2; }
  __syncthreads();
  if (tid == 0) {
    float S = r1[0] + r1[1] + r1[2] + r1[3];
    float S2 = r2[0] + r2[1] + r2[2] + r2[3];
    const float invM = 1.f / (float)(Bn * Nn);
    float mean = S * invM;
    float var = S2 * invM - mean * mean;
    stats[c] = mean;
    stats[Cc + c] = rsqrtf(var + BN_EPS);
  }
}

__global__ __launch_bounds__(256) void bn_apply_kernel(
    const float* __restrict__ proj, const float* __restrict__ stats,
    const float* __restrict__ gamma, const float* __restrict__ beta,
    float* __restrict__ out) {
  const int idx = blockIdx.x * 256 + threadIdx.x;
  const int flat = idx << 2;
  const int c = (flat >> 10) & (Cc - 1);
  float4 v = reinterpret_cast<const float4*>(proj)[idx];
  const float mean = stats[c];
  const float sc = stats[Cc + c] * gamma[c];
  const float sh = beta[c];
  float4 o;
  o.x = fmaxf((v.x - mean) * sc + sh, 0.f);
  o.y = fmaxf((v.y - mean) * sc + sh, 0.f);
  o.z = fmaxf((v.z - mean) * sc + sh, 0.f);
  o.w = fmaxf((v.w - mean) * sc + sh, 0.f);
  reinterpret_cast<float4*>(out)[idx] = o;
}

// ---------------------------------------------------------------------------
extern "C" void kernel_launch(void* const* d_in, const int* in_sizes, int n_in,
                              void* d_out, int out_size, void* d_ws, size_t ws_size,
                              hipStream_t stream) {
  const float* x = (const float*)d_in[0];
  const float* w_qkv = (const float*)d_in[1];
  const float* head_scale = (const float*)d_in[2];
  const float* w_out = (const float*)d_in[3];
  const float* gamma = (const float*)d_in[4];
  const float* beta = (const float*)d_in[5];
  float* out = (float*)d_out;

  char* w = (char*)d_ws;
  u16* qt = (u16*)(w + 0);                 // 8 MB
  u16* kt = (u16*)(w + 8388608);           // 8 MB
  u16* vt = (u16*)(w + 16777216);          // 8 MB
  u16* wA = (u16*)(w + 25165824);          // 7,077,888 B (dead after GEMM)
  u16* aout = (u16*)(w + 25165824);        // 8 MB (written post-GEMM, by attn)
  u16* B2 = (u16*)(w + 33554432);          // 37,748,736 B (dead after GEMM)
  float* proj = (float*)(w + 33554432);    // 8 MB reuse of B2 head
  float* qn = (float*)(w + 71303168);      // 262144 B
  float* kn = (float*)(w + 71565312);      // 262144 B
  float* denom = (float*)(w + 71827456);   // 32768 B
  float* stats = (float*)(w + 71860224);   // 2048 B

  wconv_kernel<<<dim3(OC), dim3(256), 0, stream>>>(w_qkv, wA);
  im2col_kernel<<<dim3(128), dim3(256), 0, stream>>>(x, B2);
  pbdenom_kernel<<<dim3(G * Nn), dim3(256), 0, stream>>>(head_scale, denom);
  qkv_gemm_kernel<<<dim3(768), dim3(256), 0, stream>>>(wA, B2, qt, kt, vt);
  norms_kernel<<<dim3(2048), dim3(256), 0, stream>>>(qt, kt, qn, kn);
  attn_mfma_kernel<<<dim3(512), dim3(256), 0, stream>>>(qt, kt, vt, qn, kn, denom, head_scale, aout);
  conv1x1_kernel<<<dim3(512), dim3(256), 0, stream>>>(aout, w_out, proj);
  bn_stats_kernel<<<dim3(Cc), dim3(256), 0, stream>>>(proj, stats);
  bn_apply_kernel<<<dim3((Bn * Cc * Nn / 4) / 256), dim3(256), 0, stream>>>(proj, stats, gamma, beta, out);
}

// Round 4
// 219.998 us; speedup vs baseline: 10.4635x; 1.6737x over previous
//
#include <hip/hip_runtime.h>
#include <math.h>

#define SMOOTH 1e-4f
#define BN_EPS 1e-5f

constexpr int Bn = 8;
constexpr int Cc = 256;
constexpr int Nn = 1024;   // H*W
constexpr int G = 8;       // heads
constexpr int INNER = 512;
constexpr int OC = 1536;   // 3*INNER
constexpr int KK = 2304;   // 9*256 im2col K

typedef unsigned short u16;
typedef __bf16 bf16x8 __attribute__((ext_vector_type(8)));
typedef float f32x4 __attribute__((ext_vector_type(4)));
typedef unsigned short us8 __attribute__((ext_vector_type(8)));
typedef unsigned short us4 __attribute__((ext_vector_type(4)));

__device__ __forceinline__ u16 f2bf(float f) {
  unsigned int u = __float_as_uint(f);
  unsigned int r = (u + 0x7fffu + ((u >> 16) & 1u)) >> 16;
  return (u16)r;
}
__device__ __forceinline__ float bf2f(u16 u) {
  return __uint_as_float(((unsigned int)u) << 16);
}

__device__ __forceinline__ float waveSum(float v) {
#pragma unroll
  for (int off = 32; off > 0; off >>= 1) v += __shfl_xor(v, off, 64);
  return v;
}

__device__ __forceinline__ void gl16(const u16* g, u16* l) {
  __builtin_amdgcn_global_load_lds(
      (const __attribute__((address_space(1))) unsigned int*)g,
      (__attribute__((address_space(3))) unsigned int*)l, 16, 0, 0);
}

// swizzled LDS fragment read (attn): rows of 64 u16, byte ^ ((row&7)<<4)
__device__ __forceinline__ bf16x8 ldfrag(const u16* base, int row, int col) {
  int idx = (row * 64 + col) ^ ((row & 7) << 3);
  return __builtin_bit_cast(bf16x8, *reinterpret_cast<const us8*>(base + idx));
}

// ---------------------------------------------------------------------------
// weight repack: wA[oc][tap*256+ic] = bf16(w_qkv[oc][ic*9+tap]). grid = 1536.
// ---------------------------------------------------------------------------
__global__ __launch_bounds__(256) void wconv_kernel(
    const float* __restrict__ wq, u16* __restrict__ wA) {
  const int oc = blockIdx.x;
  const int tid = threadIdx.x;
  __shared__ float sw[KK];
  for (int i = tid; i < KK; i += 256) sw[i] = wq[(size_t)oc * KK + i];
  __syncthreads();
#pragma unroll
  for (int j = 0; j < 2; ++j) {
    int c8 = tid + j * 256;
    if (c8 < KK / 8) {
      us8 v;
#pragma unroll
      for (int e = 0; e < 8; ++e) {
        int k = c8 * 8 + e;
        int tap = k >> 8, ic = k & 255;
        v[e] = f2bf(sw[ic * 9 + tap]);
      }
      *reinterpret_cast<us8*>(wA + (size_t)oc * KK + c8 * 8) = v;
    }
  }
}

// ---------------------------------------------------------------------------
// w_out -> bf16 repack: wB[c][i] = bf16(w_out[c][i]). 131072 elems.
// grid = 64 blocks of 256, us8 chunks.
// ---------------------------------------------------------------------------
__global__ __launch_bounds__(256) void wout_repack_kernel(
    const float* __restrict__ wout, u16* __restrict__ wB) {
  const int idx = blockIdx.x * 256 + threadIdx.x;  // us8 chunk
  const float4 a = reinterpret_cast<const float4*>(wout)[idx * 2];
  const float4 b = reinterpret_cast<const float4*>(wout)[idx * 2 + 1];
  us8 v;
  v[0] = f2bf(a.x); v[1] = f2bf(a.y); v[2] = f2bf(a.z); v[3] = f2bf(a.w);
  v[4] = f2bf(b.x); v[5] = f2bf(b.y); v[6] = f2bf(b.z); v[7] = f2bf(b.w);
  reinterpret_cast<us8*>(wB)[idx] = v;
}

// ---------------------------------------------------------------------------
// fused transpose + im2col: B2[pix][tap*256+ic] = bf16 x[b][ic][shift(pix,tap)]
// ---------------------------------------------------------------------------
__global__ __launch_bounds__(256) void im2col_kernel(
    const float* __restrict__ x, u16* __restrict__ B2) {
  const int tid = threadIdx.x;
  const int b = blockIdx.x >> 4;
  const int y0 = (blockIdx.x & 15) * 2;

  __shared__ u16 sxt[128 * 258];

  {
    const int pos = tid & 127;
    const int ichalf = tid >> 7;
    const int gidx = (y0 - 1) * 32 + pos;
    const bool valid = (gidx >= 0) && (gidx < 1024);
    const float* xb = x + (size_t)b * Cc * Nn;
    for (int ic2 = 0; ic2 < 128; ++ic2) {
      int ic = ichalf * 128 + ic2;
      float v = valid ? xb[(size_t)ic * Nn + gidx] : 0.f;
      sxt[pos * 258 + ic] = f2bf(v);
    }
  }
  __syncthreads();

  const int c16 = tid & 31;
  const int pl0 = tid >> 5;
  const us8 zero = {0, 0, 0, 0, 0, 0, 0, 0};
#pragma unroll
  for (int tap = 0; tap < 9; ++tap) {
    const int dy = tap / 3 - 1, dx = tap % 3 - 1;
#pragma unroll
    for (int it = 0; it < 8; ++it) {
      int pixloc = pl0 + it * 8;
      int yl = pixloc >> 5, xx = pixloc & 31;
      int sxx = xx + dx;
      int gy = y0 + yl + dy;
      bool v = (sxx >= 0) && (sxx < 32) && (gy >= 0) && (gy < 32);
      int spos = (yl + dy + 1) * 32 + sxx;
      us8 val = v ? *reinterpret_cast<const us8*>(sxt + spos * 258 + c16 * 8) : zero;
      size_t pix = (size_t)b * 1024 + (y0 + yl) * 32 + xx;
      *reinterpret_cast<us8*>(B2 + pix * KK + tap * 256 + c16 * 8) = val;
    }
  }
}

// ---------------------------------------------------------------------------
// qkv implicit GEMM: 128x128 tile, BK=64, 4 waves, global_load_lds staging.
// grid = 12 * 64 = 768.
// ---------------------------------------------------------------------------
__global__ __launch_bounds__(256, 2) void qkv_gemm_kernel(
    const u16* __restrict__ wA, const u16* __restrict__ B2,
    u16* __restrict__ qt, u16* __restrict__ kt, u16* __restrict__ vt) {
  const int tid = threadIdx.x;
  const int lane = tid & 63;
  const int wv = tid >> 6;
  const int wr = wv >> 1, wc = wv & 1;
  const int h = lane >> 4, l15 = lane & 15;
  const int bm = blockIdx.x % 12;
  const int bn = blockIdx.x / 12;
  const int m0 = bm * 128;
  const int n0 = bn * 128;

  __shared__ __align__(16) u16 sA[128 * 64];
  __shared__ __align__(16) u16 sB[128 * 64];

  f32x4 acc[4][4];
#pragma unroll
  for (int i = 0; i < 4; ++i)
#pragma unroll
    for (int j = 0; j < 4; ++j) acc[i][j] = (f32x4){0.f, 0.f, 0.f, 0.f};

  const int srow = (wv << 3) + (lane >> 3);
  const int scol = (lane & 7) << 3;
  const u16* gA = wA + (size_t)(m0 + srow) * KK + scol;
  const u16* gB = B2 + (size_t)(n0 + srow) * KK + scol;
  u16* lA = sA + wv * 512;
  u16* lB = sB + wv * 512;

  for (int ks = 0; ks < KK / 64; ++ks) {
    __syncthreads();
#pragma unroll
    for (int it = 0; it < 4; ++it) {
      gl16(gA + (size_t)it * 32 * KK, lA + it * 2048);
      gl16(gB + (size_t)it * 32 * KK, lB + it * 2048);
    }
    gA += 64;
    gB += 64;
    __syncthreads();
#pragma unroll
    for (int kk = 0; kk < 2; ++kk) {
      bf16x8 af[4], bv[4];
#pragma unroll
      for (int mt = 0; mt < 4; ++mt)
        af[mt] = __builtin_bit_cast(bf16x8, *reinterpret_cast<const us8*>(
            sA + (wr * 64 + mt * 16 + l15) * 64 + kk * 32 + h * 8));
#pragma unroll
      for (int nt = 0; nt < 4; ++nt)
        bv[nt] = __builtin_bit_cast(bf16x8, *reinterpret_cast<const us8*>(
            sB + (wc * 64 + nt * 16 + l15) * 64 + kk * 32 + h * 8));
#pragma unroll
      for (int mt = 0; mt < 4; ++mt)
#pragma unroll
        for (int nt = 0; nt < 4; ++nt)
          acc[mt][nt] = __builtin_amdgcn_mfma_f32_16x16x32_bf16(af[mt], bv[nt], acc[mt][nt], 0, 0, 0);
    }
  }

  const int sec = bm >> 2;
  const int g = (bm & 3) * 2 + wr;
  const int b = bn >> 3;
  const size_t bg = (size_t)b * G + g;
  if (sec < 2) {
    u16* base = (sec ? kt : qt) + bg * 65536;
#pragma unroll
    for (int nt = 0; nt < 4; ++nt) {
      const int n = (bn & 7) * 128 + wc * 64 + nt * 16 + l15;
#pragma unroll
      for (int mt = 0; mt < 4; ++mt) {
        us4 v;
        v[0] = f2bf(acc[mt][nt][0]); v[1] = f2bf(acc[mt][nt][1]);
        v[2] = f2bf(acc[mt][nt][2]); v[3] = f2bf(acc[mt][nt][3]);
        *reinterpret_cast<us4*>(base + (size_t)n * 64 + mt * 16 + 4 * h) = v;
      }
    }
  } else {
    u16* base = vt + bg * 65536;
#pragma unroll
    for (int nt = 0; nt < 4; ++nt) {
      const int n = (bn & 7) * 128 + wc * 64 + nt * 16 + l15;
#pragma unroll
      for (int mt = 0; mt < 4; ++mt)
#pragma unroll
        for (int r = 0; r < 4; ++r)
          base[(size_t)(mt * 16 + 4 * h + r) * 1024 + n] = f2bf(acc[mt][nt][r]);
    }
  }
}

// ---------------------------------------------------------------------------
__global__ __launch_bounds__(256) void pbdenom_kernel(
    const float* __restrict__ head_scale, float* __restrict__ denom) {
  const int tid = threadIdx.x;
  const int g = blockIdx.x >> 10;
  const int n = blockIdx.x & 1023;
  const float hs = head_scale[g];
  const float sg = 1.f / (1.f + __expf(-hs));
  const float s = sg * (0.4f - 0.003f) + 0.003f;
  const float sf = 1.f / (2.f * s * s);
  const float yn = (float)(n >> 5), xn = (float)(n & 31);
  float sum = 0.f;
#pragma unroll
  for (int j = 0; j < 4; ++j) {
    int m = tid + (j << 8);
    float dy = (yn - (float)(m >> 5)) * (1.f / 32.f);
    float dx = (xn - (float)(m & 31)) * (1.f / 32.f);
    sum += __expf(-sf * (dy * dy + dx * dx));
  }
  float tot = waveSum(sum);
  __shared__ float red[4];
  if ((tid & 63) == 0) red[tid >> 6] = tot;
  __syncthreads();
  if (tid == 0) denom[blockIdx.x] = red[0] + red[1] + red[2] + red[3];
}

// ---------------------------------------------------------------------------
__global__ __launch_bounds__(256) void norms_kernel(
    const u16* __restrict__ qt, const u16* __restrict__ kt,
    float* __restrict__ qn, float* __restrict__ kn) {
  const int idx = blockIdx.x * 64 + (threadIdx.x >> 2);
  const int sub = threadIdx.x & 3;
  const int sel = idx >> 16;
  const int row = idx & 65535;
  const u16* src = (sel ? kt : qt) + (size_t)row * 64 + sub * 16;
  float s = 0.f;
#pragma unroll
  for (int k = 0; k < 2; ++k) {
    us8 v = reinterpret_cast<const us8*>(src)[k];
#pragma unroll
    for (int j = 0; j < 8; ++j) {
      float f = bf2f(v[j]);
      s += f * f;
    }
  }
  s += __shfl_xor(s, 1, 64);
  s += __shfl_xor(s, 2, 64);
  if (sub == 0) (sel ? kn : qn)[row] = sqrtf(s + SMOOTH);
}

// ---------------------------------------------------------------------------
// MFMA attention. block = 256 thr (4 waves), (b, g, 128 q-rows). grid = 512.
// ---------------------------------------------------------------------------
__global__ __launch_bounds__(256, 2) void attn_mfma_kernel(
    const u16* __restrict__ qt, const u16* __restrict__ kt,
    const u16* __restrict__ vt, const float* __restrict__ qn_arr,
    const float* __restrict__ kn_arr, const float* __restrict__ denom,
    const float* __restrict__ head_scale, u16* __restrict__ aout) {
  const int tid = threadIdx.x;
  const int lane = tid & 63;
  const int wv = tid >> 6;
  const int h = lane >> 4;
  const int l15 = lane & 15;
  const int nb = blockIdx.x & 7;
  const int g = (blockIdx.x >> 3) & 7;
  const int b = blockIdx.x >> 6;

  __shared__ __align__(16) u16 smem[24576];
  u16* sQ = smem;
  u16* sK = smem + 8192;
  u16* sV = smem + 12288;
  u16* sP = smem + 16384 + wv * 2048;

  const size_t bg = (size_t)b * G + g;
  const u16* qg = qt + bg * 65536;
  const u16* kg = kt + bg * 65536;
  const u16* vg = vt + bg * 65536;

  {
    const int row = tid >> 1, c = (tid & 1) * 4;
    const us8* src = reinterpret_cast<const us8*>(qg + (size_t)(nb * 128 + row) * 64);
#pragma unroll
    for (int k = 0; k < 4; ++k) {
      int idx = (row * 64 + (c + k) * 8) ^ ((row & 7) << 3);
      *reinterpret_cast<us8*>(sQ + idx) = src[c + k];
    }
  }

  const float hs = head_scale[g];
  const float sg = 1.f / (1.f + __expf(-hs));
  const float sv = sg * (0.4f - 0.003f) + 0.003f;
  const float sf = 1.f / (2.f * sv * sv);

  float qnv[2][4], qiv[2][4], nyf[2][4], nxf[2][4];
#pragma unroll
  for (int ti = 0; ti < 2; ++ti)
#pragma unroll
    for (int r = 0; r < 4; ++r) {
      int n = nb * 128 + wv * 32 + ti * 16 + 4 * h + r;
      qnv[ti][r] = qn_arr[bg * 1024 + n];
      qiv[ti][r] = 1.f / denom[g * 1024 + n];
      nyf[ti][r] = (float)(n >> 5);
      nxf[ti][r] = (float)(n & 31);
    }

  f32x4 oacc[2][4];
#pragma unroll
  for (int ti = 0; ti < 2; ++ti)
#pragma unroll
    for (int dj = 0; dj < 4; ++dj) oacc[ti][dj] = (f32x4){0.f, 0.f, 0.f, 0.f};

  const int col8 = h * 8;

  for (int mt = 0; mt < 16; ++mt) {
    __syncthreads();
    {
      const int row = tid >> 2, cc = (tid & 3) * 2;
      const us8* ksrc = reinterpret_cast<const us8*>(kg + (size_t)(mt * 64 + row) * 64);
      const us8* vsrc = reinterpret_cast<const us8*>(vg + (size_t)row * 1024 + mt * 64);
#pragma unroll
      for (int k = 0; k < 2; ++k) {
        int idx = (row * 64 + (cc + k) * 8) ^ ((row & 7) << 3);
        *reinterpret_cast<us8*>(sK + idx) = ksrc[cc + k];
        *reinterpret_cast<us8*>(sV + idx) = vsrc[cc + k];
      }
    }
    __syncthreads();

    f32x4 sacc[2][4];
#pragma unroll
    for (int ti = 0; ti < 2; ++ti)
#pragma unroll
      for (int tj = 0; tj < 4; ++tj) sacc[ti][tj] = (f32x4){0.f, 0.f, 0.f, 0.f};
#pragma unroll
    for (int kk = 0; kk < 2; ++kk) {
      bf16x8 aq0 = ldfrag(sQ, wv * 32 + l15, kk * 32 + col8);
      bf16x8 aq1 = ldfrag(sQ, wv * 32 + 16 + l15, kk * 32 + col8);
#pragma unroll
      for (int tj = 0; tj < 4; ++tj) {
        bf16x8 bk = ldfrag(sK, tj * 16 + l15, kk * 32 + col8);
        sacc[0][tj] = __builtin_amdgcn_mfma_f32_16x16x32_bf16(aq0, bk, sacc[0][tj], 0, 0, 0);
        sacc[1][tj] = __builtin_amdgcn_mfma_f32_16x16x32_bf16(aq1, bk, sacc[1][tj], 0, 0, 0);
      }
    }

#pragma unroll
    for (int tj = 0; tj < 4; ++tj) {
      const int m = mt * 64 + tj * 16 + l15;
      const float knv = kn_arr[bg * 1024 + m];
      const float my = (float)(m >> 5), mx = (float)(m & 31);
#pragma unroll
      for (int ti = 0; ti < 2; ++ti) {
#pragma unroll
        for (int r = 0; r < 4; ++r) {
          float dy = (nyf[ti][r] - my) * (1.f / 32.f);
          float dx = (nxf[ti][r] - mx) * (1.f / 32.f);
          float pb = __expf(-sf * (dy * dy + dx * dx));
          float wgt = __fdividef(sacc[ti][tj][r], qnv[ti][r] * knv + SMOOTH) * pb * qiv[ti][r];
          int nl = ti * 16 + 4 * h + r;
          int pidx = (nl * 64 + tj * 16 + l15) ^ ((nl & 7) << 3);
          sP[pidx] = f2bf(wgt);
        }
      }
    }

#pragma unroll
    for (int km = 0; km < 2; ++km) {
      bf16x8 ap0 = ldfrag(sP, l15, km * 32 + col8);
      bf16x8 ap1 = ldfrag(sP, 16 + l15, km * 32 + col8);
#pragma unroll
      for (int dj = 0; dj < 4; ++dj) {
        bf16x8 bvv = ldfrag(sV, dj * 16 + l15, km * 32 + col8);
        oacc[0][dj] = __builtin_amdgcn_mfma_f32_16x16x32_bf16(ap0, bvv, oacc[0][dj], 0, 0, 0);
        oacc[1][dj] = __builtin_amdgcn_mfma_f32_16x16x32_bf16(ap1, bvv, oacc[1][dj], 0, 0, 0);
      }
    }
  }

  __syncthreads();
  u16* sO = sK;
#pragma unroll
  for (int ti = 0; ti < 2; ++ti)
#pragma unroll
    for (int dj = 0; dj < 4; ++dj)
#pragma unroll
      for (int r = 0; r < 4; ++r) {
        int nl = wv * 32 + ti * 16 + 4 * h + r;
        int idx = (nl * 64 + dj * 16 + l15) ^ ((nl & 7) << 3);
        sO[idx] = f2bf(oacc[ti][dj][r]);
      }
  __syncthreads();
  {
    const int row = tid >> 1, c = (tid & 1) * 4;
    us8* dst = reinterpret_cast<us8*>(aout + (bg * 1024 + (size_t)nb * 128 + row) * 64);
#pragma unroll
    for (int k = 0; k < 4; ++k) {
      int idx = (row * 64 + (c + k) * 8) ^ ((row & 7) << 3);
      dst[c + k] = *reinterpret_cast<const us8*>(sO + idx);
    }
  }
}

// ---------------------------------------------------------------------------
// 1x1 conv as MFMA GEMM: proj[b][c][n] (bf16) = sum_i wB[c][i]*aout[b,g,n,d].
// 64x64 tile, BK=64 (= one head g per K-step), 4 waves 2x2. grid = 4*128=512.
// ---------------------------------------------------------------------------
__global__ __launch_bounds__(256, 2) void conv1x1_mfma_kernel(
    const u16* __restrict__ aout, const u16* __restrict__ wB,
    u16* __restrict__ proj) {
  const int tid = threadIdx.x;
  const int lane = tid & 63;
  const int wv = tid >> 6;
  const int wr = wv >> 1, wc = wv & 1;
  const int h = lane >> 4, l15 = lane & 15;
  const int bm = blockIdx.x & 3;
  const int ntile = blockIdx.x >> 2;
  const int b = ntile >> 4;
  const int n0 = (ntile & 15) * 64;
  const int c0 = bm * 64;

  __shared__ __align__(16) u16 sA[64 * 64];
  __shared__ __align__(16) u16 sB[64 * 64];

  f32x4 acc[2][2];
#pragma unroll
  for (int i = 0; i < 2; ++i)
#pragma unroll
    for (int j = 0; j < 2; ++j) acc[i][j] = (f32x4){0.f, 0.f, 0.f, 0.f};

  const int srow = (wv << 3) + (lane >> 3);  // 0..31
  const int scol = (lane & 7) << 3;
  const u16* gA = wB + (size_t)(c0 + srow) * 512 + scol;
  const u16* gB = aout + ((size_t)(b * G) * 1024 + n0 + srow) * 64 + scol;
  u16* lA = sA + wv * 512;
  u16* lB = sB + wv * 512;

  for (int ks = 0; ks < 8; ++ks) {
    __syncthreads();
#pragma unroll
    for (int it = 0; it < 2; ++it) {
      gl16(gA + (size_t)it * 32 * 512, lA + it * 2048);
      gl16(gB + (size_t)it * 32 * 64, lB + it * 2048);
    }
    gA += 64;
    gB += 65536;  // next head g
    __syncthreads();
#pragma unroll
    for (int kk = 0; kk < 2; ++kk) {
      bf16x8 af[2], bv[2];
#pragma unroll
      for (int mt = 0; mt < 2; ++mt)
        af[mt] = __builtin_bit_cast(bf16x8, *reinterpret_cast<const us8*>(
            sA + (wr * 32 + mt * 16 + l15) * 64 + kk * 32 + h * 8));
#pragma unroll
      for (int nt = 0; nt < 2; ++nt)
        bv[nt] = __builtin_bit_cast(bf16x8, *reinterpret_cast<const us8*>(
            sB + (wc * 32 + nt * 16 + l15) * 64 + kk * 32 + h * 8));
#pragma unroll
      for (int mt = 0; mt < 2; ++mt)
#pragma unroll
        for (int nt = 0; nt < 2; ++nt)
          acc[mt][nt] = __builtin_amdgcn_mfma_f32_16x16x32_bf16(af[mt], bv[nt], acc[mt][nt], 0, 0, 0);
    }
  }

#pragma unroll
  for (int mt = 0; mt < 2; ++mt)
#pragma unroll
    for (int nt = 0; nt < 2; ++nt)
#pragma unroll
      for (int r = 0; r < 4; ++r) {
        const int c = c0 + wr * 32 + mt * 16 + 4 * h + r;
        const int n = n0 + wc * 32 + nt * 16 + l15;
        proj[((size_t)b * Cc + c) * Nn + n] = f2bf(acc[mt][nt][r]);
      }
}

// ---------------------------------------------------------------------------
__global__ __launch_bounds__(256) void bn_stats_kernel(
    const u16* __restrict__ proj, float* __restrict__ stats) {
  const int c = blockIdx.x;
  const int tid = threadIdx.x;
  float s = 0.f, s2 = 0.f;
  for (int b = 0; b < Bn; ++b) {
    us4 v = reinterpret_cast<const us4*>(proj + ((size_t)b * Cc + c) * Nn)[tid];
#pragma unroll
    for (int j = 0; j < 4; ++j) {
      float f = bf2f(v[j]);
      s += f;
      s2 += f * f;
    }
  }
  s = waveSum(s);
  s2 = waveSum(s2);
  __shared__ float r1[4], r2[4];
  if ((tid & 63) == 0) { r1[tid >> 6] = s; r2[tid >> 6] = s2; }
  __syncthreads();
  if (tid == 0) {
    float S = r1[0] + r1[1] + r1[2] + r1[3];
    float S2 = r2[0] + r2[1] + r2[2] + r2[3];
    const float invM = 1.f / (float)(Bn * Nn);
    float mean = S * invM;
    float var = S2 * invM - mean * mean;
    stats[c] = mean;
    stats[Cc + c] = rsqrtf(var + BN_EPS);
  }
}

__global__ __launch_bounds__(256) void bn_apply_kernel(
    const u16* __restrict__ proj, const float* __restrict__ stats,
    const float* __restrict__ gamma, const float* __restrict__ beta,
    float* __restrict__ out) {
  const int idx = blockIdx.x * 256 + threadIdx.x;  // us4 chunk
  const int flat = idx << 2;
  const int c = (flat >> 10) & (Cc - 1);
  us4 v = reinterpret_cast<const us4*>(proj)[idx];
  const float mean = stats[c];
  const float sc = stats[Cc + c] * gamma[c];
  const float sh = beta[c];
  float4 o;
  o.x = fmaxf((bf2f(v[0]) - mean) * sc + sh, 0.f);
  o.y = fmaxf((bf2f(v[1]) - mean) * sc + sh, 0.f);
  o.z = fmaxf((bf2f(v[2]) - mean) * sc + sh, 0.f);
  o.w = fmaxf((bf2f(v[3]) - mean) * sc + sh, 0.f);
  reinterpret_cast<float4*>(out)[idx] = o;
}

// ---------------------------------------------------------------------------
extern "C" void kernel_launch(void* const* d_in, const int* in_sizes, int n_in,
                              void* d_out, int out_size, void* d_ws, size_t ws_size,
                              hipStream_t stream) {
  const float* x = (const float*)d_in[0];
  const float* w_qkv = (const float*)d_in[1];
  const float* head_scale = (const float*)d_in[2];
  const float* w_out = (const float*)d_in[3];
  const float* gamma = (const float*)d_in[4];
  const float* beta = (const float*)d_in[5];
  float* out = (float*)d_out;

  char* w = (char*)d_ws;
  u16* qt = (u16*)(w + 0);                 // 8 MB
  u16* kt = (u16*)(w + 8388608);           // 8 MB
  u16* vt = (u16*)(w + 16777216);          // 8 MB
  u16* wA = (u16*)(w + 25165824);          // 7,077,888 B (dead after GEMM)
  u16* aout = (u16*)(w + 25165824);        // 8 MB (written post-GEMM, by attn)
  u16* B2 = (u16*)(w + 33554432);          // 37,748,736 B (dead after GEMM)
  u16* proj = (u16*)(w + 33554432);        // 4 MB bf16, overlays dead B2
  float* qn = (float*)(w + 71303168);      // 262144 B
  float* kn = (float*)(w + 71565312);      // 262144 B
  float* denom = (float*)(w + 71827456);   // 32768 B
  float* stats = (float*)(w + 71860224);   // 2048 B
  u16* wB = (u16*)(w + 71862272);          // 262144 B

  wconv_kernel<<<dim3(OC), dim3(256), 0, stream>>>(w_qkv, wA);
  wout_repack_kernel<<<dim3(64), dim3(256), 0, stream>>>(w_out, wB);
  im2col_kernel<<<dim3(128), dim3(256), 0, stream>>>(x, B2);
  pbdenom_kernel<<<dim3(G * Nn), dim3(256), 0, stream>>>(head_scale, denom);
  qkv_gemm_kernel<<<dim3(768), dim3(256), 0, stream>>>(wA, B2, qt, kt, vt);
  norms_kernel<<<dim3(2048), dim3(256), 0, stream>>>(qt, kt, qn, kn);
  attn_mfma_kernel<<<dim3(512), dim3(256), 0, stream>>>(qt, kt, vt, qn, kn, denom, head_scale, aout);
  conv1x1_mfma_kernel<<<dim3(512), dim3(256), 0, stream>>>(aout, wB, proj);
  bn_stats_kernel<<<dim3(Cc), dim3(256), 0, stream>>>(proj, stats);
  bn_apply_kernel<<<dim3((Bn * Cc * Nn / 4) / 256), dim3(256), 0, stream>>>(proj, stats, gamma, beta, out);
}

// Round 5
// 208.653 us; speedup vs baseline: 11.0324x; 1.0544x over previous
//
#include <hip/hip_runtime.h>
#include <math.h>

#define SMOOTH 1e-4f
#define BN_EPS 1e-5f

constexpr int Bn = 8;
constexpr int Cc = 256;
constexpr int Nn = 1024;   // H*W
constexpr int G = 8;       // heads
constexpr int INNER = 512;
constexpr int OC = 1536;   // 3*INNER
constexpr int KK = 2304;   // 9*256 im2col K

typedef unsigned short u16;
typedef __bf16 bf16x8 __attribute__((ext_vector_type(8)));
typedef float f32x4 __attribute__((ext_vector_type(4)));
typedef unsigned short us8 __attribute__((ext_vector_type(8)));
typedef unsigned short us4 __attribute__((ext_vector_type(4)));

__device__ __forceinline__ u16 f2bf(float f) {
  unsigned int u = __float_as_uint(f);
  unsigned int r = (u + 0x7fffu + ((u >> 16) & 1u)) >> 16;
  return (u16)r;
}
__device__ __forceinline__ float bf2f(u16 u) {
  return __uint_as_float(((unsigned int)u) << 16);
}

__device__ __forceinline__ float waveSum(float v) {
#pragma unroll
  for (int off = 32; off > 0; off >>= 1) v += __shfl_xor(v, off, 64);
  return v;
}

__device__ __forceinline__ void gl16(const u16* g, u16* l) {
  __builtin_amdgcn_global_load_lds(
      (const __attribute__((address_space(1))) unsigned int*)g,
      (__attribute__((address_space(3))) unsigned int*)l, 16, 0, 0);
}

// swizzled LDS fragment read (attn): rows of 64 u16, byte ^ ((row&7)<<4)
__device__ __forceinline__ bf16x8 ldfrag(const u16* base, int row, int col) {
  int idx = (row * 64 + col) ^ ((row & 7) << 3);
  return __builtin_bit_cast(bf16x8, *reinterpret_cast<const us8*>(base + idx));
}

// ---------------------------------------------------------------------------
// weight repack: wA[oc][tap*256+ic] = bf16(w_qkv[oc][ic*9+tap]). grid = 1536.
// ---------------------------------------------------------------------------
__global__ __launch_bounds__(256) void wconv_kernel(
    const float* __restrict__ wq, u16* __restrict__ wA) {
  const int oc = blockIdx.x;
  const int tid = threadIdx.x;
  __shared__ float sw[KK];
  for (int i = tid; i < KK; i += 256) sw[i] = wq[(size_t)oc * KK + i];
  __syncthreads();
#pragma unroll
  for (int j = 0; j < 2; ++j) {
    int c8 = tid + j * 256;
    if (c8 < KK / 8) {
      us8 v;
#pragma unroll
      for (int e = 0; e < 8; ++e) {
        int k = c8 * 8 + e;
        int tap = k >> 8, ic = k & 255;
        v[e] = f2bf(sw[ic * 9 + tap]);
      }
      *reinterpret_cast<us8*>(wA + (size_t)oc * KK + c8 * 8) = v;
    }
  }
}

// ---------------------------------------------------------------------------
// w_out -> bf16 repack. grid = 64 blocks of 256, us8 chunks.
// ---------------------------------------------------------------------------
__global__ __launch_bounds__(256) void wout_repack_kernel(
    const float* __restrict__ wout, u16* __restrict__ wB) {
  const int idx = blockIdx.x * 256 + threadIdx.x;
  const float4 a = reinterpret_cast<const float4*>(wout)[idx * 2];
  const float4 b = reinterpret_cast<const float4*>(wout)[idx * 2 + 1];
  us8 v;
  v[0] = f2bf(a.x); v[1] = f2bf(a.y); v[2] = f2bf(a.z); v[3] = f2bf(a.w);
  v[4] = f2bf(b.x); v[5] = f2bf(b.y); v[6] = f2bf(b.z); v[7] = f2bf(b.w);
  reinterpret_cast<us8*>(wB)[idx] = v;
}

// ---------------------------------------------------------------------------
// fused transpose + im2col: B2[pix][tap*256+ic] = bf16 x[b][ic][shift(pix,tap)]
// ---------------------------------------------------------------------------
__global__ __launch_bounds__(256) void im2col_kernel(
    const float* __restrict__ x, u16* __restrict__ B2) {
  const int tid = threadIdx.x;
  const int b = blockIdx.x >> 4;
  const int y0 = (blockIdx.x & 15) * 2;

  __shared__ u16 sxt[128 * 258];

  {
    const int pos = tid & 127;
    const int ichalf = tid >> 7;
    const int gidx = (y0 - 1) * 32 + pos;
    const bool valid = (gidx >= 0) && (gidx < 1024);
    const float* xb = x + (size_t)b * Cc * Nn;
    for (int ic2 = 0; ic2 < 128; ++ic2) {
      int ic = ichalf * 128 + ic2;
      float v = valid ? xb[(size_t)ic * Nn + gidx] : 0.f;
      sxt[pos * 258 + ic] = f2bf(v);
    }
  }
  __syncthreads();

  const int c16 = tid & 31;
  const int pl0 = tid >> 5;
  const us8 zero = {0, 0, 0, 0, 0, 0, 0, 0};
#pragma unroll
  for (int tap = 0; tap < 9; ++tap) {
    const int dy = tap / 3 - 1, dx = tap % 3 - 1;
#pragma unroll
    for (int it = 0; it < 8; ++it) {
      int pixloc = pl0 + it * 8;
      int yl = pixloc >> 5, xx = pixloc & 31;
      int sxx = xx + dx;
      int gy = y0 + yl + dy;
      bool v = (sxx >= 0) && (sxx < 32) && (gy >= 0) && (gy < 32);
      int spos = (yl + dy + 1) * 32 + sxx;
      us8 val = v ? *reinterpret_cast<const us8*>(sxt + spos * 258 + c16 * 8) : zero;
      size_t pix = (size_t)b * 1024 + (y0 + yl) * 32 + xx;
      *reinterpret_cast<us8*>(B2 + pix * KK + tap * 256 + c16 * 8) = val;
    }
  }
}

// ---------------------------------------------------------------------------
// qkv implicit GEMM: 128x128 tile, BK=64, 4 waves, global_load_lds staging.
// XCD-swizzled grid (768 = 8*96): each XCD owns a contiguous bn range so the
// shared B2 n-tiles stay L2-resident. Fused q/k norm epilogue (f32 acc).
// ---------------------------------------------------------------------------
__global__ __launch_bounds__(256, 2) void qkv_gemm_kernel(
    const u16* __restrict__ wA, const u16* __restrict__ B2,
    u16* __restrict__ qt, u16* __restrict__ kt, u16* __restrict__ vt,
    float* __restrict__ qn, float* __restrict__ kn) {
  const int tid = threadIdx.x;
  const int lane = tid & 63;
  const int wv = tid >> 6;
  const int wr = wv >> 1, wc = wv & 1;
  const int h = lane >> 4, l15 = lane & 15;
  // bijective XCD swizzle: 768 % 8 == 0, chunk = 96
  const int wgid = (blockIdx.x & 7) * 96 + (blockIdx.x >> 3);
  const int bm = wgid % 12;
  const int bn = wgid / 12;
  const int m0 = bm * 128;
  const int n0 = bn * 128;

  __shared__ __align__(16) u16 sA[128 * 64];
  __shared__ __align__(16) u16 sB[128 * 64];

  f32x4 acc[4][4];
#pragma unroll
  for (int i = 0; i < 4; ++i)
#pragma unroll
    for (int j = 0; j < 4; ++j) acc[i][j] = (f32x4){0.f, 0.f, 0.f, 0.f};

  const int srow = (wv << 3) + (lane >> 3);
  const int scol = (lane & 7) << 3;
  const u16* gA = wA + (size_t)(m0 + srow) * KK + scol;
  const u16* gB = B2 + (size_t)(n0 + srow) * KK + scol;
  u16* lA = sA + wv * 512;
  u16* lB = sB + wv * 512;

  for (int ks = 0; ks < KK / 64; ++ks) {
    __syncthreads();
#pragma unroll
    for (int it = 0; it < 4; ++it) {
      gl16(gA + (size_t)it * 32 * KK, lA + it * 2048);
      gl16(gB + (size_t)it * 32 * KK, lB + it * 2048);
    }
    gA += 64;
    gB += 64;
    __syncthreads();
#pragma unroll
    for (int kk = 0; kk < 2; ++kk) {
      bf16x8 af[4], bv[4];
#pragma unroll
      for (int mt = 0; mt < 4; ++mt)
        af[mt] = __builtin_bit_cast(bf16x8, *reinterpret_cast<const us8*>(
            sA + (wr * 64 + mt * 16 + l15) * 64 + kk * 32 + h * 8));
#pragma unroll
      for (int nt = 0; nt < 4; ++nt)
        bv[nt] = __builtin_bit_cast(bf16x8, *reinterpret_cast<const us8*>(
            sB + (wc * 64 + nt * 16 + l15) * 64 + kk * 32 + h * 8));
#pragma unroll
      for (int mt = 0; mt < 4; ++mt)
#pragma unroll
        for (int nt = 0; nt < 4; ++nt)
          acc[mt][nt] = __builtin_amdgcn_mfma_f32_16x16x32_bf16(af[mt], bv[nt], acc[mt][nt], 0, 0, 0);
    }
  }

  const int sec = bm >> 2;
  const int g = (bm & 3) * 2 + wr;   // one wave covers one head's full d=64
  const int b = bn >> 3;
  const size_t bg = (size_t)b * G + g;
  if (sec < 2) {
    u16* base = (sec ? kt : qt) + bg * 65536;
#pragma unroll
    for (int nt = 0; nt < 4; ++nt) {
      const int n = (bn & 7) * 128 + wc * 64 + nt * 16 + l15;
#pragma unroll
      for (int mt = 0; mt < 4; ++mt) {
        us4 v;
        v[0] = f2bf(acc[mt][nt][0]); v[1] = f2bf(acc[mt][nt][1]);
        v[2] = f2bf(acc[mt][nt][2]); v[3] = f2bf(acc[mt][nt][3]);
        *reinterpret_cast<us4*>(base + (size_t)n * 64 + mt * 16 + 4 * h) = v;
      }
    }
    // fused row norms (f32, exact): sum acc^2 over the 16 rows this lane
    // holds, then reduce across the 4 h-groups sharing the same column.
    float* dstn = sec ? kn : qn;
#pragma unroll
    for (int nt = 0; nt < 4; ++nt) {
      float ss = 0.f;
#pragma unroll
      for (int mt = 0; mt < 4; ++mt)
#pragma unroll
        for (int r = 0; r < 4; ++r) ss += acc[mt][nt][r] * acc[mt][nt][r];
      ss += __shfl_xor(ss, 16, 64);
      ss += __shfl_xor(ss, 32, 64);
      if (h == 0) {
        const int n = (bn & 7) * 128 + wc * 64 + nt * 16 + l15;
        dstn[bg * 1024 + n] = sqrtf(ss + SMOOTH);
      }
    }
  } else {
    u16* base = vt + bg * 65536;
#pragma unroll
    for (int nt = 0; nt < 4; ++nt) {
      const int n = (bn & 7) * 128 + wc * 64 + nt * 16 + l15;
#pragma unroll
      for (int mt = 0; mt < 4; ++mt)
#pragma unroll
        for (int r = 0; r < 4; ++r)
          base[(size_t)(mt * 16 + 4 * h + r) * 1024 + n] = f2bf(acc[mt][nt][r]);
    }
  }
}

// ---------------------------------------------------------------------------
__global__ __launch_bounds__(256) void pbdenom_kernel(
    const float* __restrict__ head_scale, float* __restrict__ denom) {
  const int tid = threadIdx.x;
  const int g = blockIdx.x >> 10;
  const int n = blockIdx.x & 1023;
  const float hs = head_scale[g];
  const float sg = 1.f / (1.f + __expf(-hs));
  const float s = sg * (0.4f - 0.003f) + 0.003f;
  const float sf = 1.f / (2.f * s * s);
  const float yn = (float)(n >> 5), xn = (float)(n & 31);
  float sum = 0.f;
#pragma unroll
  for (int j = 0; j < 4; ++j) {
    int m = tid + (j << 8);
    float dy = (yn - (float)(m >> 5)) * (1.f / 32.f);
    float dx = (xn - (float)(m & 31)) * (1.f / 32.f);
    sum += __expf(-sf * (dy * dy + dx * dx));
  }
  float tot = waveSum(sum);
  __shared__ float red[4];
  if ((tid & 63) == 0) red[tid >> 6] = tot;
  __syncthreads();
  if (tid == 0) denom[blockIdx.x] = red[0] + red[1] + red[2] + red[3];
}

// ---------------------------------------------------------------------------
// MFMA attention. block = 256 thr (4 waves), (b, g, 128 q-rows).
// XCD-swizzled grid (512 = 8*64): each XCD owns one batch image b.
// ---------------------------------------------------------------------------
__global__ __launch_bounds__(256, 2) void attn_mfma_kernel(
    const u16* __restrict__ qt, const u16* __restrict__ kt,
    const u16* __restrict__ vt, const float* __restrict__ qn_arr,
    const float* __restrict__ kn_arr, const float* __restrict__ denom,
    const float* __restrict__ head_scale, u16* __restrict__ aout) {
  const int tid = threadIdx.x;
  const int lane = tid & 63;
  const int wv = tid >> 6;
  const int h = lane >> 4;
  const int l15 = lane & 15;
  const int wgid = (blockIdx.x & 7) * 64 + (blockIdx.x >> 3);
  const int nb = wgid & 7;
  const int g = (wgid >> 3) & 7;
  const int b = wgid >> 6;

  __shared__ __align__(16) u16 smem[24576];
  u16* sQ = smem;
  u16* sK = smem + 8192;
  u16* sV = smem + 12288;
  u16* sP = smem + 16384 + wv * 2048;

  const size_t bg = (size_t)b * G + g;
  const u16* qg = qt + bg * 65536;
  const u16* kg = kt + bg * 65536;
  const u16* vg = vt + bg * 65536;

  {
    const int row = tid >> 1, c = (tid & 1) * 4;
    const us8* src = reinterpret_cast<const us8*>(qg + (size_t)(nb * 128 + row) * 64);
#pragma unroll
    for (int k = 0; k < 4; ++k) {
      int idx = (row * 64 + (c + k) * 8) ^ ((row & 7) << 3);
      *reinterpret_cast<us8*>(sQ + idx) = src[c + k];
    }
  }

  const float hs = head_scale[g];
  const float sg = 1.f / (1.f + __expf(-hs));
  const float sv = sg * (0.4f - 0.003f) + 0.003f;
  const float sf = 1.f / (2.f * sv * sv);

  float qnv[2][4], qiv[2][4], nyf[2][4], nxf[2][4];
#pragma unroll
  for (int ti = 0; ti < 2; ++ti)
#pragma unroll
    for (int r = 0; r < 4; ++r) {
      int n = nb * 128 + wv * 32 + ti * 16 + 4 * h + r;
      qnv[ti][r] = qn_arr[bg * 1024 + n];
      qiv[ti][r] = 1.f / denom[g * 1024 + n];
      nyf[ti][r] = (float)(n >> 5);
      nxf[ti][r] = (float)(n & 31);
    }

  f32x4 oacc[2][4];
#pragma unroll
  for (int ti = 0; ti < 2; ++ti)
#pragma unroll
    for (int dj = 0; dj < 4; ++dj) oacc[ti][dj] = (f32x4){0.f, 0.f, 0.f, 0.f};

  const int col8 = h * 8;

  for (int mt = 0; mt < 16; ++mt) {
    __syncthreads();
    {
      const int row = tid >> 2, cc = (tid & 3) * 2;
      const us8* ksrc = reinterpret_cast<const us8*>(kg + (size_t)(mt * 64 + row) * 64);
      const us8* vsrc = reinterpret_cast<const us8*>(vg + (size_t)row * 1024 + mt * 64);
#pragma unroll
      for (int k = 0; k < 2; ++k) {
        int idx = (row * 64 + (cc + k) * 8) ^ ((row & 7) << 3);
        *reinterpret_cast<us8*>(sK + idx) = ksrc[cc + k];
        *reinterpret_cast<us8*>(sV + idx) = vsrc[cc + k];
      }
    }
    __syncthreads();

    f32x4 sacc[2][4];
#pragma unroll
    for (int ti = 0; ti < 2; ++ti)
#pragma unroll
      for (int tj = 0; tj < 4; ++tj) sacc[ti][tj] = (f32x4){0.f, 0.f, 0.f, 0.f};
#pragma unroll
    for (int kk = 0; kk < 2; ++kk) {
      bf16x8 aq0 = ldfrag(sQ, wv * 32 + l15, kk * 32 + col8);
      bf16x8 aq1 = ldfrag(sQ, wv * 32 + 16 + l15, kk * 32 + col8);
#pragma unroll
      for (int tj = 0; tj < 4; ++tj) {
        bf16x8 bk = ldfrag(sK, tj * 16 + l15, kk * 32 + col8);
        sacc[0][tj] = __builtin_amdgcn_mfma_f32_16x16x32_bf16(aq0, bk, sacc[0][tj], 0, 0, 0);
        sacc[1][tj] = __builtin_amdgcn_mfma_f32_16x16x32_bf16(aq1, bk, sacc[1][tj], 0, 0, 0);
      }
    }

#pragma unroll
    for (int tj = 0; tj < 4; ++tj) {
      const int m = mt * 64 + tj * 16 + l15;
      const float knv = kn_arr[bg * 1024 + m];
      const float my = (float)(m >> 5), mx = (float)(m & 31);
#pragma unroll
      for (int ti = 0; ti < 2; ++ti) {
#pragma unroll
        for (int r = 0; r < 4; ++r) {
          float dy = (nyf[ti][r] - my) * (1.f / 32.f);
          float dx = (nxf[ti][r] - mx) * (1.f / 32.f);
          float pb = __expf(-sf * (dy * dy + dx * dx));
          float wgt = __fdividef(sacc[ti][tj][r], qnv[ti][r] * knv + SMOOTH) * pb * qiv[ti][r];
          int nl = ti * 16 + 4 * h + r;
          int pidx = (nl * 64 + tj * 16 + l15) ^ ((nl & 7) << 3);
          sP[pidx] = f2bf(wgt);
        }
      }
    }

#pragma unroll
    for (int km = 0; km < 2; ++km) {
      bf16x8 ap0 = ldfrag(sP, l15, km * 32 + col8);
      bf16x8 ap1 = ldfrag(sP, 16 + l15, km * 32 + col8);
#pragma unroll
      for (int dj = 0; dj < 4; ++dj) {
        bf16x8 bvv = ldfrag(sV, dj * 16 + l15, km * 32 + col8);
        oacc[0][dj] = __builtin_amdgcn_mfma_f32_16x16x32_bf16(ap0, bvv, oacc[0][dj], 0, 0, 0);
        oacc[1][dj] = __builtin_amdgcn_mfma_f32_16x16x32_bf16(ap1, bvv, oacc[1][dj], 0, 0, 0);
      }
    }
  }

  __syncthreads();
  u16* sO = sK;
#pragma unroll
  for (int ti = 0; ti < 2; ++ti)
#pragma unroll
    for (int dj = 0; dj < 4; ++dj)
#pragma unroll
      for (int r = 0; r < 4; ++r) {
        int nl = wv * 32 + ti * 16 + 4 * h + r;
        int idx = (nl * 64 + dj * 16 + l15) ^ ((nl & 7) << 3);
        sO[idx] = f2bf(oacc[ti][dj][r]);
      }
  __syncthreads();
  {
    const int row = tid >> 1, c = (tid & 1) * 4;
    us8* dst = reinterpret_cast<us8*>(aout + (bg * 1024 + (size_t)nb * 128 + row) * 64);
#pragma unroll
    for (int k = 0; k < 4; ++k) {
      int idx = (row * 64 + (c + k) * 8) ^ ((row & 7) << 3);
      dst[c + k] = *reinterpret_cast<const us8*>(sO + idx);
    }
  }
}

// ---------------------------------------------------------------------------
// 1x1 conv as MFMA GEMM. grid = 512.
// ---------------------------------------------------------------------------
__global__ __launch_bounds__(256, 2) void conv1x1_mfma_kernel(
    const u16* __restrict__ aout, const u16* __restrict__ wB,
    u16* __restrict__ proj) {
  const int tid = threadIdx.x;
  const int lane = tid & 63;
  const int wv = tid >> 6;
  const int wr = wv >> 1, wc = wv & 1;
  const int h = lane >> 4, l15 = lane & 15;
  const int bm = blockIdx.x & 3;
  const int ntile = blockIdx.x >> 2;
  const int b = ntile >> 4;
  const int n0 = (ntile & 15) * 64;
  const int c0 = bm * 64;

  __shared__ __align__(16) u16 sA[64 * 64];
  __shared__ __align__(16) u16 sB[64 * 64];

  f32x4 acc[2][2];
#pragma unroll
  for (int i = 0; i < 2; ++i)
#pragma unroll
    for (int j = 0; j < 2; ++j) acc[i][j] = (f32x4){0.f, 0.f, 0.f, 0.f};

  const int srow = (wv << 3) + (lane >> 3);
  const int scol = (lane & 7) << 3;
  const u16* gA = wB + (size_t)(c0 + srow) * 512 + scol;
  const u16* gB = aout + ((size_t)(b * G) * 1024 + n0 + srow) * 64 + scol;
  u16* lA = sA + wv * 512;
  u16* lB = sB + wv * 512;

  for (int ks = 0; ks < 8; ++ks) {
    __syncthreads();
#pragma unroll
    for (int it = 0; it < 2; ++it) {
      gl16(gA + (size_t)it * 32 * 512, lA + it * 2048);
      gl16(gB + (size_t)it * 32 * 64, lB + it * 2048);
    }
    gA += 64;
    gB += 65536;
    __syncthreads();
#pragma unroll
    for (int kk = 0; kk < 2; ++kk) {
      bf16x8 af[2], bv[2];
#pragma unroll
      for (int mt = 0; mt < 2; ++mt)
        af[mt] = __builtin_bit_cast(bf16x8, *reinterpret_cast<const us8*>(
            sA + (wr * 32 + mt * 16 + l15) * 64 + kk * 32 + h * 8));
#pragma unroll
      for (int nt = 0; nt < 2; ++nt)
        bv[nt] = __builtin_bit_cast(bf16x8, *reinterpret_cast<const us8*>(
            sB + (wc * 32 + nt * 16 + l15) * 64 + kk * 32 + h * 8));
#pragma unroll
      for (int mt = 0; mt < 2; ++mt)
#pragma unroll
        for (int nt = 0; nt < 2; ++nt)
          acc[mt][nt] = __builtin_amdgcn_mfma_f32_16x16x32_bf16(af[mt], bv[nt], acc[mt][nt], 0, 0, 0);
    }
  }

#pragma unroll
  for (int mt = 0; mt < 2; ++mt)
#pragma unroll
    for (int nt = 0; nt < 2; ++nt)
#pragma unroll
      for (int r = 0; r < 4; ++r) {
        const int c = c0 + wr * 32 + mt * 16 + 4 * h + r;
        const int n = n0 + wc * 32 + nt * 16 + l15;
        proj[((size_t)b * Cc + c) * Nn + n] = f2bf(acc[mt][nt][r]);
      }
}

// ---------------------------------------------------------------------------
__global__ __launch_bounds__(256) void bn_stats_kernel(
    const u16* __restrict__ proj, float* __restrict__ stats) {
  const int c = blockIdx.x;
  const int tid = threadIdx.x;
  float s = 0.f, s2 = 0.f;
  for (int b = 0; b < Bn; ++b) {
    us4 v = reinterpret_cast<const us4*>(proj + ((size_t)b * Cc + c) * Nn)[tid];
#pragma unroll
    for (int j = 0; j < 4; ++j) {
      float f = bf2f(v[j]);
      s += f;
      s2 += f * f;
    }
  }
  s = waveSum(s);
  s2 = waveSum(s2);
  __shared__ float r1[4], r2[4];
  if ((tid & 63) == 0) { r1[tid >> 6] = s; r2[tid >> 6] = s2; }
  __syncthreads();
  if (tid == 0) {
    float S = r1[0] + r1[1] + r1[2] + r1[3];
    float S2 = r2[0] + r2[1] + r2[2] + r2[3];
    const float invM = 1.f / (float)(Bn * Nn);
    float mean = S * invM;
    float var = S2 * invM - mean * mean;
    stats[c] = mean;
    stats[Cc + c] = rsqrtf(var + BN_EPS);
  }
}

__global__ __launch_bounds__(256) void bn_apply_kernel(
    const u16* __restrict__ proj, const float* __restrict__ stats,
    const float* __restrict__ gamma, const float* __restrict__ beta,
    float* __restrict__ out) {
  const int idx = blockIdx.x * 256 + threadIdx.x;
  const int flat = idx << 2;
  const int c = (flat >> 10) & (Cc - 1);
  us4 v = reinterpret_cast<const us4*>(proj)[idx];
  const float mean = stats[c];
  const float sc = stats[Cc + c] * gamma[c];
  const float sh = beta[c];
  float4 o;
  o.x = fmaxf((bf2f(v[0]) - mean) * sc + sh, 0.f);
  o.y = fmaxf((bf2f(v[1]) - mean) * sc + sh, 0.f);
  o.z = fmaxf((bf2f(v[2]) - mean) * sc + sh, 0.f);
  o.w = fmaxf((bf2f(v[3]) - mean) * sc + sh, 0.f);
  reinterpret_cast<float4*>(out)[idx] = o;
}

// ---------------------------------------------------------------------------
extern "C" void kernel_launch(void* const* d_in, const int* in_sizes, int n_in,
                              void* d_out, int out_size, void* d_ws, size_t ws_size,
                              hipStream_t stream) {
  const float* x = (const float*)d_in[0];
  const float* w_qkv = (const float*)d_in[1];
  const float* head_scale = (const float*)d_in[2];
  const float* w_out = (const float*)d_in[3];
  const float* gamma = (const float*)d_in[4];
  const float* beta = (const float*)d_in[5];
  float* out = (float*)d_out;

  char* w = (char*)d_ws;
  u16* qt = (u16*)(w + 0);                 // 8 MB
  u16* kt = (u16*)(w + 8388608);           // 8 MB
  u16* vt = (u16*)(w + 16777216);          // 8 MB
  u16* wA = (u16*)(w + 25165824);          // 7,077,888 B (dead after GEMM)
  u16* aout = (u16*)(w + 25165824);        // 8 MB (written post-GEMM, by attn)
  u16* B2 = (u16*)(w + 33554432);          // 37,748,736 B (dead after GEMM)
  u16* proj = (u16*)(w + 33554432);        // 4 MB bf16, overlays dead B2
  float* qn = (float*)(w + 71303168);      // 262144 B
  float* kn = (float*)(w + 71565312);      // 262144 B
  float* denom = (float*)(w + 71827456);   // 32768 B
  float* stats = (float*)(w + 71860224);   // 2048 B
  u16* wB = (u16*)(w + 71862272);          // 262144 B

  wconv_kernel<<<dim3(OC), dim3(256), 0, stream>>>(w_qkv, wA);
  wout_repack_kernel<<<dim3(64), dim3(256), 0, stream>>>(w_out, wB);
  im2col_kernel<<<dim3(128), dim3(256), 0, stream>>>(x, B2);
  pbdenom_kernel<<<dim3(G * Nn), dim3(256), 0, stream>>>(head_scale, denom);
  qkv_gemm_kernel<<<dim3(768), dim3(256), 0, stream>>>(wA, B2, qt, kt, vt, qn, kn);
  attn_mfma_kernel<<<dim3(512), dim3(256), 0, stream>>>(qt, kt, vt, qn, kn, denom, head_scale, aout);
  conv1x1_mfma_kernel<<<dim3(512), dim3(256), 0, stream>>>(aout, wB, proj);
  bn_stats_kernel<<<dim3(Cc), dim3(256), 0, stream>>>(proj, stats);
  bn_apply_kernel<<<dim3((Bn * Cc * Nn / 4) / 256), dim3(256), 0, stream>>>(proj, stats, gamma, beta, out);
}

// Round 6
// 203.873 us; speedup vs baseline: 11.2911x; 1.0235x over previous
//
#include <hip/hip_runtime.h>
#include <math.h>

#define SMOOTH 1e-4f
#define BN_EPS 1e-5f

constexpr int Bn = 8;
constexpr int Cc = 256;
constexpr int Nn = 1024;   // H*W
constexpr int G = 8;       // heads
constexpr int INNER = 512;
constexpr int OC = 1536;   // 3*INNER
constexpr int KK = 2304;   // 9*256 im2col K

typedef unsigned short u16;
typedef __bf16 bf16x8 __attribute__((ext_vector_type(8)));
typedef float f32x4 __attribute__((ext_vector_type(4)));
typedef unsigned short us8 __attribute__((ext_vector_type(8)));
typedef unsigned short us4 __attribute__((ext_vector_type(4)));

__device__ __forceinline__ u16 f2bf(float f) {
  unsigned int u = __float_as_uint(f);
  unsigned int r = (u + 0x7fffu + ((u >> 16) & 1u)) >> 16;
  return (u16)r;
}
__device__ __forceinline__ float bf2f(u16 u) {
  return __uint_as_float(((unsigned int)u) << 16);
}

__device__ __forceinline__ float waveSum(float v) {
#pragma unroll
  for (int off = 32; off > 0; off >>= 1) v += __shfl_xor(v, off, 64);
  return v;
}

__device__ __forceinline__ void gl16(const u16* g, u16* l) {
  __builtin_amdgcn_global_load_lds(
      (const __attribute__((address_space(1))) unsigned int*)g,
      (__attribute__((address_space(3))) unsigned int*)l, 16, 0, 0);
}

// swizzled LDS fragment read (attn): rows of 64 u16, byte ^ ((row&7)<<4)
__device__ __forceinline__ bf16x8 ldfrag(const u16* base, int row, int col) {
  int idx = (row * 64 + col) ^ ((row & 7) << 3);
  return __builtin_bit_cast(bf16x8, *reinterpret_cast<const us8*>(base + idx));
}

// ---------------------------------------------------------------------------
// weight repack: wA[oc][tap*256+ic] = bf16(w_qkv[oc][ic*9+tap]). grid = 1536.
// ---------------------------------------------------------------------------
__global__ __launch_bounds__(256) void wconv_kernel(
    const float* __restrict__ wq, u16* __restrict__ wA) {
  const int oc = blockIdx.x;
  const int tid = threadIdx.x;
  __shared__ float sw[KK];
  for (int i = tid; i < KK; i += 256) sw[i] = wq[(size_t)oc * KK + i];
  __syncthreads();
#pragma unroll
  for (int j = 0; j < 2; ++j) {
    int c8 = tid + j * 256;
    if (c8 < KK / 8) {
      us8 v;
#pragma unroll
      for (int e = 0; e < 8; ++e) {
        int k = c8 * 8 + e;
        int tap = k >> 8, ic = k & 255;
        v[e] = f2bf(sw[ic * 9 + tap]);
      }
      *reinterpret_cast<us8*>(wA + (size_t)oc * KK + c8 * 8) = v;
    }
  }
}

// ---------------------------------------------------------------------------
// w_out -> bf16 repack. grid = 64 blocks of 256, us8 chunks.
// ---------------------------------------------------------------------------
__global__ __launch_bounds__(256) void wout_repack_kernel(
    const float* __restrict__ wout, u16* __restrict__ wB) {
  const int idx = blockIdx.x * 256 + threadIdx.x;
  const float4 a = reinterpret_cast<const float4*>(wout)[idx * 2];
  const float4 b = reinterpret_cast<const float4*>(wout)[idx * 2 + 1];
  us8 v;
  v[0] = f2bf(a.x); v[1] = f2bf(a.y); v[2] = f2bf(a.z); v[3] = f2bf(a.w);
  v[4] = f2bf(b.x); v[5] = f2bf(b.y); v[6] = f2bf(b.z); v[7] = f2bf(b.w);
  reinterpret_cast<us8*>(wB)[idx] = v;
}

// ---------------------------------------------------------------------------
// fused transpose + im2col: B2[pix][tap*256+ic] = bf16 x[b][ic][shift(pix,tap)]
// ---------------------------------------------------------------------------
__global__ __launch_bounds__(256) void im2col_kernel(
    const float* __restrict__ x, u16* __restrict__ B2) {
  const int tid = threadIdx.x;
  const int b = blockIdx.x >> 4;
  const int y0 = (blockIdx.x & 15) * 2;

  __shared__ u16 sxt[128 * 258];

  {
    const int pos = tid & 127;
    const int ichalf = tid >> 7;
    const int gidx = (y0 - 1) * 32 + pos;
    const bool valid = (gidx >= 0) && (gidx < 1024);
    const float* xb = x + (size_t)b * Cc * Nn;
    for (int ic2 = 0; ic2 < 128; ++ic2) {
      int ic = ichalf * 128 + ic2;
      float v = valid ? xb[(size_t)ic * Nn + gidx] : 0.f;
      sxt[pos * 258 + ic] = f2bf(v);
    }
  }
  __syncthreads();

  const int c16 = tid & 31;
  const int pl0 = tid >> 5;
  const us8 zero = {0, 0, 0, 0, 0, 0, 0, 0};
#pragma unroll
  for (int tap = 0; tap < 9; ++tap) {
    const int dy = tap / 3 - 1, dx = tap % 3 - 1;
#pragma unroll
    for (int it = 0; it < 8; ++it) {
      int pixloc = pl0 + it * 8;
      int yl = pixloc >> 5, xx = pixloc & 31;
      int sxx = xx + dx;
      int gy = y0 + yl + dy;
      bool v = (sxx >= 0) && (sxx < 32) && (gy >= 0) && (gy < 32);
      int spos = (yl + dy + 1) * 32 + sxx;
      us8 val = v ? *reinterpret_cast<const us8*>(sxt + spos * 258 + c16 * 8) : zero;
      size_t pix = (size_t)b * 1024 + (y0 + yl) * 32 + xx;
      *reinterpret_cast<us8*>(B2 + pix * KK + tap * 256 + c16 * 8) = val;
    }
  }
}

// ---------------------------------------------------------------------------
// qkv implicit GEMM: 128x128 tile, BK=64, 4 waves, global_load_lds staging.
// XCD-swizzled grid. Epilogue: q,k rows are NORMALIZED (f32-exact row norms
// from resident accumulators) before bf16 store -> QK^T gives cosine sim.
// ---------------------------------------------------------------------------
__global__ __launch_bounds__(256, 2) void qkv_gemm_kernel(
    const u16* __restrict__ wA, const u16* __restrict__ B2,
    u16* __restrict__ qt, u16* __restrict__ kt, u16* __restrict__ vt) {
  const int tid = threadIdx.x;
  const int lane = tid & 63;
  const int wv = tid >> 6;
  const int wr = wv >> 1, wc = wv & 1;
  const int h = lane >> 4, l15 = lane & 15;
  // bijective XCD swizzle: 768 % 8 == 0, chunk = 96
  const int wgid = (blockIdx.x & 7) * 96 + (blockIdx.x >> 3);
  const int bm = wgid % 12;
  const int bn = wgid / 12;
  const int m0 = bm * 128;
  const int n0 = bn * 128;

  __shared__ __align__(16) u16 sA[128 * 64];
  __shared__ __align__(16) u16 sB[128 * 64];

  f32x4 acc[4][4];
#pragma unroll
  for (int i = 0; i < 4; ++i)
#pragma unroll
    for (int j = 0; j < 4; ++j) acc[i][j] = (f32x4){0.f, 0.f, 0.f, 0.f};

  const int srow = (wv << 3) + (lane >> 3);
  const int scol = (lane & 7) << 3;
  const u16* gA = wA + (size_t)(m0 + srow) * KK + scol;
  const u16* gB = B2 + (size_t)(n0 + srow) * KK + scol;
  u16* lA = sA + wv * 512;
  u16* lB = sB + wv * 512;

  for (int ks = 0; ks < KK / 64; ++ks) {
    __syncthreads();
#pragma unroll
    for (int it = 0; it < 4; ++it) {
      gl16(gA + (size_t)it * 32 * KK, lA + it * 2048);
      gl16(gB + (size_t)it * 32 * KK, lB + it * 2048);
    }
    gA += 64;
    gB += 64;
    __syncthreads();
#pragma unroll
    for (int kk = 0; kk < 2; ++kk) {
      bf16x8 af[4], bv[4];
#pragma unroll
      for (int mt = 0; mt < 4; ++mt)
        af[mt] = __builtin_bit_cast(bf16x8, *reinterpret_cast<const us8*>(
            sA + (wr * 64 + mt * 16 + l15) * 64 + kk * 32 + h * 8));
#pragma unroll
      for (int nt = 0; nt < 4; ++nt)
        bv[nt] = __builtin_bit_cast(bf16x8, *reinterpret_cast<const us8*>(
            sB + (wc * 64 + nt * 16 + l15) * 64 + kk * 32 + h * 8));
#pragma unroll
      for (int mt = 0; mt < 4; ++mt)
#pragma unroll
        for (int nt = 0; nt < 4; ++nt)
          acc[mt][nt] = __builtin_amdgcn_mfma_f32_16x16x32_bf16(af[mt], bv[nt], acc[mt][nt], 0, 0, 0);
    }
  }

  const int sec = bm >> 2;
  const int g = (bm & 3) * 2 + wr;   // one wave covers one head's full d=64
  const int b = bn >> 3;
  const size_t bg = (size_t)b * G + g;
  if (sec < 2) {
    u16* base = (sec ? kt : qt) + bg * 65536;
#pragma unroll
    for (int nt = 0; nt < 4; ++nt) {
      // f32-exact row norm over d (the wave's 64 M-rows for column n)
      float ss = 0.f;
#pragma unroll
      for (int mt = 0; mt < 4; ++mt)
#pragma unroll
        for (int r = 0; r < 4; ++r) ss += acc[mt][nt][r] * acc[mt][nt][r];
      ss += __shfl_xor(ss, 16, 64);
      ss += __shfl_xor(ss, 32, 64);
      const float rs = rsqrtf(ss + SMOOTH);
      const int n = (bn & 7) * 128 + wc * 64 + nt * 16 + l15;
#pragma unroll
      for (int mt = 0; mt < 4; ++mt) {
        us4 v;
        v[0] = f2bf(acc[mt][nt][0] * rs); v[1] = f2bf(acc[mt][nt][1] * rs);
        v[2] = f2bf(acc[mt][nt][2] * rs); v[3] = f2bf(acc[mt][nt][3] * rs);
        *reinterpret_cast<us4*>(base + (size_t)n * 64 + mt * 16 + 4 * h) = v;
      }
    }
  } else {
    u16* base = vt + bg * 65536;
#pragma unroll
    for (int nt = 0; nt < 4; ++nt) {
      const int n = (bn & 7) * 128 + wc * 64 + nt * 16 + l15;
#pragma unroll
      for (int mt = 0; mt < 4; ++mt)
#pragma unroll
        for (int r = 0; r < 4; ++r)
          base[(size_t)(mt * 16 + 4 * h + r) * 1024 + n] = f2bf(acc[mt][nt][r]);
    }
  }
}

// ---------------------------------------------------------------------------
// normalized positional bias, fragment-ordered:
// pbF[g][nb][wv][mt][lane][e] = bf16( exp(-sf*dis(n,m)) / denom(g,n) )
// where n = nb*128+wv*32+ti*16+4h+r, m = mt*64+tj*16+l15, lane = h*16+l15,
// e = ti*16+tj*4+r. grid = G*Nn = 8192 blocks of 256.
// ---------------------------------------------------------------------------
__global__ __launch_bounds__(256) void pbgen_kernel(
    const float* __restrict__ head_scale, u16* __restrict__ pbF) {
  const int tid = threadIdx.x;
  const int g = blockIdx.x >> 10;
  const int n = blockIdx.x & 1023;
  const float hs = head_scale[g];
  const float sg = 1.f / (1.f + __expf(-hs));
  const float s = sg * (0.4f - 0.003f) + 0.003f;
  const float sf = 1.f / (2.f * s * s);
  const float yn = (float)(n >> 5), xn = (float)(n & 31);
  float e4[4];
  float sum = 0.f;
#pragma unroll
  for (int j = 0; j < 4; ++j) {
    int m = tid + (j << 8);
    float dy = (yn - (float)(m >> 5)) * (1.f / 32.f);
    float dx = (xn - (float)(m & 31)) * (1.f / 32.f);
    e4[j] = __expf(-sf * (dy * dy + dx * dx));
    sum += e4[j];
  }
  float tot = waveSum(sum);
  __shared__ float red[4];
  if ((tid & 63) == 0) red[tid >> 6] = tot;
  __syncthreads();
  const float inv = 1.f / (red[0] + red[1] + red[2] + red[3]);
  const int nb = n >> 7, wv = (n >> 5) & 3, ti = (n >> 4) & 1;
  const int h = (n >> 2) & 3, r = n & 3;
  u16* base = pbF + ((((size_t)g * 8 + nb) * 4 + wv) * 16) * 2048;
#pragma unroll
  for (int j = 0; j < 4; ++j) {
    int m = tid + (j << 8);
    int mt = m >> 6, tj = (m >> 4) & 3, l15 = m & 15;
    base[(size_t)mt * 2048 + (h * 16 + l15) * 32 + ti * 16 + tj * 4 + r] =
        f2bf(e4[j] * inv);
  }
}

// ---------------------------------------------------------------------------
// MFMA attention. block = 256 thr (4 waves), (b, g, 128 q-rows).
// q,k pre-normalized -> sacc is cosine sim; weighting = sacc * pbF (1 mul).
// XCD swizzle groups blocks by head g (pbF[g] = 2MB L2-resident per XCD).
// ---------------------------------------------------------------------------
__global__ __launch_bounds__(256, 2) void attn_mfma_kernel(
    const u16* __restrict__ qt, const u16* __restrict__ kt,
    const u16* __restrict__ vt, const u16* __restrict__ pbF,
    u16* __restrict__ aout) {
  const int tid = threadIdx.x;
  const int lane = tid & 63;
  const int wv = tid >> 6;
  const int h = lane >> 4;
  const int l15 = lane & 15;
  const int wgid = (blockIdx.x & 7) * 64 + (blockIdx.x >> 3);
  const int g = wgid >> 6;        // slow index: one g per XCD
  const int b = (wgid >> 3) & 7;
  const int nb = wgid & 7;

  __shared__ __align__(16) u16 smem[24576];
  u16* sQ = smem;
  u16* sK = smem + 8192;
  u16* sV = smem + 12288;
  u16* sP = smem + 16384 + wv * 2048;

  const size_t bg = (size_t)b * G + g;
  const u16* qg = qt + bg * 65536;
  const u16* kg = kt + bg * 65536;
  const u16* vg = vt + bg * 65536;
  const u16* pbBase = pbF + ((((size_t)g * 8 + nb) * 4 + wv) * 16) * 2048 + lane * 32;

  {
    const int row = tid >> 1, c = (tid & 1) * 4;
    const us8* src = reinterpret_cast<const us8*>(qg + (size_t)(nb * 128 + row) * 64);
#pragma unroll
    for (int k = 0; k < 4; ++k) {
      int idx = (row * 64 + (c + k) * 8) ^ ((row & 7) << 3);
      *reinterpret_cast<us8*>(sQ + idx) = src[c + k];
    }
  }

  f32x4 oacc[2][4];
#pragma unroll
  for (int ti = 0; ti < 2; ++ti)
#pragma unroll
    for (int dj = 0; dj < 4; ++dj) oacc[ti][dj] = (f32x4){0.f, 0.f, 0.f, 0.f};

  const int col8 = h * 8;

  for (int mt = 0; mt < 16; ++mt) {
    __syncthreads();
    // prefetch this m-tile's positional-bias fragment (coalesced us8 x4)
    const us8* pbp = reinterpret_cast<const us8*>(pbBase + (size_t)mt * 2048);
    us8 pbv[4];
    pbv[0] = pbp[0]; pbv[1] = pbp[1]; pbv[2] = pbp[2]; pbv[3] = pbp[3];
    {
      const int row = tid >> 2, cc = (tid & 3) * 2;
      const us8* ksrc = reinterpret_cast<const us8*>(kg + (size_t)(mt * 64 + row) * 64);
      const us8* vsrc = reinterpret_cast<const us8*>(vg + (size_t)row * 1024 + mt * 64);
#pragma unroll
      for (int k = 0; k < 2; ++k) {
        int idx = (row * 64 + (cc + k) * 8) ^ ((row & 7) << 3);
        *reinterpret_cast<us8*>(sK + idx) = ksrc[cc + k];
        *reinterpret_cast<us8*>(sV + idx) = vsrc[cc + k];
      }
    }
    __syncthreads();

    f32x4 sacc[2][4];
#pragma unroll
    for (int ti = 0; ti < 2; ++ti)
#pragma unroll
      for (int tj = 0; tj < 4; ++tj) sacc[ti][tj] = (f32x4){0.f, 0.f, 0.f, 0.f};
#pragma unroll
    for (int kk = 0; kk < 2; ++kk) {
      bf16x8 aq0 = ldfrag(sQ, wv * 32 + l15, kk * 32 + col8);
      bf16x8 aq1 = ldfrag(sQ, wv * 32 + 16 + l15, kk * 32 + col8);
#pragma unroll
      for (int tj = 0; tj < 4; ++tj) {
        bf16x8 bk = ldfrag(sK, tj * 16 + l15, kk * 32 + col8);
        sacc[0][tj] = __builtin_amdgcn_mfma_f32_16x16x32_bf16(aq0, bk, sacc[0][tj], 0, 0, 0);
        sacc[1][tj] = __builtin_amdgcn_mfma_f32_16x16x32_bf16(aq1, bk, sacc[1][tj], 0, 0, 0);
      }
    }

    // weight P = cos * pb and write bf16 to per-wave LDS
#pragma unroll
    for (int tj = 0; tj < 4; ++tj) {
#pragma unroll
      for (int ti = 0; ti < 2; ++ti) {
#pragma unroll
        for (int r = 0; r < 4; ++r) {
          const int e = ti * 16 + tj * 4 + r;          // compile-time const
          float wgt = sacc[ti][tj][r] * bf2f(pbv[e >> 3][e & 7]);
          int nl = ti * 16 + 4 * h + r;
          int pidx = (nl * 64 + tj * 16 + l15) ^ ((nl & 7) << 3);
          sP[pidx] = f2bf(wgt);
        }
      }
    }

#pragma unroll
    for (int km = 0; km < 2; ++km) {
      bf16x8 ap0 = ldfrag(sP, l15, km * 32 + col8);
      bf16x8 ap1 = ldfrag(sP, 16 + l15, km * 32 + col8);
#pragma unroll
      for (int dj = 0; dj < 4; ++dj) {
        bf16x8 bvv = ldfrag(sV, dj * 16 + l15, km * 32 + col8);
        oacc[0][dj] = __builtin_amdgcn_mfma_f32_16x16x32_bf16(ap0, bvv, oacc[0][dj], 0, 0, 0);
        oacc[1][dj] = __builtin_amdgcn_mfma_f32_16x16x32_bf16(ap1, bvv, oacc[1][dj], 0, 0, 0);
      }
    }
  }

  __syncthreads();
  u16* sO = sK;
#pragma unroll
  for (int ti = 0; ti < 2; ++ti)
#pragma unroll
    for (int dj = 0; dj < 4; ++dj)
#pragma unroll
      for (int r = 0; r < 4; ++r) {
        int nl = wv * 32 + ti * 16 + 4 * h + r;
        int idx = (nl * 64 + dj * 16 + l15) ^ ((nl & 7) << 3);
        sO[idx] = f2bf(oacc[ti][dj][r]);
      }
  __syncthreads();
  {
    const int row = tid >> 1, c = (tid & 1) * 4;
    us8* dst = reinterpret_cast<us8*>(aout + (bg * 1024 + (size_t)nb * 128 + row) * 64);
#pragma unroll
    for (int k = 0; k < 4; ++k) {
      int idx = (row * 64 + (c + k) * 8) ^ ((row & 7) << 3);
      dst[c + k] = *reinterpret_cast<const us8*>(sO + idx);
    }
  }
}

// ---------------------------------------------------------------------------
// 1x1 conv as MFMA GEMM. grid = 512.
// ---------------------------------------------------------------------------
__global__ __launch_bounds__(256, 2) void conv1x1_mfma_kernel(
    const u16* __restrict__ aout, const u16* __restrict__ wB,
    u16* __restrict__ proj) {
  const int tid = threadIdx.x;
  const int lane = tid & 63;
  const int wv = tid >> 6;
  const int wr = wv >> 1, wc = wv & 1;
  const int h = lane >> 4, l15 = lane & 15;
  const int bm = blockIdx.x & 3;
  const int ntile = blockIdx.x >> 2;
  const int b = ntile >> 4;
  const int n0 = (ntile & 15) * 64;
  const int c0 = bm * 64;

  __shared__ __align__(16) u16 sA[64 * 64];
  __shared__ __align__(16) u16 sB[64 * 64];

  f32x4 acc[2][2];
#pragma unroll
  for (int i = 0; i < 2; ++i)
#pragma unroll
    for (int j = 0; j < 2; ++j) acc[i][j] = (f32x4){0.f, 0.f, 0.f, 0.f};

  const int srow = (wv << 3) + (lane >> 3);
  const int scol = (lane & 7) << 3;
  const u16* gA = wB + (size_t)(c0 + srow) * 512 + scol;
  const u16* gB = aout + ((size_t)(b * G) * 1024 + n0 + srow) * 64 + scol;
  u16* lA = sA + wv * 512;
  u16* lB = sB + wv * 512;

  for (int ks = 0; ks < 8; ++ks) {
    __syncthreads();
#pragma unroll
    for (int it = 0; it < 2; ++it) {
      gl16(gA + (size_t)it * 32 * 512, lA + it * 2048);
      gl16(gB + (size_t)it * 32 * 64, lB + it * 2048);
    }
    gA += 64;
    gB += 65536;
    __syncthreads();
#pragma unroll
    for (int kk = 0; kk < 2; ++kk) {
      bf16x8 af[2], bv[2];
#pragma unroll
      for (int mt = 0; mt < 2; ++mt)
        af[mt] = __builtin_bit_cast(bf16x8, *reinterpret_cast<const us8*>(
            sA + (wr * 32 + mt * 16 + l15) * 64 + kk * 32 + h * 8));
#pragma unroll
      for (int nt = 0; nt < 2; ++nt)
        bv[nt] = __builtin_bit_cast(bf16x8, *reinterpret_cast<const us8*>(
            sB + (wc * 32 + nt * 16 + l15) * 64 + kk * 32 + h * 8));
#pragma unroll
      for (int mt = 0; mt < 2; ++mt)
#pragma unroll
        for (int nt = 0; nt < 2; ++nt)
          acc[mt][nt] = __builtin_amdgcn_mfma_f32_16x16x32_bf16(af[mt], bv[nt], acc[mt][nt], 0, 0, 0);
    }
  }

#pragma unroll
  for (int mt = 0; mt < 2; ++mt)
#pragma unroll
    for (int nt = 0; nt < 2; ++nt)
#pragma unroll
      for (int r = 0; r < 4; ++r) {
        const int c = c0 + wr * 32 + mt * 16 + 4 * h + r;
        const int n = n0 + wc * 32 + nt * 16 + l15;
        proj[((size_t)b * Cc + c) * Nn + n] = f2bf(acc[mt][nt][r]);
      }
}

// ---------------------------------------------------------------------------
__global__ __launch_bounds__(256) void bn_stats_kernel(
    const u16* __restrict__ proj, float* __restrict__ stats) {
  const int c = blockIdx.x;
  const int tid = threadIdx.x;
  float s = 0.f, s2 = 0.f;
  for (int b = 0; b < Bn; ++b) {
    us4 v = reinterpret_cast<const us4*>(proj + ((size_t)b * Cc + c) * Nn)[tid];
#pragma unroll
    for (int j = 0; j < 4; ++j) {
      float f = bf2f(v[j]);
      s += f;
      s2 += f * f;
    }
  }
  s = waveSum(s);
  s2 = waveSum(s2);
  __shared__ float r1[4], r2[4];
  if ((tid & 63) == 0) { r1[tid >> 6] = s; r2[tid >> 6] = s2; }
  __syncthreads();
  if (tid == 0) {
    float S = r1[0] + r1[1] + r1[2] + r1[3];
    float S2 = r2[0] + r2[1] + r2[2] + r2[3];
    const float invM = 1.f / (float)(Bn * Nn);
    float mean = S * invM;
    float var = S2 * invM - mean * mean;
    stats[c] = mean;
    stats[Cc + c] = rsqrtf(var + BN_EPS);
  }
}

__global__ __launch_bounds__(256) void bn_apply_kernel(
    const u16* __restrict__ proj, const float* __restrict__ stats,
    const float* __restrict__ gamma, const float* __restrict__ beta,
    float* __restrict__ out) {
  const int idx = blockIdx.x * 256 + threadIdx.x;
  const int flat = idx << 2;
  const int c = (flat >> 10) & (Cc - 1);
  us4 v = reinterpret_cast<const us4*>(proj)[idx];
  const float mean = stats[c];
  const float sc = stats[Cc + c] * gamma[c];
  const float sh = beta[c];
  float4 o;
  o.x = fmaxf((bf2f(v[0]) - mean) * sc + sh, 0.f);
  o.y = fmaxf((bf2f(v[1]) - mean) * sc + sh, 0.f);
  o.z = fmaxf((bf2f(v[2]) - mean) * sc + sh, 0.f);
  o.w = fmaxf((bf2f(v[3]) - mean) * sc + sh, 0.f);
  reinterpret_cast<float4*>(out)[idx] = o;
}

// ---------------------------------------------------------------------------
extern "C" void kernel_launch(void* const* d_in, const int* in_sizes, int n_in,
                              void* d_out, int out_size, void* d_ws, size_t ws_size,
                              hipStream_t stream) {
  const float* x = (const float*)d_in[0];
  const float* w_qkv = (const float*)d_in[1];
  const float* head_scale = (const float*)d_in[2];
  const float* w_out = (const float*)d_in[3];
  const float* gamma = (const float*)d_in[4];
  const float* beta = (const float*)d_in[5];
  float* out = (float*)d_out;

  char* w = (char*)d_ws;
  u16* qt = (u16*)(w + 0);                 // 8 MB
  u16* kt = (u16*)(w + 8388608);           // 8 MB
  u16* vt = (u16*)(w + 16777216);          // 8 MB
  u16* wA = (u16*)(w + 25165824);          // 7 MB (dead after qkv GEMM)
  u16* aout = (u16*)(w + 25165824);        // 8 MB (written post-GEMM, by attn)
  u16* B2 = (u16*)(w + 33554432);          // 37.7 MB (dead after qkv GEMM)
  u16* proj = (u16*)(w + 33554432);        // 4 MB bf16, overlays dead B2
  u16* pbF = (u16*)(w + 41943040);         // 16.8 MB, overlays dead B2 tail
  float* stats = (float*)(w + 71860224);   // 2048 B
  u16* wB = (u16*)(w + 71862272);          // 262144 B

  wconv_kernel<<<dim3(OC), dim3(256), 0, stream>>>(w_qkv, wA);
  wout_repack_kernel<<<dim3(64), dim3(256), 0, stream>>>(w_out, wB);
  im2col_kernel<<<dim3(128), dim3(256), 0, stream>>>(x, B2);
  qkv_gemm_kernel<<<dim3(768), dim3(256), 0, stream>>>(wA, B2, qt, kt, vt);
  pbgen_kernel<<<dim3(G * Nn), dim3(256), 0, stream>>>(head_scale, pbF);
  attn_mfma_kernel<<<dim3(512), dim3(256), 0, stream>>>(qt, kt, vt, pbF, aout);
  conv1x1_mfma_kernel<<<dim3(512), dim3(256), 0, stream>>>(aout, wB, proj);
  bn_stats_kernel<<<dim3(Cc), dim3(256), 0, stream>>>(proj, stats);
  bn_apply_kernel<<<dim3((Bn * Cc * Nn / 4) / 256), dim3(256), 0, stream>>>(proj, stats, gamma, beta, out);
}

// Round 7
// 172.725 us; speedup vs baseline: 13.3272x; 1.1803x over previous
//
#include <hip/hip_runtime.h>
#include <math.h>

#define SMOOTH 1e-4f
#define BN_EPS 1e-5f

constexpr int Bn = 8;
constexpr int Cc = 256;
constexpr int Nn = 1024;   // H*W
constexpr int G = 8;       // heads
constexpr int INNER = 512;
constexpr int OC = 1536;   // 3*INNER
constexpr int KK = 2304;   // 9*256 im2col K

typedef unsigned short u16;
typedef __bf16 bf16x8 __attribute__((ext_vector_type(8)));
typedef float f32x4 __attribute__((ext_vector_type(4)));
typedef unsigned short us8 __attribute__((ext_vector_type(8)));
typedef unsigned short us4 __attribute__((ext_vector_type(4)));

__device__ __forceinline__ u16 f2bf(float f) {
  unsigned int u = __float_as_uint(f);
  unsigned int r = (u + 0x7fffu + ((u >> 16) & 1u)) >> 16;
  return (u16)r;
}
__device__ __forceinline__ float bf2f(u16 u) {
  return __uint_as_float(((unsigned int)u) << 16);
}

__device__ __forceinline__ float waveSum(float v) {
#pragma unroll
  for (int off = 32; off > 0; off >>= 1) v += __shfl_xor(v, off, 64);
  return v;
}

__device__ __forceinline__ void gl16(const u16* g, u16* l) {
  __builtin_amdgcn_global_load_lds(
      (const __attribute__((address_space(1))) unsigned int*)g,
      (__attribute__((address_space(3))) unsigned int*)l, 16, 0, 0);
}

__device__ __forceinline__ bf16x8 ld8(const u16* p) {
  return __builtin_bit_cast(bf16x8, *reinterpret_cast<const us8*>(p));
}

// raw barrier with compiler fences (no vmcnt/lgkm drain)
__device__ __forceinline__ void barrier_raw() {
  asm volatile("" ::: "memory");
  __builtin_amdgcn_s_barrier();
  asm volatile("" ::: "memory");
  __builtin_amdgcn_sched_barrier(0);
}

// swizzled LDS fragment read (attn): rows of 64 u16, byte ^ ((row&7)<<4)
__device__ __forceinline__ bf16x8 ldfrag(const u16* base, int row, int col) {
  int idx = (row * 64 + col) ^ ((row & 7) << 3);
  return ld8(base + idx);
}

// ---------------------------------------------------------------------------
// weight repack: wA[oc][tap*256+ic] = bf16(w_qkv[oc][ic*9+tap]). grid = 1536.
// ---------------------------------------------------------------------------
__global__ __launch_bounds__(256) void wconv_kernel(
    const float* __restrict__ wq, u16* __restrict__ wA) {
  const int oc = blockIdx.x;
  const int tid = threadIdx.x;
  __shared__ float sw[KK];
  for (int i = tid; i < KK; i += 256) sw[i] = wq[(size_t)oc * KK + i];
  __syncthreads();
#pragma unroll
  for (int j = 0; j < 2; ++j) {
    int c8 = tid + j * 256;
    if (c8 < KK / 8) {
      us8 v;
#pragma unroll
      for (int e = 0; e < 8; ++e) {
        int k = c8 * 8 + e;
        int tap = k >> 8, ic = k & 255;
        v[e] = f2bf(sw[ic * 9 + tap]);
      }
      *reinterpret_cast<us8*>(wA + (size_t)oc * KK + c8 * 8) = v;
    }
  }
}

// ---------------------------------------------------------------------------
// w_out -> bf16 repack. grid = 64 blocks of 256, us8 chunks.
// ---------------------------------------------------------------------------
__global__ __launch_bounds__(256) void wout_repack_kernel(
    const float* __restrict__ wout, u16* __restrict__ wB) {
  const int idx = blockIdx.x * 256 + threadIdx.x;
  const float4 a = reinterpret_cast<const float4*>(wout)[idx * 2];
  const float4 b = reinterpret_cast<const float4*>(wout)[idx * 2 + 1];
  us8 v;
  v[0] = f2bf(a.x); v[1] = f2bf(a.y); v[2] = f2bf(a.z); v[3] = f2bf(a.w);
  v[4] = f2bf(b.x); v[5] = f2bf(b.y); v[6] = f2bf(b.z); v[7] = f2bf(b.w);
  reinterpret_cast<us8*>(wB)[idx] = v;
}

// ---------------------------------------------------------------------------
// fused transpose + im2col: B2[pix][tap*256+ic] = bf16 x[b][ic][shift(pix,tap)]
// ---------------------------------------------------------------------------
__global__ __launch_bounds__(256) void im2col_kernel(
    const float* __restrict__ x, u16* __restrict__ B2) {
  const int tid = threadIdx.x;
  const int b = blockIdx.x >> 4;
  const int y0 = (blockIdx.x & 15) * 2;

  __shared__ u16 sxt[128 * 258];

  {
    const int pos = tid & 127;
    const int ichalf = tid >> 7;
    const int gidx = (y0 - 1) * 32 + pos;
    const bool valid = (gidx >= 0) && (gidx < 1024);
    const float* xb = x + (size_t)b * Cc * Nn;
    for (int ic2 = 0; ic2 < 128; ++ic2) {
      int ic = ichalf * 128 + ic2;
      float v = valid ? xb[(size_t)ic * Nn + gidx] : 0.f;
      sxt[pos * 258 + ic] = f2bf(v);
    }
  }
  __syncthreads();

  const int c16 = tid & 31;
  const int pl0 = tid >> 5;
  const us8 zero = {0, 0, 0, 0, 0, 0, 0, 0};
#pragma unroll
  for (int tap = 0; tap < 9; ++tap) {
    const int dy = tap / 3 - 1, dx = tap % 3 - 1;
#pragma unroll
    for (int it = 0; it < 8; ++it) {
      int pixloc = pl0 + it * 8;
      int yl = pixloc >> 5, xx = pixloc & 31;
      int sxx = xx + dx;
      int gy = y0 + yl + dy;
      bool v = (sxx >= 0) && (sxx < 32) && (gy >= 0) && (gy < 32);
      int spos = (yl + dy + 1) * 32 + sxx;
      us8 val = v ? *reinterpret_cast<const us8*>(sxt + spos * 258 + c16 * 8) : zero;
      size_t pix = (size_t)b * 1024 + (y0 + yl) * 32 + xx;
      *reinterpret_cast<us8*>(B2 + pix * KK + tap * 256 + c16 * 8) = val;
    }
  }
}

// ---------------------------------------------------------------------------
// separable positional-bias tables (H==W -> one 1D table per head):
// etab[g][d+31] = exp(-sf_g*(d/32)^2), idn[g][n] = 1/(rsum(y_n)*rsum(x_n))
// grid = 8 blocks of 256.
// ---------------------------------------------------------------------------
__global__ __launch_bounds__(256) void pbtab_kernel(
    const float* __restrict__ head_scale, float* __restrict__ etab,
    float* __restrict__ idn) {
  const int g = blockIdx.x;
  const int tid = threadIdx.x;
  __shared__ float et[64];
  __shared__ float rsum[32];
  const float hs = head_scale[g];
  const float sg = 1.f / (1.f + __expf(-hs));
  const float s = sg * (0.4f - 0.003f) + 0.003f;
  const float sf = 1.f / (2.f * s * s);
  if (tid < 64) {
    float v = 0.f;
    if (tid < 63) {
      float d = (float)(tid - 31) * (1.f / 32.f);
      v = __expf(-sf * d * d);
    }
    et[tid] = v;
    etab[g * 64 + tid] = v;
  }
  __syncthreads();
  if (tid < 32) {
    float sum = 0.f;
#pragma unroll
    for (int ym = 0; ym < 32; ++ym) sum += et[tid - ym + 31];
    rsum[tid] = sum;
  }
  __syncthreads();
  for (int i = tid; i < 1024; i += 256)
    idn[g * 1024 + i] = 1.f / (rsum[i >> 5] * rsum[i & 31]);
}

// ---------------------------------------------------------------------------
// qkv implicit GEMM, pipelined 256x256 tile, BK=64, 8 waves (2Mx4N),
// 4 phases/K-tile (K-half split), counted vmcnt(4), double-buffered 128KB LDS
// with involution swizzle slot^=(row>>1)&3 (pre-swizzled global source for
// global_load_lds, swizzled ds_read). grid = 6*32 = 192, XCD-swizzled.
// Epilogue: q,k normalized (f32-exact), q also scaled by 1/denom(g,n).
// ---------------------------------------------------------------------------
__global__ __launch_bounds__(512, 1) void qkv_gemm_kernel(
    const u16* __restrict__ wA, const u16* __restrict__ B2,
    const float* __restrict__ idn,
    u16* __restrict__ qt, u16* __restrict__ ktp, u16* __restrict__ vt) {
  const int tid = threadIdx.x;
  const int lane = tid & 63;
  const int wv = tid >> 6;
  const int wm = wv >> 2, wn = wv & 3;
  const int h = lane >> 4, l15 = lane & 15;
  const int wgid = ((int)blockIdx.x & 7) * 24 + ((int)blockIdx.x >> 3);
  const int bm = wgid % 6;
  const int bn = wgid / 6;
  const int m0 = bm * 256, n0 = bn * 256;

  // [buf(32768)][A:0/B:16384][kap(8192)][row(32)][slot(8)]
  __shared__ __align__(16) u16 smem[65536];  // 128 KiB

  // staging: thread covers (row = it*128 + tid>>2, slot' = tid&3);
  // source slot pre-swizzled so LDS content is swizzle(row): slot^((row>>1)&3)
  const int srow = tid >> 2;
  const int sslot = (tid & 3) ^ ((srow >> 1) & 3);
  const u16* gA0 = wA + (size_t)(m0 + srow) * KK + sslot * 8;
  const u16* gB0 = B2 + (size_t)(n0 + srow) * KK + sslot * 8;

  // fragment read: slot' = h ^ ((row>>1)&3); (row>>1)&3 == (l15>>1)&3 here
  const int fsl = (h ^ ((l15 >> 1) & 3)) * 8;
  const u16* fragA = smem + wm * 4096 + l15 * 32 + fsl;          // +buf+kap+mi*512
  const u16* fragB = smem + 16384 + wn * 2048 + l15 * 32 + fsl;  // +buf+kap+ni*512

  f32x4 acc[8][4];
#pragma unroll
  for (int i = 0; i < 8; ++i)
#pragma unroll
    for (int j = 0; j < 4; ++j) acc[i][j] = (f32x4){0.f, 0.f, 0.f, 0.f};

  auto STAGE = [&](int tens, int kap, int dbuf, int kti) {
    const u16* s = (tens ? gB0 : gA0) + kti * 64 + kap * 32;
    u16* d = smem + dbuf + tens * 16384 + kap * 8192 + tid * 8;
    gl16(s, d);
    gl16(s + (size_t)128 * KK, d + 4096);
  };

  // prologue: stage tile 0 (order: A k0, B k0, A k1, B k1)
  STAGE(0, 0, 0, 0);
  STAGE(1, 0, 0, 0);
  STAGE(0, 1, 0, 0);
  STAGE(1, 1, 0, 0);
  asm volatile("s_waitcnt vmcnt(4)" ::: "memory");  // A k0, B k0 landed
  barrier_raw();

  bf16x8 af[4], bf[4];
#pragma unroll 1
  for (int kt = 0; kt < 36; ++kt) {
    const int buf = (kt & 1) << 15;
    const int nbuf = buf ^ 32768;
    const bool more = (kt < 35);
    const u16* fA = fragA + buf;
    const u16* fB = fragB + buf;

    // ---- P1: kap0, mi 0..3 (+ B kap0) ------------------------------------
#pragma unroll
    for (int ni = 0; ni < 4; ++ni) bf[ni] = ld8(fB + ni * 512);
#pragma unroll
    for (int q = 0; q < 4; ++q) af[q] = ld8(fA + q * 512);
    if (more) STAGE(0, 0, nbuf, kt + 1);
    barrier_raw();
    __builtin_amdgcn_s_setprio(1);
#pragma unroll
    for (int q = 0; q < 4; ++q)
#pragma unroll
      for (int ni = 0; ni < 4; ++ni)
        acc[q][ni] = __builtin_amdgcn_mfma_f32_16x16x32_bf16(af[q], bf[ni], acc[q][ni], 0, 0, 0);
    __builtin_amdgcn_s_setprio(0);

    // ---- P2: kap0, mi 4..7 ----------------------------------------------
#pragma unroll
    for (int q = 0; q < 4; ++q) af[q] = ld8(fA + (4 + q) * 512);
    if (more) {
      STAGE(1, 0, nbuf, kt + 1);
      asm volatile("s_waitcnt vmcnt(4)" ::: "memory");  // A k1,B k1 of tile kt landed
    } else {
      asm volatile("s_waitcnt vmcnt(0)" ::: "memory");
    }
    barrier_raw();
    __builtin_amdgcn_s_setprio(1);
#pragma unroll
    for (int q = 0; q < 4; ++q)
#pragma unroll
      for (int ni = 0; ni < 4; ++ni)
        acc[4 + q][ni] = __builtin_amdgcn_mfma_f32_16x16x32_bf16(af[q], bf[ni], acc[4 + q][ni], 0, 0, 0);
    __builtin_amdgcn_s_setprio(0);

    // ---- P3: kap1, mi 0..3 (+ B kap1) ------------------------------------
#pragma unroll
    for (int ni = 0; ni < 4; ++ni) bf[ni] = ld8(fB + 8192 + ni * 512);
#pragma unroll
    for (int q = 0; q < 4; ++q) af[q] = ld8(fA + 8192 + q * 512);
    if (more) STAGE(0, 1, nbuf, kt + 1);
    barrier_raw();
    __builtin_amdgcn_s_setprio(1);
#pragma unroll
    for (int q = 0; q < 4; ++q)
#pragma unroll
      for (int ni = 0; ni < 4; ++ni)
        acc[q][ni] = __builtin_amdgcn_mfma_f32_16x16x32_bf16(af[q], bf[ni], acc[q][ni], 0, 0, 0);
    __builtin_amdgcn_s_setprio(0);

    // ---- P4: kap1, mi 4..7 ----------------------------------------------
#pragma unroll
    for (int q = 0; q < 4; ++q) af[q] = ld8(fA + 8192 + (4 + q) * 512);
    if (more) {
      STAGE(1, 1, nbuf, kt + 1);
      asm volatile("s_waitcnt vmcnt(4)" ::: "memory");  // A k0,B k0 of tile kt+1 landed
    }
    barrier_raw();
    __builtin_amdgcn_s_setprio(1);
#pragma unroll
    for (int q = 0; q < 4; ++q)
#pragma unroll
      for (int ni = 0; ni < 4; ++ni)
        acc[4 + q][ni] = __builtin_amdgcn_mfma_f32_16x16x32_bf16(af[q], bf[ni], acc[4 + q][ni], 0, 0, 0);
    __builtin_amdgcn_s_setprio(0);
  }

  // ---- epilogue ----------------------------------------------------------
  const int sec = bm >> 1;  // 0=q 1=k 2=v
  const int b = bn >> 2;
#pragma unroll
  for (int hd = 0; hd < 2; ++hd) {
    const int g = (bm * 4 + wm * 2 + hd) & 7;
    const size_t bg = (size_t)b * G + g;
    if (sec < 2) {
      u16* basep = (sec ? ktp : qt) + bg * 65536;
#pragma unroll
      for (int ni = 0; ni < 4; ++ni) {
        float ss = 0.f;
#pragma unroll
        for (int m4 = 0; m4 < 4; ++m4)
#pragma unroll
          for (int r = 0; r < 4; ++r) {
            float a = acc[hd * 4 + m4][ni][r];
            ss += a * a;
          }
        ss += __shfl_xor(ss, 16, 64);
        ss += __shfl_xor(ss, 32, 64);
        float rs = rsqrtf(ss + SMOOTH);
        const int nn = (bn & 3) * 256 + wn * 64 + ni * 16 + l15;
        if (sec == 0) rs *= idn[g * 1024 + nn];
#pragma unroll
        for (int m4 = 0; m4 < 4; ++m4) {
          us4 v;
          v[0] = f2bf(acc[hd * 4 + m4][ni][0] * rs);
          v[1] = f2bf(acc[hd * 4 + m4][ni][1] * rs);
          v[2] = f2bf(acc[hd * 4 + m4][ni][2] * rs);
          v[3] = f2bf(acc[hd * 4 + m4][ni][3] * rs);
          *reinterpret_cast<us4*>(basep + (size_t)nn * 64 + m4 * 16 + 4 * h) = v;
        }
      }
    } else {
      u16* basep = vt + bg * 65536;
#pragma unroll
      for (int ni = 0; ni < 4; ++ni) {
        const int nn = (bn & 3) * 256 + wn * 64 + ni * 16 + l15;
#pragma unroll
        for (int m4 = 0; m4 < 4; ++m4)
#pragma unroll
          for (int r = 0; r < 4; ++r)
            basep[(size_t)(m4 * 16 + 4 * h + r) * 1024 + nn] = f2bf(acc[hd * 4 + m4][ni][r]);
      }
    }
  }
}

// ---------------------------------------------------------------------------
// MFMA attention. block = 256 thr (4 waves), (b, g, 128 q-rows).
// q pre-scaled by 1/denom, q/k pre-normalized -> wgt = sacc * ey * ex from
// the separable 64-entry table (LDS broadcast reads). grid = 512.
// ---------------------------------------------------------------------------
__global__ __launch_bounds__(256, 2) void attn_mfma_kernel(
    const u16* __restrict__ qt, const u16* __restrict__ ktp,
    const u16* __restrict__ vt, const float* __restrict__ etab,
    u16* __restrict__ aout) {
  const int tid = threadIdx.x;
  const int lane = tid & 63;
  const int wv = tid >> 6;
  const int h = lane >> 4;
  const int l15 = lane & 15;
  const int wgid = (blockIdx.x & 7) * 64 + (blockIdx.x >> 3);
  const int g = wgid >> 6;  // one g per XCD
  const int b = (wgid >> 3) & 7;
  const int nb = wgid & 7;

  __shared__ __align__(16) u16 smem[24576];
  __shared__ float etabL[64];
  u16* sQ = smem;
  u16* sK = smem + 8192;
  u16* sV = smem + 12288;
  u16* sP = smem + 16384 + wv * 2048;

  const size_t bg = (size_t)b * G + g;
  const u16* qg = qt + bg * 65536;
  const u16* kg = ktp + bg * 65536;
  const u16* vg = vt + bg * 65536;

  if (tid < 64) etabL[tid] = etab[g * 64 + tid];
  {
    const int row = tid >> 1, c = (tid & 1) * 4;
    const us8* src = reinterpret_cast<const us8*>(qg + (size_t)(nb * 128 + row) * 64);
#pragma unroll
    for (int k = 0; k < 4; ++k) {
      int idx = (row * 64 + (c + k) * 8) ^ ((row & 7) << 3);
      *reinterpret_cast<us8*>(sQ + idx) = src[c + k];
    }
  }
  __syncthreads();

  // per-lane x-part of pb (m-tile independent): x_m = l15 or l15+16
  float exv[2][4][2];
  int ynr[2][4];
#pragma unroll
  for (int ti = 0; ti < 2; ++ti)
#pragma unroll
    for (int r = 0; r < 4; ++r) {
      int n = nb * 128 + wv * 32 + ti * 16 + 4 * h + r;
      int xn = n & 31;
      ynr[ti][r] = n >> 5;
      exv[ti][r][0] = etabL[xn - l15 + 31];
      exv[ti][r][1] = etabL[xn - l15 + 15];
    }

  f32x4 oacc[2][4];
#pragma unroll
  for (int ti = 0; ti < 2; ++ti)
#pragma unroll
    for (int dj = 0; dj < 4; ++dj) oacc[ti][dj] = (f32x4){0.f, 0.f, 0.f, 0.f};

  const int col8 = h * 8;

  for (int mt = 0; mt < 16; ++mt) {
    __syncthreads();
    {
      const int row = tid >> 2, cc = (tid & 3) * 2;
      const us8* ksrc = reinterpret_cast<const us8*>(kg + (size_t)(mt * 64 + row) * 64);
      const us8* vsrc = reinterpret_cast<const us8*>(vg + (size_t)row * 1024 + mt * 64);
#pragma unroll
      for (int k = 0; k < 2; ++k) {
        int idx = (row * 64 + (cc + k) * 8) ^ ((row & 7) << 3);
        *reinterpret_cast<us8*>(sK + idx) = ksrc[cc + k];
        *reinterpret_cast<us8*>(sV + idx) = vsrc[cc + k];
      }
    }
    __syncthreads();

    // y-part of pb for this m-tile: y_m = 2*mt + {0,1}
    float eyv[2][4][2];
#pragma unroll
    for (int ti = 0; ti < 2; ++ti)
#pragma unroll
      for (int r = 0; r < 4; ++r) {
        eyv[ti][r][0] = etabL[ynr[ti][r] - 2 * mt + 31];
        eyv[ti][r][1] = etabL[ynr[ti][r] - 2 * mt + 30];
      }

    f32x4 sacc[2][4];
#pragma unroll
    for (int ti = 0; ti < 2; ++ti)
#pragma unroll
      for (int tj = 0; tj < 4; ++tj) sacc[ti][tj] = (f32x4){0.f, 0.f, 0.f, 0.f};
#pragma unroll
    for (int kk = 0; kk < 2; ++kk) {
      bf16x8 aq0 = ldfrag(sQ, wv * 32 + l15, kk * 32 + col8);
      bf16x8 aq1 = ldfrag(sQ, wv * 32 + 16 + l15, kk * 32 + col8);
#pragma unroll
      for (int tj = 0; tj < 4; ++tj) {
        bf16x8 bk = ldfrag(sK, tj * 16 + l15, kk * 32 + col8);
        sacc[0][tj] = __builtin_amdgcn_mfma_f32_16x16x32_bf16(aq0, bk, sacc[0][tj], 0, 0, 0);
        sacc[1][tj] = __builtin_amdgcn_mfma_f32_16x16x32_bf16(aq1, bk, sacc[1][tj], 0, 0, 0);
      }
    }

    // P = cos*idn * ey * ex -> bf16 -> per-wave LDS
#pragma unroll
    for (int tj = 0; tj < 4; ++tj) {
#pragma unroll
      for (int ti = 0; ti < 2; ++ti) {
#pragma unroll
        for (int r = 0; r < 4; ++r) {
          float wgt = sacc[ti][tj][r] * (eyv[ti][r][tj >> 1] * exv[ti][r][tj & 1]);
          int nl = ti * 16 + 4 * h + r;
          int pidx = (nl * 64 + tj * 16 + l15) ^ ((nl & 7) << 3);
          sP[pidx] = f2bf(wgt);
        }
      }
    }

#pragma unroll
    for (int km = 0; km < 2; ++km) {
      bf16x8 ap0 = ldfrag(sP, l15, km * 32 + col8);
      bf16x8 ap1 = ldfrag(sP, 16 + l15, km * 32 + col8);
#pragma unroll
      for (int dj = 0; dj < 4; ++dj) {
        bf16x8 bvv = ldfrag(sV, dj * 16 + l15, km * 32 + col8);
        oacc[0][dj] = __builtin_amdgcn_mfma_f32_16x16x32_bf16(ap0, bvv, oacc[0][dj], 0, 0, 0);
        oacc[1][dj] = __builtin_amdgcn_mfma_f32_16x16x32_bf16(ap1, bvv, oacc[1][dj], 0, 0, 0);
      }
    }
  }

  __syncthreads();
  u16* sO = sK;
#pragma unroll
  for (int ti = 0; ti < 2; ++ti)
#pragma unroll
    for (int dj = 0; dj < 4; ++dj)
#pragma unroll
      for (int r = 0; r < 4; ++r) {
        int nl = wv * 32 + ti * 16 + 4 * h + r;
        int idx = (nl * 64 + dj * 16 + l15) ^ ((nl & 7) << 3);
        sO[idx] = f2bf(oacc[ti][dj][r]);
      }
  __syncthreads();
  {
    const int row = tid >> 1, c = (tid & 1) * 4;
    us8* dst = reinterpret_cast<us8*>(aout + (bg * 1024 + (size_t)nb * 128 + row) * 64);
#pragma unroll
    for (int k = 0; k < 4; ++k) {
      int idx = (row * 64 + (c + k) * 8) ^ ((row & 7) << 3);
      dst[c + k] = *reinterpret_cast<const us8*>(sO + idx);
    }
  }
}

// ---------------------------------------------------------------------------
// 1x1 conv as MFMA GEMM. grid = 512.
// ---------------------------------------------------------------------------
__global__ __launch_bounds__(256, 2) void conv1x1_mfma_kernel(
    const u16* __restrict__ aout, const u16* __restrict__ wB,
    u16* __restrict__ proj) {
  const int tid = threadIdx.x;
  const int lane = tid & 63;
  const int wv = tid >> 6;
  const int wr = wv >> 1, wc = wv & 1;
  const int h = lane >> 4, l15 = lane & 15;
  const int bm = blockIdx.x & 3;
  const int ntile = blockIdx.x >> 2;
  const int b = ntile >> 4;
  const int n0 = (ntile & 15) * 64;
  const int c0 = bm * 64;

  __shared__ __align__(16) u16 sA[64 * 64];
  __shared__ __align__(16) u16 sB[64 * 64];

  f32x4 acc[2][2];
#pragma unroll
  for (int i = 0; i < 2; ++i)
#pragma unroll
    for (int j = 0; j < 2; ++j) acc[i][j] = (f32x4){0.f, 0.f, 0.f, 0.f};

  const int srow = (wv << 3) + (lane >> 3);
  const int scol = (lane & 7) << 3;
  const u16* gA = wB + (size_t)(c0 + srow) * 512 + scol;
  const u16* gB = aout + ((size_t)(b * G) * 1024 + n0 + srow) * 64 + scol;
  u16* lA = sA + wv * 512;
  u16* lB = sB + wv * 512;

  for (int ks = 0; ks < 8; ++ks) {
    __syncthreads();
#pragma unroll
    for (int it = 0; it < 2; ++it) {
      gl16(gA + (size_t)it * 32 * 512, lA + it * 2048);
      gl16(gB + (size_t)it * 32 * 64, lB + it * 2048);
    }
    gA += 64;
    gB += 65536;
    __syncthreads();
#pragma unroll
    for (int kk = 0; kk < 2; ++kk) {
      bf16x8 af[2], bv[2];
#pragma unroll
      for (int mt = 0; mt < 2; ++mt)
        af[mt] = ld8(sA + (wr * 32 + mt * 16 + l15) * 64 + kk * 32 + h * 8);
#pragma unroll
      for (int nt = 0; nt < 2; ++nt)
        bv[nt] = ld8(sB + (wc * 32 + nt * 16 + l15) * 64 + kk * 32 + h * 8);
#pragma unroll
      for (int mt = 0; mt < 2; ++mt)
#pragma unroll
        for (int nt = 0; nt < 2; ++nt)
          acc[mt][nt] = __builtin_amdgcn_mfma_f32_16x16x32_bf16(af[mt], bv[nt], acc[mt][nt], 0, 0, 0);
    }
  }

#pragma unroll
  for (int mt = 0; mt < 2; ++mt)
#pragma unroll
    for (int nt = 0; nt < 2; ++nt)
#pragma unroll
      for (int r = 0; r < 4; ++r) {
        const int c = c0 + wr * 32 + mt * 16 + 4 * h + r;
        const int n = n0 + wc * 32 + nt * 16 + l15;
        proj[((size_t)b * Cc + c) * Nn + n] = f2bf(acc[mt][nt][r]);
      }
}

// ---------------------------------------------------------------------------
__global__ __launch_bounds__(256) void bn_stats_kernel(
    const u16* __restrict__ proj, float* __restrict__ stats) {
  const int c = blockIdx.x;
  const int tid = threadIdx.x;
  float s = 0.f, s2 = 0.f;
  for (int b = 0; b < Bn; ++b) {
    us4 v = reinterpret_cast<const us4*>(proj + ((size_t)b * Cc + c) * Nn)[tid];
#pragma unroll
    for (int j = 0; j < 4; ++j) {
      float f = bf2f(v[j]);
      s += f;
      s2 += f * f;
    }
  }
  s = waveSum(s);
  s2 = waveSum(s2);
  __shared__ float r1[4], r2[4];
  if ((tid & 63) == 0) { r1[tid >> 6] = s; r2[tid >> 6] = s2; }
  __syncthreads();
  if (tid == 0) {
    float S = r1[0] + r1[1] + r1[2] + r1[3];
    float S2 = r2[0] + r2[1] + r2[2] + r2[3];
    const float invM = 1.f / (float)(Bn * Nn);
    float mean = S * invM;
    float var = S2 * invM - mean * mean;
    stats[c] = mean;
    stats[Cc + c] = rsqrtf(var + BN_EPS);
  }
}

__global__ __launch_bounds__(256) void bn_apply_kernel(
    const u16* __restrict__ proj, const float* __restrict__ stats,
    const float* __restrict__ gamma, const float* __restrict__ beta,
    float* __restrict__ out) {
  const int idx = blockIdx.x * 256 + threadIdx.x;
  const int flat = idx << 2;
  const int c = (flat >> 10) & (Cc - 1);
  us4 v = reinterpret_cast<const us4*>(proj)[idx];
  const float mean = stats[c];
  const float sc = stats[Cc + c] * gamma[c];
  const float sh = beta[c];
  float4 o;
  o.x = fmaxf((bf2f(v[0]) - mean) * sc + sh, 0.f);
  o.y = fmaxf((bf2f(v[1]) - mean) * sc + sh, 0.f);
  o.z = fmaxf((bf2f(v[2]) - mean) * sc + sh, 0.f);
  o.w = fmaxf((bf2f(v[3]) - mean) * sc + sh, 0.f);
  reinterpret_cast<float4*>(out)[idx] = o;
}

// ---------------------------------------------------------------------------
extern "C" void kernel_launch(void* const* d_in, const int* in_sizes, int n_in,
                              void* d_out, int out_size, void* d_ws, size_t ws_size,
                              hipStream_t stream) {
  const float* x = (const float*)d_in[0];
  const float* w_qkv = (const float*)d_in[1];
  const float* head_scale = (const float*)d_in[2];
  const float* w_out = (const float*)d_in[3];
  const float* gamma = (const float*)d_in[4];
  const float* beta = (const float*)d_in[5];
  float* out = (float*)d_out;

  char* w = (char*)d_ws;
  u16* qt = (u16*)(w + 0);                 // 8 MB
  u16* kt = (u16*)(w + 8388608);           // 8 MB
  u16* vt = (u16*)(w + 16777216);          // 8 MB
  u16* wA = (u16*)(w + 25165824);          // 7 MB (dead after qkv GEMM)
  u16* aout = (u16*)(w + 25165824);        // 8 MB (written post-GEMM, by attn)
  u16* B2 = (u16*)(w + 33554432);          // 37.7 MB (dead after qkv GEMM)
  u16* proj = (u16*)(w + 33554432);        // 4 MB bf16, overlays dead B2
  float* etab = (float*)(w + 71303168);    // 2 KB  (old qn region, free)
  float* idn = (float*)(w + 71305216);     // 32 KB
  float* stats = (float*)(w + 71860224);   // 2 KB
  u16* wB = (u16*)(w + 71862272);          // 256 KB

  wconv_kernel<<<dim3(OC), dim3(256), 0, stream>>>(w_qkv, wA);
  wout_repack_kernel<<<dim3(64), dim3(256), 0, stream>>>(w_out, wB);
  im2col_kernel<<<dim3(128), dim3(256), 0, stream>>>(x, B2);
  pbtab_kernel<<<dim3(8), dim3(256), 0, stream>>>(head_scale, etab, idn);
  qkv_gemm_kernel<<<dim3(192), dim3(512), 0, stream>>>(wA, B2, idn, qt, kt, vt);
  attn_mfma_kernel<<<dim3(512), dim3(256), 0, stream>>>(qt, kt, vt, etab, aout);
  conv1x1_mfma_kernel<<<dim3(512), dim3(256), 0, stream>>>(aout, wB, proj);
  bn_stats_kernel<<<dim3(Cc), dim3(256), 0, stream>>>(proj, stats);
  bn_apply_kernel<<<dim3((Bn * Cc * Nn / 4) / 256), dim3(256), 0, stream>>>(proj, stats, gamma, beta, out);
}

// Round 8
// 165.694 us; speedup vs baseline: 13.8928x; 1.0424x over previous
//
#include <hip/hip_runtime.h>
#include <math.h>

#define SMOOTH 1e-4f
#define BN_EPS 1e-5f

constexpr int Bn = 8;
constexpr int Cc = 256;
constexpr int Nn = 1024;   // H*W
constexpr int G = 8;       // heads
constexpr int INNER = 512;
constexpr int OC = 1536;   // 3*INNER
constexpr int KK = 2304;   // 9*256 im2col K

typedef unsigned short u16;
typedef __bf16 bf16x8 __attribute__((ext_vector_type(8)));
typedef float f32x4 __attribute__((ext_vector_type(4)));
typedef unsigned short us8 __attribute__((ext_vector_type(8)));
typedef unsigned short us4 __attribute__((ext_vector_type(4)));

__device__ __forceinline__ u16 f2bf(float f) {
  unsigned int u = __float_as_uint(f);
  unsigned int r = (u + 0x7fffu + ((u >> 16) & 1u)) >> 16;
  return (u16)r;
}
__device__ __forceinline__ float bf2f(u16 u) {
  return __uint_as_float(((unsigned int)u) << 16);
}

__device__ __forceinline__ float waveSum(float v) {
#pragma unroll
  for (int off = 32; off > 0; off >>= 1) v += __shfl_xor(v, off, 64);
  return v;
}

__device__ __forceinline__ void gl16(const u16* g, u16* l) {
  __builtin_amdgcn_global_load_lds(
      (const __attribute__((address_space(1))) unsigned int*)g,
      (__attribute__((address_space(3))) unsigned int*)l, 16, 0, 0);
}

__device__ __forceinline__ bf16x8 ld8(const u16* p) {
  return __builtin_bit_cast(bf16x8, *reinterpret_cast<const us8*>(p));
}

// raw barrier with compiler fences (no vmcnt/lgkm drain)
__device__ __forceinline__ void barrier_raw() {
  asm volatile("" ::: "memory");
  __builtin_amdgcn_s_barrier();
  asm volatile("" ::: "memory");
  __builtin_amdgcn_sched_barrier(0);
}

// swizzled LDS fragment read: rows of 64 u16, u16idx ^ ((row&7)<<3)
__device__ __forceinline__ bf16x8 ldfrag(const u16* base, int row, int col) {
  int idx = (row * 64 + col) ^ ((row & 7) << 3);
  return ld8(base + idx);
}

// ---------------------------------------------------------------------------
// weight repack: wA[oc][tap*256+ic] = bf16(w_qkv[oc][ic*9+tap]). grid = 1536.
// ---------------------------------------------------------------------------
__global__ __launch_bounds__(256) void wconv_kernel(
    const float* __restrict__ wq, u16* __restrict__ wA) {
  const int oc = blockIdx.x;
  const int tid = threadIdx.x;
  __shared__ float sw[KK];
  for (int i = tid; i < KK; i += 256) sw[i] = wq[(size_t)oc * KK + i];
  __syncthreads();
#pragma unroll
  for (int j = 0; j < 2; ++j) {
    int c8 = tid + j * 256;
    if (c8 < KK / 8) {
      us8 v;
#pragma unroll
      for (int e = 0; e < 8; ++e) {
        int k = c8 * 8 + e;
        int tap = k >> 8, ic = k & 255;
        v[e] = f2bf(sw[ic * 9 + tap]);
      }
      *reinterpret_cast<us8*>(wA + (size_t)oc * KK + c8 * 8) = v;
    }
  }
}

// ---------------------------------------------------------------------------
// w_out -> bf16 repack. grid = 64 blocks of 256, us8 chunks.
// ---------------------------------------------------------------------------
__global__ __launch_bounds__(256) void wout_repack_kernel(
    const float* __restrict__ wout, u16* __restrict__ wB) {
  const int idx = blockIdx.x * 256 + threadIdx.x;
  const float4 a = reinterpret_cast<const float4*>(wout)[idx * 2];
  const float4 b = reinterpret_cast<const float4*>(wout)[idx * 2 + 1];
  us8 v;
  v[0] = f2bf(a.x); v[1] = f2bf(a.y); v[2] = f2bf(a.z); v[3] = f2bf(a.w);
  v[4] = f2bf(b.x); v[5] = f2bf(b.y); v[6] = f2bf(b.z); v[7] = f2bf(b.w);
  reinterpret_cast<us8*>(wB)[idx] = v;
}

// ---------------------------------------------------------------------------
// fused transpose + im2col: B2[pix][tap*256+ic] = bf16 x[b][ic][shift(pix,tap)]
// ---------------------------------------------------------------------------
__global__ __launch_bounds__(256) void im2col_kernel(
    const float* __restrict__ x, u16* __restrict__ B2) {
  const int tid = threadIdx.x;
  const int b = blockIdx.x >> 4;
  const int y0 = (blockIdx.x & 15) * 2;

  __shared__ u16 sxt[128 * 258];

  {
    const int pos = tid & 127;
    const int ichalf = tid >> 7;
    const int gidx = (y0 - 1) * 32 + pos;
    const bool valid = (gidx >= 0) && (gidx < 1024);
    const float* xb = x + (size_t)b * Cc * Nn;
    for (int ic2 = 0; ic2 < 128; ++ic2) {
      int ic = ichalf * 128 + ic2;
      float v = valid ? xb[(size_t)ic * Nn + gidx] : 0.f;
      sxt[pos * 258 + ic] = f2bf(v);
    }
  }
  __syncthreads();

  const int c16 = tid & 31;
  const int pl0 = tid >> 5;
  const us8 zero = {0, 0, 0, 0, 0, 0, 0, 0};
#pragma unroll
  for (int tap = 0; tap < 9; ++tap) {
    const int dy = tap / 3 - 1, dx = tap % 3 - 1;
#pragma unroll
    for (int it = 0; it < 8; ++it) {
      int pixloc = pl0 + it * 8;
      int yl = pixloc >> 5, xx = pixloc & 31;
      int sxx = xx + dx;
      int gy = y0 + yl + dy;
      bool v = (sxx >= 0) && (sxx < 32) && (gy >= 0) && (gy < 32);
      int spos = (yl + dy + 1) * 32 + sxx;
      us8 val = v ? *reinterpret_cast<const us8*>(sxt + spos * 258 + c16 * 8) : zero;
      size_t pix = (size_t)b * 1024 + (y0 + yl) * 32 + xx;
      *reinterpret_cast<us8*>(B2 + pix * KK + tap * 256 + c16 * 8) = val;
    }
  }
}

// ---------------------------------------------------------------------------
// separable positional-bias tables (H==W -> one 1D table per head):
// etab[g][d+31] = exp(-sf_g*(d/32)^2), idn[g][n] = 1/(rsum(y_n)*rsum(x_n))
// ---------------------------------------------------------------------------
__global__ __launch_bounds__(256) void pbtab_kernel(
    const float* __restrict__ head_scale, float* __restrict__ etab,
    float* __restrict__ idn) {
  const int g = blockIdx.x;
  const int tid = threadIdx.x;
  __shared__ float et[64];
  __shared__ float rsum[32];
  const float hs = head_scale[g];
  const float sg = 1.f / (1.f + __expf(-hs));
  const float s = sg * (0.4f - 0.003f) + 0.003f;
  const float sf = 1.f / (2.f * s * s);
  if (tid < 64) {
    float v = 0.f;
    if (tid < 63) {
      float d = (float)(tid - 31) * (1.f / 32.f);
      v = __expf(-sf * d * d);
    }
    et[tid] = v;
    etab[g * 64 + tid] = v;
  }
  __syncthreads();
  if (tid < 32) {
    float sum = 0.f;
#pragma unroll
    for (int ym = 0; ym < 32; ++ym) sum += et[tid - ym + 31];
    rsum[tid] = sum;
  }
  __syncthreads();
  for (int i = tid; i < 1024; i += 256)
    idn[g * 1024 + i] = 1.f / (rsum[i >> 5] * rsum[i & 31]);
}

// ---------------------------------------------------------------------------
// qkv implicit GEMM, pipelined 256x256 tile, BK=64, 8 waves (2Mx4N),
// 4 phases/K-tile, counted vmcnt(4), double-buffered 128KB LDS with
// involution swizzle. grid = 6*32 = 192, XCD-swizzled. (unchanged from R7)
// ---------------------------------------------------------------------------
__global__ __launch_bounds__(512, 1) void qkv_gemm_kernel(
    const u16* __restrict__ wA, const u16* __restrict__ B2,
    const float* __restrict__ idn,
    u16* __restrict__ qt, u16* __restrict__ ktp, u16* __restrict__ vt) {
  const int tid = threadIdx.x;
  const int lane = tid & 63;
  const int wv = tid >> 6;
  const int wm = wv >> 2, wn = wv & 3;
  const int h = lane >> 4, l15 = lane & 15;
  const int wgid = ((int)blockIdx.x & 7) * 24 + ((int)blockIdx.x >> 3);
  const int bm = wgid % 6;
  const int bn = wgid / 6;
  const int m0 = bm * 256, n0 = bn * 256;

  __shared__ __align__(16) u16 smem[65536];  // 128 KiB

  const int srow = tid >> 2;
  const int sslot = (tid & 3) ^ ((srow >> 1) & 3);
  const u16* gA0 = wA + (size_t)(m0 + srow) * KK + sslot * 8;
  const u16* gB0 = B2 + (size_t)(n0 + srow) * KK + sslot * 8;

  const int fsl = (h ^ ((l15 >> 1) & 3)) * 8;
  const u16* fragA = smem + wm * 4096 + l15 * 32 + fsl;
  const u16* fragB = smem + 16384 + wn * 2048 + l15 * 32 + fsl;

  f32x4 acc[8][4];
#pragma unroll
  for (int i = 0; i < 8; ++i)
#pragma unroll
    for (int j = 0; j < 4; ++j) acc[i][j] = (f32x4){0.f, 0.f, 0.f, 0.f};

  auto STAGE = [&](int tens, int kap, int dbuf, int kti) {
    const u16* s = (tens ? gB0 : gA0) + kti * 64 + kap * 32;
    u16* d = smem + dbuf + tens * 16384 + kap * 8192 + tid * 8;
    gl16(s, d);
    gl16(s + (size_t)128 * KK, d + 4096);
  };

  STAGE(0, 0, 0, 0);
  STAGE(1, 0, 0, 0);
  STAGE(0, 1, 0, 0);
  STAGE(1, 1, 0, 0);
  asm volatile("s_waitcnt vmcnt(4)" ::: "memory");
  barrier_raw();

  bf16x8 af[4], bf[4];
#pragma unroll 1
  for (int kt = 0; kt < 36; ++kt) {
    const int buf = (kt & 1) << 15;
    const int nbuf = buf ^ 32768;
    const bool more = (kt < 35);
    const u16* fA = fragA + buf;
    const u16* fB = fragB + buf;

#pragma unroll
    for (int ni = 0; ni < 4; ++ni) bf[ni] = ld8(fB + ni * 512);
#pragma unroll
    for (int q = 0; q < 4; ++q) af[q] = ld8(fA + q * 512);
    if (more) STAGE(0, 0, nbuf, kt + 1);
    barrier_raw();
    __builtin_amdgcn_s_setprio(1);
#pragma unroll
    for (int q = 0; q < 4; ++q)
#pragma unroll
      for (int ni = 0; ni < 4; ++ni)
        acc[q][ni] = __builtin_amdgcn_mfma_f32_16x16x32_bf16(af[q], bf[ni], acc[q][ni], 0, 0, 0);
    __builtin_amdgcn_s_setprio(0);

#pragma unroll
    for (int q = 0; q < 4; ++q) af[q] = ld8(fA + (4 + q) * 512);
    if (more) {
      STAGE(1, 0, nbuf, kt + 1);
      asm volatile("s_waitcnt vmcnt(4)" ::: "memory");
    } else {
      asm volatile("s_waitcnt vmcnt(0)" ::: "memory");
    }
    barrier_raw();
    __builtin_amdgcn_s_setprio(1);
#pragma unroll
    for (int q = 0; q < 4; ++q)
#pragma unroll
      for (int ni = 0; ni < 4; ++ni)
        acc[4 + q][ni] = __builtin_amdgcn_mfma_f32_16x16x32_bf16(af[q], bf[ni], acc[4 + q][ni], 0, 0, 0);
    __builtin_amdgcn_s_setprio(0);

#pragma unroll
    for (int ni = 0; ni < 4; ++ni) bf[ni] = ld8(fB + 8192 + ni * 512);
#pragma unroll
    for (int q = 0; q < 4; ++q) af[q] = ld8(fA + 8192 + q * 512);
    if (more) STAGE(0, 1, nbuf, kt + 1);
    barrier_raw();
    __builtin_amdgcn_s_setprio(1);
#pragma unroll
    for (int q = 0; q < 4; ++q)
#pragma unroll
      for (int ni = 0; ni < 4; ++ni)
        acc[q][ni] = __builtin_amdgcn_mfma_f32_16x16x32_bf16(af[q], bf[ni], acc[q][ni], 0, 0, 0);
    __builtin_amdgcn_s_setprio(0);

#pragma unroll
    for (int q = 0; q < 4; ++q) af[q] = ld8(fA + 8192 + (4 + q) * 512);
    if (more) {
      STAGE(1, 1, nbuf, kt + 1);
      asm volatile("s_waitcnt vmcnt(4)" ::: "memory");
    }
    barrier_raw();
    __builtin_amdgcn_s_setprio(1);
#pragma unroll
    for (int q = 0; q < 4; ++q)
#pragma unroll
      for (int ni = 0; ni < 4; ++ni)
        acc[4 + q][ni] = __builtin_amdgcn_mfma_f32_16x16x32_bf16(af[q], bf[ni], acc[4 + q][ni], 0, 0, 0);
    __builtin_amdgcn_s_setprio(0);
  }

  const int sec = bm >> 1;  // 0=q 1=k 2=v
  const int b = bn >> 2;
#pragma unroll
  for (int hd = 0; hd < 2; ++hd) {
    const int g = (bm * 4 + wm * 2 + hd) & 7;
    const size_t bg = (size_t)b * G + g;
    if (sec < 2) {
      u16* basep = (sec ? ktp : qt) + bg * 65536;
#pragma unroll
      for (int ni = 0; ni < 4; ++ni) {
        float ss = 0.f;
#pragma unroll
        for (int m4 = 0; m4 < 4; ++m4)
#pragma unroll
          for (int r = 0; r < 4; ++r) {
            float a = acc[hd * 4 + m4][ni][r];
            ss += a * a;
          }
        ss += __shfl_xor(ss, 16, 64);
        ss += __shfl_xor(ss, 32, 64);
        float rs = rsqrtf(ss + SMOOTH);
        const int nn = (bn & 3) * 256 + wn * 64 + ni * 16 + l15;
        if (sec == 0) rs *= idn[g * 1024 + nn];
#pragma unroll
        for (int m4 = 0; m4 < 4; ++m4) {
          us4 v;
          v[0] = f2bf(acc[hd * 4 + m4][ni][0] * rs);
          v[1] = f2bf(acc[hd * 4 + m4][ni][1] * rs);
          v[2] = f2bf(acc[hd * 4 + m4][ni][2] * rs);
          v[3] = f2bf(acc[hd * 4 + m4][ni][3] * rs);
          *reinterpret_cast<us4*>(basep + (size_t)nn * 64 + m4 * 16 + 4 * h) = v;
        }
      }
    } else {
      u16* basep = vt + bg * 65536;
#pragma unroll
      for (int ni = 0; ni < 4; ++ni) {
        const int nn = (bn & 3) * 256 + wn * 64 + ni * 16 + l15;
#pragma unroll
        for (int m4 = 0; m4 < 4; ++m4)
#pragma unroll
          for (int r = 0; r < 4; ++r)
            basep[(size_t)(m4 * 16 + 4 * h + r) * 1024 + nn] = f2bf(acc[hd * 4 + m4][ni][r]);
      }
    }
  }
}

// ---------------------------------------------------------------------------
// MFMA attention, async-staged: Q/K/V via global_load_lds (linear LDS dest,
// pre-swizzled per-lane SOURCE col ^= row&7; read-side swizzle unchanged),
// K/V double-buffered, tile t+1 prefetched before computing tile t, ONE
// __syncthreads per m-tile. LDS 64KB -> 2 blocks/CU. grid = 512.
// ---------------------------------------------------------------------------
__global__ __launch_bounds__(256, 2) void attn_mfma_kernel(
    const u16* __restrict__ qt, const u16* __restrict__ ktp,
    const u16* __restrict__ vt, const float* __restrict__ etab,
    u16* __restrict__ aout) {
  const int tid = threadIdx.x;
  const int lane = tid & 63;
  const int wv = tid >> 6;
  const int h = lane >> 4;
  const int l15 = lane & 15;
  const int wgid = (blockIdx.x & 7) * 64 + (blockIdx.x >> 3);
  const int g = wgid >> 6;  // one g per XCD
  const int b = (wgid >> 3) & 7;
  const int nb = wgid & 7;

  __shared__ __align__(16) u16 smem[32768];  // 64 KB
  __shared__ float etabL[64];
  u16* sQ = smem;  // 128x64 = 8192 u16
  // K buf d: smem + 8192 + d*4096 ; V buf d: smem + 16384 + d*4096
  u16* sP = smem + 24576 + wv * 2048;  // 32x64 per wave

  const size_t bg = (size_t)b * G + g;
  const u16* qg = qt + bg * 65536;
  const u16* kg = ktp + bg * 65536;
  const u16* vg = vt + bg * 65536;

  if (tid < 64) etabL[tid] = etab[g * 64 + tid];

  const int srow = tid >> 3;                      // 0..31
  const int scol = ((tid & 7) ^ (srow & 7)) * 8;  // pre-swizzled source col

  // prologue: stage Q (4 passes) + KV tile 0 into buf0
#pragma unroll
  for (int pass = 0; pass < 4; ++pass)
    gl16(qg + (size_t)(nb * 128 + pass * 32 + srow) * 64 + scol,
         sQ + pass * 2048 + tid * 8);
#pragma unroll
  for (int pass = 0; pass < 2; ++pass) {
    gl16(kg + (size_t)(pass * 32 + srow) * 64 + scol,
         smem + 8192 + pass * 2048 + tid * 8);
    gl16(vg + (size_t)(pass * 32 + srow) * 1024 + scol,
         smem + 16384 + pass * 2048 + tid * 8);
  }
  __syncthreads();

  // per-lane x-part of pb (m-tile independent)
  float exv[2][4][2];
  int ynr[2][4];
#pragma unroll
  for (int ti = 0; ti < 2; ++ti)
#pragma unroll
    for (int r = 0; r < 4; ++r) {
      int n = nb * 128 + wv * 32 + ti * 16 + 4 * h + r;
      int xn = n & 31;
      ynr[ti][r] = n >> 5;
      exv[ti][r][0] = etabL[xn - l15 + 31];
      exv[ti][r][1] = etabL[xn - l15 + 15];
    }

  f32x4 oacc[2][4];
#pragma unroll
  for (int ti = 0; ti < 2; ++ti)
#pragma unroll
    for (int dj = 0; dj < 4; ++dj) oacc[ti][dj] = (f32x4){0.f, 0.f, 0.f, 0.f};

  const int col8 = h * 8;

  for (int mt = 0; mt < 16; ++mt) {
    const u16* sKb = smem + 8192 + (mt & 1) * 4096;
    const u16* sVb = smem + 16384 + (mt & 1) * 4096;
    if (mt < 15) {  // prefetch next tile into the other buffer
      const int nt2 = mt + 1;
      const int d = nt2 & 1;
#pragma unroll
      for (int pass = 0; pass < 2; ++pass) {
        gl16(kg + (size_t)(nt2 * 64 + pass * 32 + srow) * 64 + scol,
             smem + 8192 + d * 4096 + pass * 2048 + tid * 8);
        gl16(vg + (size_t)(pass * 32 + srow) * 1024 + nt2 * 64 + scol,
             smem + 16384 + d * 4096 + pass * 2048 + tid * 8);
      }
    }

    // y-part of pb for this m-tile: y_m = 2*mt + {0,1}
    float eyv[2][4][2];
#pragma unroll
    for (int ti = 0; ti < 2; ++ti)
#pragma unroll
      for (int r = 0; r < 4; ++r) {
        eyv[ti][r][0] = etabL[ynr[ti][r] - 2 * mt + 31];
        eyv[ti][r][1] = etabL[ynr[ti][r] - 2 * mt + 30];
      }

    f32x4 sacc[2][4];
#pragma unroll
    for (int ti = 0; ti < 2; ++ti)
#pragma unroll
      for (int tj = 0; tj < 4; ++tj) sacc[ti][tj] = (f32x4){0.f, 0.f, 0.f, 0.f};
#pragma unroll
    for (int kk = 0; kk < 2; ++kk) {
      bf16x8 aq0 = ldfrag(sQ, wv * 32 + l15, kk * 32 + col8);
      bf16x8 aq1 = ldfrag(sQ, wv * 32 + 16 + l15, kk * 32 + col8);
#pragma unroll
      for (int tj = 0; tj < 4; ++tj) {
        bf16x8 bk = ldfrag(sKb, tj * 16 + l15, kk * 32 + col8);
        sacc[0][tj] = __builtin_amdgcn_mfma_f32_16x16x32_bf16(aq0, bk, sacc[0][tj], 0, 0, 0);
        sacc[1][tj] = __builtin_amdgcn_mfma_f32_16x16x32_bf16(aq1, bk, sacc[1][tj], 0, 0, 0);
      }
    }

    // P = cos*idn * ey * ex -> bf16 -> per-wave LDS
#pragma unroll
    for (int tj = 0; tj < 4; ++tj) {
#pragma unroll
      for (int ti = 0; ti < 2; ++ti) {
#pragma unroll
        for (int r = 0; r < 4; ++r) {
          float wgt = sacc[ti][tj][r] * (eyv[ti][r][tj >> 1] * exv[ti][r][tj & 1]);
          int nl = ti * 16 + 4 * h + r;
          int pidx = (nl * 64 + tj * 16 + l15) ^ ((nl & 7) << 3);
          sP[pidx] = f2bf(wgt);
        }
      }
    }

#pragma unroll
    for (int km = 0; km < 2; ++km) {
      bf16x8 ap0 = ldfrag(sP, l15, km * 32 + col8);
      bf16x8 ap1 = ldfrag(sP, 16 + l15, km * 32 + col8);
#pragma unroll
      for (int dj = 0; dj < 4; ++dj) {
        bf16x8 bvv = ldfrag(sVb, dj * 16 + l15, km * 32 + col8);
        oacc[0][dj] = __builtin_amdgcn_mfma_f32_16x16x32_bf16(ap0, bvv, oacc[0][dj], 0, 0, 0);
        oacc[1][dj] = __builtin_amdgcn_mfma_f32_16x16x32_bf16(ap1, bvv, oacc[1][dj], 0, 0, 0);
      }
    }
    __syncthreads();  // next-tile loads landed + all waves done with this buf
  }

  u16* sO = smem + 8192;  // 8192 u16 (spans both K buffers, now dead)
#pragma unroll
  for (int ti = 0; ti < 2; ++ti)
#pragma unroll
    for (int dj = 0; dj < 4; ++dj)
#pragma unroll
      for (int r = 0; r < 4; ++r) {
        int nl = wv * 32 + ti * 16 + 4 * h + r;
        int idx = (nl * 64 + dj * 16 + l15) ^ ((nl & 7) << 3);
        sO[idx] = f2bf(oacc[ti][dj][r]);
      }
  __syncthreads();
  {
    const int row = tid >> 1, c = (tid & 1) * 4;
    us8* dst = reinterpret_cast<us8*>(aout + (bg * 1024 + (size_t)nb * 128 + row) * 64);
#pragma unroll
    for (int k = 0; k < 4; ++k) {
      int idx = (row * 64 + (c + k) * 8) ^ ((row & 7) << 3);
      dst[c + k] = *reinterpret_cast<const us8*>(sO + idx);
    }
  }
}

// ---------------------------------------------------------------------------
// 1x1 conv as MFMA GEMM, async-staged double-buffer (one barrier per K-step),
// 4 blocks/CU. grid = 512.
// ---------------------------------------------------------------------------
__global__ __launch_bounds__(256, 4) void conv1x1_mfma_kernel(
    const u16* __restrict__ aout, const u16* __restrict__ wB,
    u16* __restrict__ proj) {
  const int tid = threadIdx.x;
  const int lane = tid & 63;
  const int wv = tid >> 6;
  const int wr = wv >> 1, wc = wv & 1;
  const int h = lane >> 4, l15 = lane & 15;
  const int bm = blockIdx.x & 3;
  const int ntile = blockIdx.x >> 2;
  const int b = ntile >> 4;
  const int n0 = (ntile & 15) * 64;
  const int c0 = bm * 64;

  __shared__ __align__(16) u16 smem[16384];  // 32 KB: A[2][4096] B[2][4096]

  f32x4 acc[2][2];
#pragma unroll
  for (int i = 0; i < 2; ++i)
#pragma unroll
    for (int j = 0; j < 2; ++j) acc[i][j] = (f32x4){0.f, 0.f, 0.f, 0.f};

  const int srow = tid >> 3;       // 0..31
  const int scol = (tid & 7) * 8;  // u16

  auto STG = [&](int ks) {
    const int d = ks & 1;
#pragma unroll
    for (int pass = 0; pass < 2; ++pass) {
      gl16(wB + (size_t)(c0 + pass * 32 + srow) * 512 + ks * 64 + scol,
           smem + d * 4096 + pass * 2048 + tid * 8);
      gl16(aout + ((size_t)(b * G + ks) * 1024 + n0 + pass * 32 + srow) * 64 + scol,
           smem + 8192 + d * 4096 + pass * 2048 + tid * 8);
    }
  };

  STG(0);
  __syncthreads();
  for (int ks = 0; ks < 8; ++ks) {
    if (ks < 7) STG(ks + 1);
    const u16* sA = smem + (ks & 1) * 4096;
    const u16* sB = smem + 8192 + (ks & 1) * 4096;
#pragma unroll
    for (int kk = 0; kk < 2; ++kk) {
      bf16x8 af[2], bv[2];
#pragma unroll
      for (int mt = 0; mt < 2; ++mt)
        af[mt] = ld8(sA + (wr * 32 + mt * 16 + l15) * 64 + kk * 32 + h * 8);
#pragma unroll
      for (int nt = 0; nt < 2; ++nt)
        bv[nt] = ld8(sB + (wc * 32 + nt * 16 + l15) * 64 + kk * 32 + h * 8);
#pragma unroll
      for (int mt = 0; mt < 2; ++mt)
#pragma unroll
        for (int nt = 0; nt < 2; ++nt)
          acc[mt][nt] = __builtin_amdgcn_mfma_f32_16x16x32_bf16(af[mt], bv[nt], acc[mt][nt], 0, 0, 0);
    }
    __syncthreads();
  }

#pragma unroll
  for (int mt = 0; mt < 2; ++mt)
#pragma unroll
    for (int nt = 0; nt < 2; ++nt)
#pragma unroll
      for (int r = 0; r < 4; ++r) {
        const int c = c0 + wr * 32 + mt * 16 + 4 * h + r;
        const int n = n0 + wc * 32 + nt * 16 + l15;
        proj[((size_t)b * Cc + c) * Nn + n] = f2bf(acc[mt][nt][r]);
      }
}

// ---------------------------------------------------------------------------
__global__ __launch_bounds__(256) void bn_stats_kernel(
    const u16* __restrict__ proj, float* __restrict__ stats) {
  const int c = blockIdx.x;
  const int tid = threadIdx.x;
  float s = 0.f, s2 = 0.f;
  for (int b = 0; b < Bn; ++b) {
    us4 v = reinterpret_cast<const us4*>(proj + ((size_t)b * Cc + c) * Nn)[tid];
#pragma unroll
    for (int j = 0; j < 4; ++j) {
      float f = bf2f(v[j]);
      s += f;
      s2 += f * f;
    }
  }
  s = waveSum(s);
  s2 = waveSum(s2);
  __shared__ float r1[4], r2[4];
  if ((tid & 63) == 0) { r1[tid >> 6] = s; r2[tid >> 6] = s2; }
  __syncthreads();
  if (tid == 0) {
    float S = r1[0] + r1[1] + r1[2] + r1[3];
    float S2 = r2[0] + r2[1] + r2[2] + r2[3];
    const float invM = 1.f / (float)(Bn * Nn);
    float mean = S * invM;
    float var = S2 * invM - mean * mean;
    stats[c] = mean;
    stats[Cc + c] = rsqrtf(var + BN_EPS);
  }
}

__global__ __launch_bounds__(256) void bn_apply_kernel(
    const u16* __restrict__ proj, const float* __restrict__ stats,
    const float* __restrict__ gamma, const float* __restrict__ beta,
    float* __restrict__ out) {
  const int idx = blockIdx.x * 256 + threadIdx.x;
  const int flat = idx << 2;
  const int c = (flat >> 10) & (Cc - 1);
  us4 v = reinterpret_cast<const us4*>(proj)[idx];
  const float mean = stats[c];
  const float sc = stats[Cc + c] * gamma[c];
  const float sh = beta[c];
  float4 o;
  o.x = fmaxf((bf2f(v[0]) - mean) * sc + sh, 0.f);
  o.y = fmaxf((bf2f(v[1]) - mean) * sc + sh, 0.f);
  o.z = fmaxf((bf2f(v[2]) - mean) * sc + sh, 0.f);
  o.w = fmaxf((bf2f(v[3]) - mean) * sc + sh, 0.f);
  reinterpret_cast<float4*>(out)[idx] = o;
}

// ---------------------------------------------------------------------------
extern "C" void kernel_launch(void* const* d_in, const int* in_sizes, int n_in,
                              void* d_out, int out_size, void* d_ws, size_t ws_size,
                              hipStream_t stream) {
  const float* x = (const float*)d_in[0];
  const float* w_qkv = (const float*)d_in[1];
  const float* head_scale = (const float*)d_in[2];
  const float* w_out = (const float*)d_in[3];
  const float* gamma = (const float*)d_in[4];
  const float* beta = (const float*)d_in[5];
  float* out = (float*)d_out;

  char* w = (char*)d_ws;
  u16* qt = (u16*)(w + 0);                 // 8 MB
  u16* kt = (u16*)(w + 8388608);           // 8 MB
  u16* vt = (u16*)(w + 16777216);          // 8 MB
  u16* wA = (u16*)(w + 25165824);          // 7 MB (dead after qkv GEMM)
  u16* aout = (u16*)(w + 25165824);        // 8 MB (written post-GEMM, by attn)
  u16* B2 = (u16*)(w + 33554432);          // 37.7 MB (dead after qkv GEMM)
  u16* proj = (u16*)(w + 33554432);        // 4 MB bf16, overlays dead B2
  float* etab = (float*)(w + 71303168);    // 2 KB
  float* idn = (float*)(w + 71305216);     // 32 KB
  float* stats = (float*)(w + 71860224);   // 2 KB
  u16* wB = (u16*)(w + 71862272);          // 256 KB

  wconv_kernel<<<dim3(OC), dim3(256), 0, stream>>>(w_qkv, wA);
  wout_repack_kernel<<<dim3(64), dim3(256), 0, stream>>>(w_out, wB);
  im2col_kernel<<<dim3(128), dim3(256), 0, stream>>>(x, B2);
  pbtab_kernel<<<dim3(8), dim3(256), 0, stream>>>(head_scale, etab, idn);
  qkv_gemm_kernel<<<dim3(192), dim3(512), 0, stream>>>(wA, B2, idn, qt, kt, vt);
  attn_mfma_kernel<<<dim3(512), dim3(256), 0, stream>>>(qt, kt, vt, etab, aout);
  conv1x1_mfma_kernel<<<dim3(512), dim3(256), 0, stream>>>(aout, wB, proj);
  bn_stats_kernel<<<dim3(Cc), dim3(256), 0, stream>>>(proj, stats);
  bn_apply_kernel<<<dim3((Bn * Cc * Nn / 4) / 256), dim3(256), 0, stream>>>(proj, stats, gamma, beta, out);
}